// Round 1
// baseline (2089.117 us; speedup 1.0000x reference)
//
#include <hip/hip_runtime.h>
#include <math.h>

// ---- problem constants ----
#define NB    8        // batch
#define LSEQ  2048     // seq len
#define TKN   16384    // NB*LSEQ tokens
#define DM    256      // d_model
#define DI    512      // d_inner
#define DS    64       // d_state
#define DIP   1153     // 2*DI + 2*DS + 1
#define CDIM  640      // DI + 2*DS
#define NL    4
#define NC    16       // scan chunks
#define CL    128      // LSEQ/NC
#define VOC   100

__device__ __forceinline__ float block_reduce_sum256(float v) {
  __shared__ float sred[4];
  #pragma unroll
  for (int off = 32; off > 0; off >>= 1) v += __shfl_down(v, off, 64);
  int lane = threadIdx.x & 63, wid = threadIdx.x >> 6;
  if (lane == 0) sred[wid] = v;
  __syncthreads();
  return sred[0] + sred[1] + sred[2] + sred[3];
}

// hidden = embed[ids], resid = 0
__global__ __launch_bounds__(256) void embed_init(const int* __restrict__ ids,
    const float* __restrict__ embed, float* __restrict__ hidden, float* __restrict__ resid) {
  int t = blockIdx.x, tid = threadIdx.x;
  int id = ids[t];
  hidden[(size_t)t * DM + tid] = embed[(size_t)id * DM + tid];
  resid[(size_t)t * DM + tid] = 0.f;
}

// resid += hidden; hidden = rmsnorm(resid)*w
__global__ __launch_bounds__(256) void add_rmsnorm(float* __restrict__ resid,
    float* __restrict__ hidden, const float* __restrict__ w) {
  int t = blockIdx.x, tid = threadIdx.x;
  size_t o = (size_t)t * DM + tid;
  float r = resid[o] + hidden[o];
  resid[o] = r;
  float ss = block_reduce_sum256(r * r);
  hidden[o] = r * rsqrtf(ss * (1.f / DM) + 1e-5f) * w[tid];
}

// C[M,N] = A[M,K] @ Bw[N,K]^T   (both row-major, K contiguous). M%64==0, K%16==0.
__global__ __launch_bounds__(256) void gemm_nt(const float* __restrict__ A,
    const float* __restrict__ Bw, float* __restrict__ C, int M, int N, int K) {
  __shared__ float As[16][64];
  __shared__ float Bs[16][64];
  int tid = threadIdx.x;
  int bm = blockIdx.x * 64;
  int bn = blockIdx.y * 64;
  int tx = tid & 15, ty = tid >> 4;
  int lr = tid >> 2;            // 0..63 tile row
  int lc = (tid & 3) << 2;      // 0,4,8,12 k-offset
  float acc[4][4] = {{0.f}};
  const float* Arow = A + (size_t)(bm + lr) * K + lc;
  const float* Brow = Bw + (size_t)(bn + lr) * K + lc;
  bool bvalid = (bn + lr) < N;
  for (int k0 = 0; k0 < K; k0 += 16) {
    float4 av = *(const float4*)(Arow + k0);
    float4 bv = make_float4(0.f, 0.f, 0.f, 0.f);
    if (bvalid) bv = *(const float4*)(Brow + k0);
    __syncthreads();
    As[lc + 0][lr] = av.x; As[lc + 1][lr] = av.y; As[lc + 2][lr] = av.z; As[lc + 3][lr] = av.w;
    Bs[lc + 0][lr] = bv.x; Bs[lc + 1][lr] = bv.y; Bs[lc + 2][lr] = bv.z; Bs[lc + 3][lr] = bv.w;
    __syncthreads();
    #pragma unroll
    for (int kk = 0; kk < 16; ++kk) {
      float4 a4 = *(const float4*)&As[kk][ty << 2];
      float4 b4 = *(const float4*)&Bs[kk][tx << 2];
      float a[4] = {a4.x, a4.y, a4.z, a4.w};
      float b[4] = {b4.x, b4.y, b4.z, b4.w};
      #pragma unroll
      for (int i = 0; i < 4; ++i)
        #pragma unroll
        for (int j = 0; j < 4; ++j)
          acc[i][j] += a[i] * b[j];
    }
  }
  #pragma unroll
  for (int i = 0; i < 4; ++i) {
    int m = bm + (ty << 2) + i;
    #pragma unroll
    for (int j = 0; j < 4; ++j) {
      int n = bn + (tx << 2) + j;
      if (n < N) C[(size_t)m * N + n] = acc[i][j];
    }
  }
}

// depthwise causal conv(width 4)+bias+silu over zx[...,512:1152]; split into x,B,C; also dt=softplus
__global__ __launch_bounds__(256) void conv_silu(const float* __restrict__ zx,
    const float* __restrict__ cw, const float* __restrict__ cb,
    const float* __restrict__ dtbias, float* __restrict__ xo,
    float* __restrict__ Bo, float* __restrict__ Co, float* __restrict__ dto) {
  int idx = blockIdx.x * 256 + threadIdx.x;
  if (idx >= TKN * CDIM) return;
  int c = idx % CDIM;
  int tl = idx / CDIM;          // b*LSEQ + l
  int l = tl & (LSEQ - 1);
  float s = cb[c];
  #pragma unroll
  for (int k = 0; k < 4; ++k) {
    int ls = l - 3 + k;
    if (ls >= 0) s += cw[(c << 2) + k] * zx[(size_t)(tl - 3 + k) * DIP + DI + c];
  }
  float v = s / (1.f + expf(-s));
  if (c < DI)            xo[(size_t)tl * DI + c] = v;
  else if (c < DI + DS)  Bo[(size_t)tl * DS + (c - DI)] = v;
  else                   Co[(size_t)tl * DS + (c - DI - DS)] = v;
  if (c == 0) {
    float xr = zx[(size_t)tl * DIP + (DIP - 1)] + dtbias[0];
    dto[tl] = (xr > 20.f) ? xr : log1pf(expf(xr));
  }
}

// pass1: per-chunk local end state (h_in = 0). grid (DI/64, NC, NB), block 64.
__global__ __launch_bounds__(64) void scan_pass1(const float* __restrict__ x,
    const float* __restrict__ Bc, const float* __restrict__ dtb,
    const float* __restrict__ alog, float* __restrict__ hst, float* __restrict__ dts) {
  int lane = threadIdx.x;
  int pw = blockIdx.x, ch = blockIdx.y, b = blockIdx.z;
  int p = pw * 64 + lane;
  float A = -expf(alog[0]);
  float h[64];
  #pragma unroll
  for (int n = 0; n < 64; ++n) h[n] = 0.f;
  __shared__ float bsh[64];
  float dsum = 0.f;
  int t0 = ch * CL;
  for (int t = t0; t < t0 + CL; ++t) {
    size_t tl = (size_t)b * LSEQ + t;
    float dt = dtb[tl];
    dsum += dt;
    float a = expf(A * dt);
    float w = dt * x[tl * DI + p];
    __syncthreads();
    bsh[lane] = Bc[tl * DS + lane];
    __syncthreads();
    #pragma unroll
    for (int n4 = 0; n4 < 16; ++n4) {
      float4 bb = *(const float4*)&bsh[n4 * 4];
      h[n4 * 4 + 0] = h[n4 * 4 + 0] * a + w * bb.x;
      h[n4 * 4 + 1] = h[n4 * 4 + 1] * a + w * bb.y;
      h[n4 * 4 + 2] = h[n4 * 4 + 2] * a + w * bb.z;
      h[n4 * 4 + 3] = h[n4 * 4 + 3] * a + w * bb.w;
    }
  }
  size_t base = (((size_t)(b * NC + ch)) << 15) + (size_t)p * 64;
  #pragma unroll
  for (int n = 0; n < 64; ++n) hst[base + n] = h[n];
  if (pw == 0 && lane == 0) dts[b * NC + ch] = dsum;
}

// sequential combine across chunks, in place: hst[c] := carry-in state for chunk c
__global__ __launch_bounds__(256) void scan_combine(float* __restrict__ hst,
    const float* __restrict__ dts, const float* __restrict__ alog) {
  int idx = blockIdx.x * 256 + threadIdx.x;   // NB*512*64 = 262144 strands
  int b = idx >> 15, pn = idx & 32767;
  float A = -expf(alog[0]);
  float h = 0.f;
  for (int c = 0; c < NC; ++c) {
    size_t o = (((size_t)(b * NC + c)) << 15) + pn;
    float loc = hst[o];
    hst[o] = h;
    float dec = expf(A * dts[b * NC + c]);
    h = h * dec + loc;
  }
}

// pass2: replay chunk with true carry-in, emit y = scan_y + D*x
__global__ __launch_bounds__(64) void scan_pass2(const float* __restrict__ x,
    const float* __restrict__ Bc, const float* __restrict__ Cc,
    const float* __restrict__ dtb, const float* __restrict__ alog,
    const float* __restrict__ dpar, const float* __restrict__ hst, float* __restrict__ y) {
  int lane = threadIdx.x;
  int pw = blockIdx.x, ch = blockIdx.y, b = blockIdx.z;
  int p = pw * 64 + lane;
  float A = -expf(alog[0]);
  float dp = dpar[0];
  float h[64];
  size_t base = (((size_t)(b * NC + ch)) << 15) + (size_t)p * 64;
  #pragma unroll
  for (int n = 0; n < 64; ++n) h[n] = hst[base + n];
  __shared__ float bsh[64];
  __shared__ float csh[64];
  int t0 = ch * CL;
  for (int t = t0; t < t0 + CL; ++t) {
    size_t tl = (size_t)b * LSEQ + t;
    float dt = dtb[tl];
    float a = expf(A * dt);
    float xv = x[tl * DI + p];
    float w = dt * xv;
    __syncthreads();
    bsh[lane] = Bc[tl * DS + lane];
    csh[lane] = Cc[tl * DS + lane];
    __syncthreads();
    float yacc = 0.f;
    #pragma unroll
    for (int n4 = 0; n4 < 16; ++n4) {
      float4 bb = *(const float4*)&bsh[n4 * 4];
      float4 cc = *(const float4*)&csh[n4 * 4];
      h[n4 * 4 + 0] = h[n4 * 4 + 0] * a + w * bb.x;  yacc += h[n4 * 4 + 0] * cc.x;
      h[n4 * 4 + 1] = h[n4 * 4 + 1] * a + w * bb.y;  yacc += h[n4 * 4 + 1] * cc.y;
      h[n4 * 4 + 2] = h[n4 * 4 + 2] * a + w * bb.z;  yacc += h[n4 * 4 + 2] * cc.z;
      h[n4 * 4 + 3] = h[n4 * 4 + 3] * a + w * bb.w;  yacc += h[n4 * 4 + 3] * cc.w;
    }
    y[tl * DI + p] = yacc + dp * xv;
  }
}

// y = rmsnorm(y * silu(z)) * w   (z = zx[...,0:512]), in place
__global__ __launch_bounds__(256) void gated_rmsnorm(float* __restrict__ y,
    const float* __restrict__ zx, const float* __restrict__ w) {
  int t = blockIdx.x, tid = threadIdx.x;
  const float* zr = zx + (size_t)t * DIP;
  float* yr = y + (size_t)t * DI;
  int c0 = tid, c1 = tid + 256;
  float z0 = zr[c0], z1 = zr[c1];
  float g0 = yr[c0] * (z0 / (1.f + expf(-z0)));
  float g1 = yr[c1] * (z1 / (1.f + expf(-z1)));
  float ss = block_reduce_sum256(g0 * g0 + g1 * g1);
  float r = rsqrtf(ss * (1.f / DI) + 1e-5f);
  yr[c0] = g0 * r * w[c0];
  yr[c1] = g1 * r * w[c1];
}

// last token only: resid+=hidden, rmsnorm, logits = final @ embed[:100].T
__global__ __launch_bounds__(256) void finalize(const float* __restrict__ resid,
    const float* __restrict__ hidden, const float* __restrict__ embed,
    const float* __restrict__ nfw, float* __restrict__ out) {
  int b = blockIdx.x, tid = threadIdx.x;
  __shared__ float fin[DM];
  size_t off = ((size_t)b * LSEQ + (LSEQ - 1)) * DM;
  float r = resid[off + tid] + hidden[off + tid];
  float ss = block_reduce_sum256(r * r);
  fin[tid] = r * rsqrtf(ss * (1.f / DM) + 1e-5f) * nfw[tid];
  __syncthreads();
  if (tid < VOC) {
    float acc = 0.f;
    #pragma unroll 8
    for (int d = 0; d < DM; ++d) acc += fin[d] * embed[(size_t)tid * DM + d];
    out[b * VOC + tid] = acc;
  }
}

extern "C" void kernel_launch(void* const* d_in, const int* in_sizes, int n_in,
                              void* d_out, int out_size, void* d_ws, size_t ws_size,
                              hipStream_t stream) {
  const int*   ids   = (const int*)d_in[0];
  const float* embed = (const float*)d_in[1];
  const float* ipw   = (const float*)d_in[2];
  const float* cw    = (const float*)d_in[3];
  const float* cb    = (const float*)d_in[4];
  const float* dtbias= (const float*)d_in[5];
  const float* alog  = (const float*)d_in[6];
  const float* dpar  = (const float*)d_in[7];
  const float* ngw   = (const float*)d_in[8];
  const float* opw   = (const float*)d_in[9];
  const float* bnw   = (const float*)d_in[10];
  const float* nfw   = (const float*)d_in[11];
  float* out = (float*)d_out;

  // workspace layout (floats) — total ~50.4M floats ≈ 192 MiB
  float* ws    = (float*)d_ws;
  float* resid = ws;
  float* hidden= resid  + (size_t)TKN * DM;
  float* zx    = hidden + (size_t)TKN * DM;
  float* xb    = zx     + (size_t)TKN * DIP;
  float* Bb    = xb     + (size_t)TKN * DI;
  float* Cb    = Bb     + (size_t)TKN * DS;
  float* dtb   = Cb     + (size_t)TKN * DS;
  float* yb    = dtb    + (size_t)TKN;
  float* hst   = yb     + (size_t)TKN * DI;
  float* dts   = hst    + (size_t)NB * NC * DI * DS;

  embed_init<<<TKN, 256, 0, stream>>>(ids, embed, hidden, resid);

  for (int i = 0; i < NL; ++i) {
    add_rmsnorm<<<TKN, 256, 0, stream>>>(resid, hidden, bnw + (size_t)i * DM);
    gemm_nt<<<dim3(TKN / 64, (DIP + 63) / 64), 256, 0, stream>>>(
        hidden, ipw + (size_t)i * DIP * DM, zx, TKN, DIP, DM);
    conv_silu<<<(TKN * CDIM + 255) / 256, 256, 0, stream>>>(
        zx, cw + (size_t)i * CDIM * 4, cb + (size_t)i * CDIM, dtbias + i,
        xb, Bb, Cb, dtb);
    scan_pass1<<<dim3(DI / 64, NC, NB), 64, 0, stream>>>(xb, Bb, dtb, alog + i, hst, dts);
    scan_combine<<<(NB * DI * DS) / 256, 256, 0, stream>>>(hst, dts, alog + i);
    scan_pass2<<<dim3(DI / 64, NC, NB), 64, 0, stream>>>(xb, Bb, Cb, dtb, alog + i,
                                                         dpar + i, hst, yb);
    gated_rmsnorm<<<TKN, 256, 0, stream>>>(yb, zx, ngw + (size_t)i * DI);
    gemm_nt<<<dim3(TKN / 64, DM / 64), 256, 0, stream>>>(
        yb, opw + (size_t)i * DM * DI, hidden, TKN, DM, DI);
  }

  finalize<<<NB, 256, 0, stream>>>(resid, hidden, embed, nfw, out);
}

// Round 2
// 1509.016 us; speedup vs baseline: 1.3844x; 1.3844x over previous
//
#include <hip/hip_runtime.h>
#include <math.h>

// ---- problem constants ----
#define NB    8        // batch
#define LSEQ  2048     // seq len
#define TKN   16384    // NB*LSEQ tokens
#define DM    256      // d_model
#define DI    512      // d_inner
#define DS    64       // d_state
#define DIP   1153     // 2*DI + 2*DS + 1
#define CDIM  640      // DI + 2*DS
#define NL    4
#define NC    16       // scan chunks
#define CL    128      // LSEQ/NC
#define VOC   100

typedef short bf16x8 __attribute__((ext_vector_type(8)));
typedef float f32x4  __attribute__((ext_vector_type(4)));

__device__ __forceinline__ float block_reduce_sum256(float v) {
  __shared__ float sred[4];
  #pragma unroll
  for (int off = 32; off > 0; off >>= 1) v += __shfl_down(v, off, 64);
  int lane = threadIdx.x & 63, wid = threadIdx.x >> 6;
  if (lane == 0) sred[wid] = v;
  __syncthreads();
  return sred[0] + sred[1] + sred[2] + sred[3];
}

__device__ __forceinline__ unsigned short f2bf(float f) {
  unsigned int u = __float_as_uint(f);
  unsigned int r = u + 0x7FFFu + ((u >> 16) & 1u);   // RNE
  return (unsigned short)(r >> 16);
}

__device__ __forceinline__ bf16x8 pack8(float4 x, float4 y) {
  bf16x8 v;
  v[0] = (short)f2bf(x.x); v[1] = (short)f2bf(x.y);
  v[2] = (short)f2bf(x.z); v[3] = (short)f2bf(x.w);
  v[4] = (short)f2bf(y.x); v[5] = (short)f2bf(y.y);
  v[6] = (short)f2bf(y.z); v[7] = (short)f2bf(y.w);
  return v;
}

// hidden = embed[ids], resid = 0
__global__ __launch_bounds__(256) void embed_init(const int* __restrict__ ids,
    const float* __restrict__ embed, float* __restrict__ hidden, float* __restrict__ resid) {
  int t = blockIdx.x, tid = threadIdx.x;
  int id = ids[t];
  hidden[(size_t)t * DM + tid] = embed[(size_t)id * DM + tid];
  resid[(size_t)t * DM + tid] = 0.f;
}

// resid += hidden; hidden = rmsnorm(resid)*w
__global__ __launch_bounds__(256) void add_rmsnorm(float* __restrict__ resid,
    float* __restrict__ hidden, const float* __restrict__ w) {
  int t = blockIdx.x, tid = threadIdx.x;
  size_t o = (size_t)t * DM + tid;
  float r = resid[o] + hidden[o];
  resid[o] = r;
  float ss = block_reduce_sum256(r * r);
  hidden[o] = r * rsqrtf(ss * (1.f / DM) + 1e-5f) * w[tid];
}

// ---------------- bf16 MFMA GEMM ----------------
// C[M,N](row stride N) = A[M,K] @ Bw[N,K]^T, computed in bf16 via MFMA.
// A,Bw fp32 in global; converted to bf16 in-register during LDS staging.
// Tile 128x128, BK=32. grid = (ceil(N/128), M/128), block 256 (4 waves).
// M % 128 == 0, K % 32 == 0. N guarded.
#define LSTR 40   // LDS row stride in bf16 elems (80B: 16B-aligned, 2-way-max bank alias)

__global__ __launch_bounds__(256) void gemm_nt_mfma(const float* __restrict__ A,
    const float* __restrict__ Bw, float* __restrict__ C, int N, int K) {
  __shared__ short sA[128 * LSTR];
  __shared__ short sB[128 * LSTR];
  int tid = threadIdx.x;
  int bn = blockIdx.x * 128;
  int bm = blockIdx.y * 128;
  int wave = tid >> 6, lane = tid & 63;
  int wm = (wave >> 1) * 64, wn = (wave & 1) * 64;
  int q = lane >> 4, c = lane & 15;

  f32x4 acc[4][4];
  #pragma unroll
  for (int i = 0; i < 4; ++i)
    #pragma unroll
    for (int j = 0; j < 4; ++j) acc[i][j] = (f32x4)0.f;

  int sr = tid >> 1;            // staging row 0..127
  int sc = (tid & 1) * 16;      // k-offset 0 / 16
  const float* Ag = A  + (size_t)(bm + sr) * K + sc;
  const float* Bg = Bw + (size_t)(bn + sr) * K + sc;
  bool bok = (bn + sr) < N;
  short* sAp = &sA[sr * LSTR + sc];
  short* sBp = &sB[sr * LSTR + sc];

  for (int k0 = 0; k0 < K; k0 += 32) {
    float4 a0 = *(const float4*)(Ag + k0);
    float4 a1 = *(const float4*)(Ag + k0 + 4);
    float4 a2 = *(const float4*)(Ag + k0 + 8);
    float4 a3 = *(const float4*)(Ag + k0 + 12);
    float4 z4 = make_float4(0.f, 0.f, 0.f, 0.f);
    float4 b0 = z4, b1 = z4, b2 = z4, b3 = z4;
    if (bok) {
      b0 = *(const float4*)(Bg + k0);
      b1 = *(const float4*)(Bg + k0 + 4);
      b2 = *(const float4*)(Bg + k0 + 8);
      b3 = *(const float4*)(Bg + k0 + 12);
    }
    __syncthreads();   // previous iter's LDS reads done
    ((bf16x8*)sAp)[0] = pack8(a0, a1);
    ((bf16x8*)sAp)[1] = pack8(a2, a3);
    ((bf16x8*)sBp)[0] = pack8(b0, b1);
    ((bf16x8*)sBp)[1] = pack8(b2, b3);
    __syncthreads();
    bf16x8 af[4], bfr[4];
    #pragma unroll
    for (int i = 0; i < 4; ++i)
      af[i] = *(const bf16x8*)&sA[(wm + i * 16 + c) * LSTR + q * 8];
    #pragma unroll
    for (int j = 0; j < 4; ++j)
      bfr[j] = *(const bf16x8*)&sB[(wn + j * 16 + c) * LSTR + q * 8];
    #pragma unroll
    for (int i = 0; i < 4; ++i)
      #pragma unroll
      for (int j = 0; j < 4; ++j)
        acc[i][j] = __builtin_amdgcn_mfma_f32_16x16x32_bf16(af[i], bfr[j], acc[i][j], 0, 0, 0);
  }

  // C/D layout: col = lane&15, row = (lane>>4)*4 + reg
  #pragma unroll
  for (int i = 0; i < 4; ++i) {
    int m = bm + wm + i * 16 + q * 4;
    #pragma unroll
    for (int j = 0; j < 4; ++j) {
      int n = bn + wn + j * 16 + c;
      if (n < N) {
        #pragma unroll
        for (int r = 0; r < 4; ++r)
          C[(size_t)(m + r) * N + n] = acc[i][j][r];
      }
    }
  }
}

// depthwise causal conv(width 4)+bias+silu over zx[...,512:1152]; split into x,B,C; also dt=softplus
__global__ __launch_bounds__(256) void conv_silu(const float* __restrict__ zx,
    const float* __restrict__ cw, const float* __restrict__ cb,
    const float* __restrict__ dtbias, float* __restrict__ xo,
    float* __restrict__ Bo, float* __restrict__ Co, float* __restrict__ dto) {
  int idx = blockIdx.x * 256 + threadIdx.x;
  if (idx >= TKN * CDIM) return;
  int c = idx % CDIM;
  int tl = idx / CDIM;          // b*LSEQ + l
  int l = tl & (LSEQ - 1);
  float s = cb[c];
  #pragma unroll
  for (int k = 0; k < 4; ++k) {
    int ls = l - 3 + k;
    if (ls >= 0) s += cw[(c << 2) + k] * zx[(size_t)(tl - 3 + k) * DIP + DI + c];
  }
  float v = s / (1.f + expf(-s));
  if (c < DI)            xo[(size_t)tl * DI + c] = v;
  else if (c < DI + DS)  Bo[(size_t)tl * DS + (c - DI)] = v;
  else                   Co[(size_t)tl * DS + (c - DI - DS)] = v;
  if (c == 0) {
    float xr = zx[(size_t)tl * DIP + (DIP - 1)] + dtbias[0];
    dto[tl] = (xr > 20.f) ? xr : log1pf(expf(xr));
  }
}

// pass1: per-chunk local end state (h_in = 0). grid (DI/64, NC, NB), block 64.
__global__ __launch_bounds__(64) void scan_pass1(const float* __restrict__ x,
    const float* __restrict__ Bc, const float* __restrict__ dtb,
    const float* __restrict__ alog, float* __restrict__ hst, float* __restrict__ dts) {
  int lane = threadIdx.x;
  int pw = blockIdx.x, ch = blockIdx.y, b = blockIdx.z;
  int p = pw * 64 + lane;
  float A = -expf(alog[0]);
  float h[64];
  #pragma unroll
  for (int n = 0; n < 64; ++n) h[n] = 0.f;
  __shared__ float bsh[64];
  float dsum = 0.f;
  int t0 = ch * CL;
  for (int t = t0; t < t0 + CL; ++t) {
    size_t tl = (size_t)b * LSEQ + t;
    float dt = dtb[tl];
    dsum += dt;
    float a = expf(A * dt);
    float w = dt * x[tl * DI + p];
    __syncthreads();
    bsh[lane] = Bc[tl * DS + lane];
    __syncthreads();
    #pragma unroll
    for (int n4 = 0; n4 < 16; ++n4) {
      float4 bb = *(const float4*)&bsh[n4 * 4];
      h[n4 * 4 + 0] = h[n4 * 4 + 0] * a + w * bb.x;
      h[n4 * 4 + 1] = h[n4 * 4 + 1] * a + w * bb.y;
      h[n4 * 4 + 2] = h[n4 * 4 + 2] * a + w * bb.z;
      h[n4 * 4 + 3] = h[n4 * 4 + 3] * a + w * bb.w;
    }
  }
  size_t base = (((size_t)(b * NC + ch)) << 15) + (size_t)p * 64;
  #pragma unroll
  for (int n = 0; n < 64; ++n) hst[base + n] = h[n];
  if (pw == 0 && lane == 0) dts[b * NC + ch] = dsum;
}

// sequential combine across chunks, in place: hst[c] := carry-in state for chunk c
__global__ __launch_bounds__(256) void scan_combine(float* __restrict__ hst,
    const float* __restrict__ dts, const float* __restrict__ alog) {
  int idx = blockIdx.x * 256 + threadIdx.x;   // NB*512*64 = 262144 strands
  int b = idx >> 15, pn = idx & 32767;
  float A = -expf(alog[0]);
  float h = 0.f;
  for (int c = 0; c < NC; ++c) {
    size_t o = (((size_t)(b * NC + c)) << 15) + pn;
    float loc = hst[o];
    hst[o] = h;
    float dec = expf(A * dts[b * NC + c]);
    h = h * dec + loc;
  }
}

// pass2: replay chunk with true carry-in, emit y = scan_y + D*x
__global__ __launch_bounds__(64) void scan_pass2(const float* __restrict__ x,
    const float* __restrict__ Bc, const float* __restrict__ Cc,
    const float* __restrict__ dtb, const float* __restrict__ alog,
    const float* __restrict__ dpar, const float* __restrict__ hst, float* __restrict__ y) {
  int lane = threadIdx.x;
  int pw = blockIdx.x, ch = blockIdx.y, b = blockIdx.z;
  int p = pw * 64 + lane;
  float A = -expf(alog[0]);
  float dp = dpar[0];
  float h[64];
  size_t base = (((size_t)(b * NC + ch)) << 15) + (size_t)p * 64;
  #pragma unroll
  for (int n = 0; n < 64; ++n) h[n] = hst[base + n];
  __shared__ float bsh[64];
  __shared__ float csh[64];
  int t0 = ch * CL;
  for (int t = t0; t < t0 + CL; ++t) {
    size_t tl = (size_t)b * LSEQ + t;
    float dt = dtb[tl];
    float a = expf(A * dt);
    float xv = x[tl * DI + p];
    float w = dt * xv;
    __syncthreads();
    bsh[lane] = Bc[tl * DS + lane];
    csh[lane] = Cc[tl * DS + lane];
    __syncthreads();
    float yacc = 0.f;
    #pragma unroll
    for (int n4 = 0; n4 < 16; ++n4) {
      float4 bb = *(const float4*)&bsh[n4 * 4];
      float4 cc = *(const float4*)&csh[n4 * 4];
      h[n4 * 4 + 0] = h[n4 * 4 + 0] * a + w * bb.x;  yacc += h[n4 * 4 + 0] * cc.x;
      h[n4 * 4 + 1] = h[n4 * 4 + 1] * a + w * bb.y;  yacc += h[n4 * 4 + 1] * cc.y;
      h[n4 * 4 + 2] = h[n4 * 4 + 2] * a + w * bb.z;  yacc += h[n4 * 4 + 2] * cc.z;
      h[n4 * 4 + 3] = h[n4 * 4 + 3] * a + w * bb.w;  yacc += h[n4 * 4 + 3] * cc.w;
    }
    y[tl * DI + p] = yacc + dp * xv;
  }
}

// y = rmsnorm(y * silu(z)) * w   (z = zx[...,0:512]), in place
__global__ __launch_bounds__(256) void gated_rmsnorm(float* __restrict__ y,
    const float* __restrict__ zx, const float* __restrict__ w) {
  int t = blockIdx.x, tid = threadIdx.x;
  const float* zr = zx + (size_t)t * DIP;
  float* yr = y + (size_t)t * DI;
  int c0 = tid, c1 = tid + 256;
  float z0 = zr[c0], z1 = zr[c1];
  float g0 = yr[c0] * (z0 / (1.f + expf(-z0)));
  float g1 = yr[c1] * (z1 / (1.f + expf(-z1)));
  float ss = block_reduce_sum256(g0 * g0 + g1 * g1);
  float r = rsqrtf(ss * (1.f / DI) + 1e-5f);
  yr[c0] = g0 * r * w[c0];
  yr[c1] = g1 * r * w[c1];
}

// last token only: resid+=hidden, rmsnorm, logits = final @ embed[:100].T
__global__ __launch_bounds__(256) void finalize(const float* __restrict__ resid,
    const float* __restrict__ hidden, const float* __restrict__ embed,
    const float* __restrict__ nfw, float* __restrict__ out) {
  int b = blockIdx.x, tid = threadIdx.x;
  __shared__ float fin[DM];
  size_t off = ((size_t)b * LSEQ + (LSEQ - 1)) * DM;
  float r = resid[off + tid] + hidden[off + tid];
  float ss = block_reduce_sum256(r * r);
  fin[tid] = r * rsqrtf(ss * (1.f / DM) + 1e-5f) * nfw[tid];
  __syncthreads();
  if (tid < VOC) {
    float acc = 0.f;
    #pragma unroll 8
    for (int d = 0; d < DM; ++d) acc += fin[d] * embed[(size_t)tid * DM + d];
    out[b * VOC + tid] = acc;
  }
}

extern "C" void kernel_launch(void* const* d_in, const int* in_sizes, int n_in,
                              void* d_out, int out_size, void* d_ws, size_t ws_size,
                              hipStream_t stream) {
  const int*   ids   = (const int*)d_in[0];
  const float* embed = (const float*)d_in[1];
  const float* ipw   = (const float*)d_in[2];
  const float* cw    = (const float*)d_in[3];
  const float* cb    = (const float*)d_in[4];
  const float* dtbias= (const float*)d_in[5];
  const float* alog  = (const float*)d_in[6];
  const float* dpar  = (const float*)d_in[7];
  const float* ngw   = (const float*)d_in[8];
  const float* opw   = (const float*)d_in[9];
  const float* bnw   = (const float*)d_in[10];
  const float* nfw   = (const float*)d_in[11];
  float* out = (float*)d_out;

  // workspace layout (floats) — same as round 1, ~50.4M floats
  float* ws    = (float*)d_ws;
  float* resid = ws;
  float* hidden= resid  + (size_t)TKN * DM;
  float* zx    = hidden + (size_t)TKN * DM;
  float* xb    = zx     + (size_t)TKN * DIP;
  float* Bb    = xb     + (size_t)TKN * DI;
  float* Cb    = Bb     + (size_t)TKN * DS;
  float* dtb   = Cb     + (size_t)TKN * DS;
  float* yb    = dtb    + (size_t)TKN;
  float* hst   = yb     + (size_t)TKN * DI;
  float* dts   = hst    + (size_t)NB * NC * DI * DS;

  embed_init<<<TKN, 256, 0, stream>>>(ids, embed, hidden, resid);

  for (int i = 0; i < NL; ++i) {
    add_rmsnorm<<<TKN, 256, 0, stream>>>(resid, hidden, bnw + (size_t)i * DM);
    gemm_nt_mfma<<<dim3((DIP + 127) / 128, TKN / 128), 256, 0, stream>>>(
        hidden, ipw + (size_t)i * DIP * DM, zx, DIP, DM);
    conv_silu<<<(TKN * CDIM + 255) / 256, 256, 0, stream>>>(
        zx, cw + (size_t)i * CDIM * 4, cb + (size_t)i * CDIM, dtbias + i,
        xb, Bb, Cb, dtb);
    scan_pass1<<<dim3(DI / 64, NC, NB), 64, 0, stream>>>(xb, Bb, dtb, alog + i, hst, dts);
    scan_combine<<<(NB * DI * DS) / 256, 256, 0, stream>>>(hst, dts, alog + i);
    scan_pass2<<<dim3(DI / 64, NC, NB), 64, 0, stream>>>(xb, Bb, Cb, dtb, alog + i,
                                                         dpar + i, hst, yb);
    gated_rmsnorm<<<TKN, 256, 0, stream>>>(yb, zx, ngw + (size_t)i * DI);
    gemm_nt_mfma<<<dim3(DM / 128, TKN / 128), 256, 0, stream>>>(
        yb, opw + (size_t)i * DM * DI, hidden, DM, DI);
  }

  finalize<<<NB, 256, 0, stream>>>(resid, hidden, embed, nfw, out);
}

// Round 3
// 995.620 us; speedup vs baseline: 2.0983x; 1.5157x over previous
//
#include <hip/hip_runtime.h>
#include <math.h>

// ---- problem constants ----
#define NB    8        // batch
#define LSEQ  2048     // seq len
#define TKN   16384    // NB*LSEQ tokens
#define DM    256      // d_model
#define DI    512      // d_inner
#define DS    64       // d_state
#define DIP   1153     // 2*DI + 2*DS + 1
#define CDIM  640      // DI + 2*DS
#define NL    4
#define NC    16       // scan chunks
#define CL    128      // LSEQ/NC
#define VOC   100

typedef short bf16x8 __attribute__((ext_vector_type(8)));
typedef float f32x4  __attribute__((ext_vector_type(4)));

__device__ __forceinline__ float block_reduce_sum256(float v) {
  __shared__ float sred[4];
  #pragma unroll
  for (int off = 32; off > 0; off >>= 1) v += __shfl_down(v, off, 64);
  int lane = threadIdx.x & 63, wid = threadIdx.x >> 6;
  if (lane == 0) sred[wid] = v;
  __syncthreads();
  return sred[0] + sred[1] + sred[2] + sred[3];
}

__device__ __forceinline__ unsigned short f2bf(float f) {
  unsigned int u = __float_as_uint(f);
  unsigned int r = u + 0x7FFFu + ((u >> 16) & 1u);   // RNE
  return (unsigned short)(r >> 16);
}
__device__ __forceinline__ float bf2f(unsigned short u) {
  return __uint_as_float(((unsigned int)u) << 16);
}

__device__ __forceinline__ bf16x8 pack8(float4 x, float4 y) {
  bf16x8 v;
  v[0] = (short)f2bf(x.x); v[1] = (short)f2bf(x.y);
  v[2] = (short)f2bf(x.z); v[3] = (short)f2bf(x.w);
  v[4] = (short)f2bf(y.x); v[5] = (short)f2bf(y.y);
  v[6] = (short)f2bf(y.z); v[7] = (short)f2bf(y.w);
  return v;
}

// hidden = embed[ids], resid = 0
__global__ __launch_bounds__(256) void embed_init(const int* __restrict__ ids,
    const float* __restrict__ embed, float* __restrict__ hidden, float* __restrict__ resid) {
  int t = blockIdx.x, tid = threadIdx.x;
  int id = ids[t];
  hidden[(size_t)t * DM + tid] = embed[(size_t)id * DM + tid];
  resid[(size_t)t * DM + tid] = 0.f;
}

// resid += hidden; hidden = rmsnorm(resid)*w
__global__ __launch_bounds__(256) void add_rmsnorm(float* __restrict__ resid,
    float* __restrict__ hidden, const float* __restrict__ w) {
  int t = blockIdx.x, tid = threadIdx.x;
  size_t o = (size_t)t * DM + tid;
  float r = resid[o] + hidden[o];
  resid[o] = r;
  float ss = block_reduce_sum256(r * r);
  hidden[o] = r * rsqrtf(ss * (1.f / DM) + 1e-5f) * w[tid];
}

// ---------------- bf16 MFMA GEMM (unchanged from round 2) ----------------
#define LSTR 40
__global__ __launch_bounds__(256) void gemm_nt_mfma(const float* __restrict__ A,
    const float* __restrict__ Bw, float* __restrict__ C, int N, int K) {
  __shared__ short sA[128 * LSTR];
  __shared__ short sB[128 * LSTR];
  int tid = threadIdx.x;
  int bn = blockIdx.x * 128;
  int bm = blockIdx.y * 128;
  int wave = tid >> 6, lane = tid & 63;
  int wm = (wave >> 1) * 64, wn = (wave & 1) * 64;
  int q = lane >> 4, c = lane & 15;

  f32x4 acc[4][4];
  #pragma unroll
  for (int i = 0; i < 4; ++i)
    #pragma unroll
    for (int j = 0; j < 4; ++j) acc[i][j] = (f32x4)0.f;

  int sr = tid >> 1;
  int sc = (tid & 1) * 16;
  const float* Ag = A  + (size_t)(bm + sr) * K + sc;
  const float* Bg = Bw + (size_t)(bn + sr) * K + sc;
  bool bok = (bn + sr) < N;
  short* sAp = &sA[sr * LSTR + sc];
  short* sBp = &sB[sr * LSTR + sc];

  for (int k0 = 0; k0 < K; k0 += 32) {
    float4 a0 = *(const float4*)(Ag + k0);
    float4 a1 = *(const float4*)(Ag + k0 + 4);
    float4 a2 = *(const float4*)(Ag + k0 + 8);
    float4 a3 = *(const float4*)(Ag + k0 + 12);
    float4 z4 = make_float4(0.f, 0.f, 0.f, 0.f);
    float4 b0 = z4, b1 = z4, b2 = z4, b3 = z4;
    if (bok) {
      b0 = *(const float4*)(Bg + k0);
      b1 = *(const float4*)(Bg + k0 + 4);
      b2 = *(const float4*)(Bg + k0 + 8);
      b3 = *(const float4*)(Bg + k0 + 12);
    }
    __syncthreads();
    ((bf16x8*)sAp)[0] = pack8(a0, a1);
    ((bf16x8*)sAp)[1] = pack8(a2, a3);
    ((bf16x8*)sBp)[0] = pack8(b0, b1);
    ((bf16x8*)sBp)[1] = pack8(b2, b3);
    __syncthreads();
    bf16x8 af[4], bfr[4];
    #pragma unroll
    for (int i = 0; i < 4; ++i)
      af[i] = *(const bf16x8*)&sA[(wm + i * 16 + c) * LSTR + q * 8];
    #pragma unroll
    for (int j = 0; j < 4; ++j)
      bfr[j] = *(const bf16x8*)&sB[(wn + j * 16 + c) * LSTR + q * 8];
    #pragma unroll
    for (int i = 0; i < 4; ++i)
      #pragma unroll
      for (int j = 0; j < 4; ++j)
        acc[i][j] = __builtin_amdgcn_mfma_f32_16x16x32_bf16(af[i], bfr[j], acc[i][j], 0, 0, 0);
  }
  #pragma unroll
  for (int i = 0; i < 4; ++i) {
    int m = bm + wm + i * 16 + q * 4;
    #pragma unroll
    for (int j = 0; j < 4; ++j) {
      int n = bn + wn + j * 16 + c;
      if (n < N) {
        #pragma unroll
        for (int r = 0; r < 4; ++r)
          C[(size_t)(m + r) * N + n] = acc[i][j][r];
      }
    }
  }
}

// conv+bias+silu; x -> fp32, B/C -> bf16, dt -> softplus fp32
__global__ __launch_bounds__(256) void conv_silu(const float* __restrict__ zx,
    const float* __restrict__ cw, const float* __restrict__ cb,
    const float* __restrict__ dtbias, float* __restrict__ xo,
    unsigned short* __restrict__ Bo, unsigned short* __restrict__ Co,
    float* __restrict__ dto) {
  int idx = blockIdx.x * 256 + threadIdx.x;
  if (idx >= TKN * CDIM) return;
  int c = idx % CDIM;
  int tl = idx / CDIM;
  int l = tl & (LSEQ - 1);
  float s = cb[c];
  #pragma unroll
  for (int k = 0; k < 4; ++k) {
    int ls = l - 3 + k;
    if (ls >= 0) s += cw[(c << 2) + k] * zx[(size_t)(tl - 3 + k) * DIP + DI + c];
  }
  float v = s / (1.f + expf(-s));
  if (c < DI)            xo[(size_t)tl * DI + c] = v;
  else if (c < DI + DS)  Bo[(size_t)tl * DS + (c - DI)] = f2bf(v);
  else                   Co[(size_t)tl * DS + (c - DI - DS)] = f2bf(v);
  if (c == 0) {
    float xr = zx[(size_t)tl * DIP + (DIP - 1)] + dtbias[0];
    dto[tl] = (xr > 20.f) ? xr : log1pf(expf(xr));
  }
}

// per-chunk inclusive prefix sum of dt. one wave per chunk (128 steps, 2/lane).
__global__ __launch_bounds__(256) void csum_k(const float* __restrict__ dtb,
    float* __restrict__ csumb) {
  int tid = threadIdx.x;
  int wave = tid >> 6, lane = tid & 63;
  int cg = blockIdx.x * 4 + wave;          // global chunk 0..127
  int b = cg >> 4, ch = cg & 15;
  size_t base = (size_t)b * LSEQ + ch * CL;
  float d0 = dtb[base + 2 * lane];
  float d1 = dtb[base + 2 * lane + 1];
  float p = d0 + d1;
  #pragma unroll
  for (int off = 1; off < 64; off <<= 1) {
    float t = __shfl_up(p, off, 64);
    if (lane >= off) p += t;
  }
  // p = inclusive scan of pair sums
  csumb[base + 2 * lane]     = p - d1;
  csumb[base + 2 * lane + 1] = p;
}

// Ut[b][p][s_global] bf16 = dt[s]*x[s][p]  (transpose). block: 64s x 64p tile.
__global__ __launch_bounds__(256) void transpose_u(const float* __restrict__ xb,
    const float* __restrict__ dtb, unsigned short* __restrict__ Ut) {
  __shared__ unsigned short tile[64 * 65];
  int tid = threadIdx.x;
  int pt = blockIdx.x, st = blockIdx.y, b = blockIdx.z;
  int s0 = st * 64, p0 = pt * 64;
  #pragma unroll
  for (int i = 0; i < 16; ++i) {
    int sl = (tid >> 6) * 16 + i;
    int pl = tid & 63;
    float dt = dtb[(size_t)b * LSEQ + s0 + sl];
    float v = xb[((size_t)b * LSEQ + s0 + sl) * DI + p0 + pl] * dt;
    tile[pl * 65 + sl] = f2bf(v);
  }
  __syncthreads();
  #pragma unroll
  for (int i = 0; i < 16; ++i) {
    int op = (tid >> 6) * 16 + i;
    int os = tid & 63;
    Ut[((size_t)b * DI + p0 + op) * LSEQ + s0 + os] = tile[op * 65 + os];
  }
}

// state GEMM: Hloc[bc][n][p] = sum_s exp(A(S - cs[s])) * B[s][n] * U[s][p]
// grid (2, NC, NB), block 256. M=64(n), N=256(p), K=128(s).
__global__ __launch_bounds__(256) void state_gemm(const unsigned short* __restrict__ Bb,
    const unsigned short* __restrict__ Ut, const float* __restrict__ csumb,
    const float* __restrict__ alog, float* __restrict__ hst) {
  __shared__ short sW[64 * 144];
  __shared__ short sX[256 * 40];
  __shared__ float scs[128];
  int tid = threadIdx.x;
  int ph = blockIdx.x, ch = blockIdx.y, b = blockIdx.z;
  int bc = b * NC + ch;
  size_t tb = (size_t)b * LSEQ + ch * CL;     // token base of chunk
  float Aval = -__expf(alog[0] * 1.44269504f) ; // placeholder replaced below
  Aval = -expf(alog[0]);
  if (tid < 128) scs[tid] = csumb[tb + tid];
  __syncthreads();
  float Stot = scs[127];
  // build W[n][s] = exp(A*(Stot-cs[s])) * B[s][n], transposed store
  {
    int s = tid >> 1, noff = (tid & 1) * 32;
    float scale = __expf(Aval * (Stot - scs[s]));
    bf16x8 v0 = *(const bf16x8*)&Bb[(tb + s) * DS + noff];
    bf16x8 v1 = *(const bf16x8*)&Bb[(tb + s) * DS + noff + 8];
    #pragma unroll
    for (int e = 0; e < 8; ++e) {
      sW[(noff + e) * 144 + s]     = (short)f2bf(bf2f((unsigned short)v0[e]) * scale);
      sW[(noff + 8 + e) * 144 + s] = (short)f2bf(bf2f((unsigned short)v1[e]) * scale);
    }
    // second half (16..31 of the 32-block)
    bf16x8 v2 = *(const bf16x8*)&Bb[(tb + s) * DS + noff + 16];
    bf16x8 v3 = *(const bf16x8*)&Bb[(tb + s) * DS + noff + 24];
    #pragma unroll
    for (int e = 0; e < 8; ++e) {
      sW[(noff + 16 + e) * 144 + s] = (short)f2bf(bf2f((unsigned short)v2[e]) * scale);
      sW[(noff + 24 + e) * 144 + s] = (short)f2bf(bf2f((unsigned short)v3[e]) * scale);
    }
  }
  int wave = tid >> 6, lane = tid & 63;
  int wp = wave * 64;
  int q = lane >> 4, c = lane & 15;
  f32x4 acc[4][4];
  #pragma unroll
  for (int i = 0; i < 4; ++i)
    #pragma unroll
    for (int j = 0; j < 4; ++j) acc[i][j] = (f32x4)0.f;

  for (int ks = 0; ks < 4; ++ks) {
    __syncthreads();
    // stage U^T slice: sX[p 0..255][k 0..31]
    {
      size_t ua = ((size_t)b * DI + ph * 256 + tid) * LSEQ + ch * CL + ks * 32;
      bf16x8 u0 = *(const bf16x8*)&Ut[ua];
      bf16x8 u1 = *(const bf16x8*)&Ut[ua + 8];
      bf16x8 u2 = *(const bf16x8*)&Ut[ua + 16];
      bf16x8 u3 = *(const bf16x8*)&Ut[ua + 24];
      ((bf16x8*)&sX[tid * 40])[0] = u0;
      *(bf16x8*)&sX[tid * 40 + 8]  = u1;
      *(bf16x8*)&sX[tid * 40 + 16] = u2;
      *(bf16x8*)&sX[tid * 40 + 24] = u3;
    }
    __syncthreads();
    bf16x8 af[4], bfr[4];
    #pragma unroll
    for (int i = 0; i < 4; ++i)
      af[i] = *(const bf16x8*)&sW[(i * 16 + c) * 144 + ks * 32 + q * 8];
    #pragma unroll
    for (int j = 0; j < 4; ++j)
      bfr[j] = *(const bf16x8*)&sX[(wp + j * 16 + c) * 40 + q * 8];
    #pragma unroll
    for (int i = 0; i < 4; ++i)
      #pragma unroll
      for (int j = 0; j < 4; ++j)
        acc[i][j] = __builtin_amdgcn_mfma_f32_16x16x32_bf16(af[i], bfr[j], acc[i][j], 0, 0, 0);
  }
  // write Hloc[n][p] coalesced
  #pragma unroll
  for (int i = 0; i < 4; ++i) {
    int n = i * 16 + q * 4;
    #pragma unroll
    for (int j = 0; j < 4; ++j) {
      int pg = ph * 256 + wp + j * 16 + c;
      #pragma unroll
      for (int r = 0; r < 4; ++r)
        hst[((size_t)bc * DS + n + r) * DI + pg] = acc[i][j][r];
    }
  }
}

// combine: sequential over chunks; outputs carry-in states hin_t[bc][p][n] bf16
// grid (8 p-tiles, NB), block 256.
__global__ __launch_bounds__(256) void combine2(const float* __restrict__ hst,
    const float* __restrict__ csumb, const float* __restrict__ alog,
    unsigned short* __restrict__ hin) {
  __shared__ unsigned short ts[64 * 65];
  int tid = threadIdx.x;
  int pt = blockIdx.x, b = blockIdx.y;
  int p0 = pt * 64;
  int pl = tid & 63, ng = tid >> 6;   // thread strands: p = p0+pl, n = ng*16+i
  float Aval = -expf(alog[0]);
  float h[16];
  #pragma unroll
  for (int i = 0; i < 16; ++i) h[i] = 0.f;
  for (int c = 0; c < NC; ++c) {
    int bc = b * NC + c;
    // write carry-in (pre-update) transposed to hin[bc][p][n]
    #pragma unroll
    for (int i = 0; i < 16; ++i)
      ts[pl * 65 + ng * 16 + i] = f2bf(h[i]);
    __syncthreads();
    {
      int on = tid & 63;
      #pragma unroll
      for (int i = 0; i < 16; ++i) {
        int op = (tid >> 6) * 16 + i;
        hin[((size_t)bc * DI + p0 + op) * DS + on] = ts[op * 65 + on];
      }
    }
    __syncthreads();
    // update h with this chunk's local state
    float Sc = csumb[(size_t)b * LSEQ + c * CL + CL - 1];
    float dec = __expf(Aval * Sc);
    #pragma unroll
    for (int i = 0; i < 16; ++i) {
      float loc = hst[((size_t)bc * DS + ng * 16 + i) * DI + p0 + pl];
      h[i] = h[i] * dec + loc;
    }
  }
}

// y GEMM: per (b,ch,phalf): G=C@B^T -> M masked-decayed -> Y = M@U + Chat@Hin; y += dp*x
// grid (2, NC, NB), block 256.
__global__ __launch_bounds__(256) void y_gemm(const unsigned short* __restrict__ Bb,
    const unsigned short* __restrict__ Cb, const unsigned short* __restrict__ Ut,
    const unsigned short* __restrict__ hin, const float* __restrict__ csumb,
    const float* __restrict__ alog, const float* __restrict__ dpar,
    const float* __restrict__ xb, float* __restrict__ y) {
  __shared__ short sC[128 * 72];
  __shared__ short sBX[256 * 40];   // phase1: B[s][n] (str 80); phase2: U^T/Hin slices (str 40)
  __shared__ short sM[128 * 136];   // phase2 ks0-3: M[t][s] str 136; ks4-5: Chat[t][n] str 80
  __shared__ float scs[128];
  int tid = threadIdx.x;
  int ph = blockIdx.x, ch = blockIdx.y, b = blockIdx.z;
  int bc = b * NC + ch;
  size_t tb = (size_t)b * LSEQ + ch * CL;
  float Aval = -expf(alog[0]);
  float dp = dpar[0];
  int wave = tid >> 6, lane = tid & 63;
  int q = lane >> 4, c = lane & 15;

  // stage C (str 72), B (str 80), csum
  {
    int r = tid >> 1, off = (tid & 1) * 32;
    *(bf16x8*)&sC[r * 72 + off]      = *(const bf16x8*)&Cb[(tb + r) * DS + off];
    *(bf16x8*)&sC[r * 72 + off + 8]  = *(const bf16x8*)&Cb[(tb + r) * DS + off + 8];
    *(bf16x8*)&sC[r * 72 + off + 16] = *(const bf16x8*)&Cb[(tb + r) * DS + off + 16];
    *(bf16x8*)&sC[r * 72 + off + 24] = *(const bf16x8*)&Cb[(tb + r) * DS + off + 24];
    *(bf16x8*)&sBX[r * 80 + off]      = *(const bf16x8*)&Bb[(tb + r) * DS + off];
    *(bf16x8*)&sBX[r * 80 + off + 8]  = *(const bf16x8*)&Bb[(tb + r) * DS + off + 8];
    *(bf16x8*)&sBX[r * 80 + off + 16] = *(const bf16x8*)&Bb[(tb + r) * DS + off + 16];
    *(bf16x8*)&sBX[r * 80 + off + 24] = *(const bf16x8*)&Bb[(tb + r) * DS + off + 24];
  }
  if (tid < 128) scs[tid] = csumb[tb + tid];
  __syncthreads();

  // ---- phase 1: G = C @ B^T (M=128 t, N=128 s, K=64 n) ----
  {
    int wm = (wave >> 1) * 64, ws = (wave & 1) * 64;
    f32x4 g[4][4];
    #pragma unroll
    for (int i = 0; i < 4; ++i)
      #pragma unroll
      for (int j = 0; j < 4; ++j) g[i][j] = (f32x4)0.f;
    #pragma unroll
    for (int k0 = 0; k0 < 64; k0 += 32) {
      bf16x8 af[4], bfr[4];
      #pragma unroll
      for (int i = 0; i < 4; ++i)
        af[i] = *(const bf16x8*)&sC[(wm + i * 16 + c) * 72 + k0 + q * 8];
      #pragma unroll
      for (int j = 0; j < 4; ++j)
        bfr[j] = *(const bf16x8*)&sBX[(ws + j * 16 + c) * 80 + k0 + q * 8];
      #pragma unroll
      for (int i = 0; i < 4; ++i)
        #pragma unroll
        for (int j = 0; j < 4; ++j)
          g[i][j] = __builtin_amdgcn_mfma_f32_16x16x32_bf16(af[i], bfr[j], g[i][j], 0, 0, 0);
    }
    // mask + decay + store M bf16
    #pragma unroll
    for (int i = 0; i < 4; ++i) {
      #pragma unroll
      for (int r = 0; r < 4; ++r) {
        int t = wm + i * 16 + q * 4 + r;
        float ct = scs[t];
        #pragma unroll
        for (int j = 0; j < 4; ++j) {
          int s = ws + j * 16 + c;
          float v = g[i][j][r];
          float m = (s <= t) ? v * __expf(Aval * (ct - scs[s])) : 0.f;
          sM[t * 136 + s] = (short)f2bf(m);
        }
      }
    }
  }

  // ---- phase 2: Y = M @ U^T' + Chat @ Hin ----
  int wm2 = (wave >> 1) * 64, wp = (wave & 1) * 128;
  f32x4 acc[4][8];
  #pragma unroll
  for (int i = 0; i < 4; ++i)
    #pragma unroll
    for (int j = 0; j < 8; ++j) acc[i][j] = (f32x4)0.f;

  for (int ks = 0; ks < 4; ++ks) {
    __syncthreads();   // covers M-writes (ks=0) and prior sBX reads
    {
      size_t ua = ((size_t)b * DI + ph * 256 + tid) * LSEQ + ch * CL + ks * 32;
      bf16x8 u0 = *(const bf16x8*)&Ut[ua];
      bf16x8 u1 = *(const bf16x8*)&Ut[ua + 8];
      bf16x8 u2 = *(const bf16x8*)&Ut[ua + 16];
      bf16x8 u3 = *(const bf16x8*)&Ut[ua + 24];
      *(bf16x8*)&sBX[tid * 40]      = u0;
      *(bf16x8*)&sBX[tid * 40 + 8]  = u1;
      *(bf16x8*)&sBX[tid * 40 + 16] = u2;
      *(bf16x8*)&sBX[tid * 40 + 24] = u3;
    }
    __syncthreads();
    bf16x8 af[4], bfr[8];
    #pragma unroll
    for (int i = 0; i < 4; ++i)
      af[i] = *(const bf16x8*)&sM[(wm2 + i * 16 + c) * 136 + ks * 32 + q * 8];
    #pragma unroll
    for (int j = 0; j < 8; ++j)
      bfr[j] = *(const bf16x8*)&sBX[(wp + j * 16 + c) * 40 + q * 8];
    #pragma unroll
    for (int i = 0; i < 4; ++i)
      #pragma unroll
      for (int j = 0; j < 8; ++j)
        acc[i][j] = __builtin_amdgcn_mfma_f32_16x16x32_bf16(af[i], bfr[j], acc[i][j], 0, 0, 0);
  }

  // build Chat[t][n] = exp(A*cs[t]) * C[t][n] into sM (str 80)
  __syncthreads();
  {
    int r = tid >> 1, off = (tid & 1) * 32;
    float sc_t = __expf(Aval * scs[r]);
    #pragma unroll
    for (int blk = 0; blk < 4; ++blk) {
      bf16x8 v = *(const bf16x8*)&sC[r * 72 + off + blk * 8];
      bf16x8 o;
      #pragma unroll
      for (int e = 0; e < 8; ++e)
        o[e] = (short)f2bf(bf2f((unsigned short)v[e]) * sc_t);
      *(bf16x8*)&sM[r * 80 + off + blk * 8] = o;
    }
  }
  for (int ks = 4; ks < 6; ++ks) {
    __syncthreads();
    {
      size_t ha = ((size_t)bc * DI + ph * 256 + tid) * DS + (ks - 4) * 32;
      bf16x8 h0 = *(const bf16x8*)&hin[ha];
      bf16x8 h1 = *(const bf16x8*)&hin[ha + 8];
      bf16x8 h2 = *(const bf16x8*)&hin[ha + 16];
      bf16x8 h3 = *(const bf16x8*)&hin[ha + 24];
      *(bf16x8*)&sBX[tid * 40]      = h0;
      *(bf16x8*)&sBX[tid * 40 + 8]  = h1;
      *(bf16x8*)&sBX[tid * 40 + 16] = h2;
      *(bf16x8*)&sBX[tid * 40 + 24] = h3;
    }
    __syncthreads();
    bf16x8 af[4], bfr[8];
    #pragma unroll
    for (int i = 0; i < 4; ++i)
      af[i] = *(const bf16x8*)&sM[(wm2 + i * 16 + c) * 80 + (ks - 4) * 32 + q * 8];
    #pragma unroll
    for (int j = 0; j < 8; ++j)
      bfr[j] = *(const bf16x8*)&sBX[(wp + j * 16 + c) * 40 + q * 8];
    #pragma unroll
    for (int i = 0; i < 4; ++i)
      #pragma unroll
      for (int j = 0; j < 8; ++j)
        acc[i][j] = __builtin_amdgcn_mfma_f32_16x16x32_bf16(af[i], bfr[j], acc[i][j], 0, 0, 0);
  }

  // epilogue: y = acc + dp * x
  #pragma unroll
  for (int i = 0; i < 4; ++i) {
    #pragma unroll
    for (int r = 0; r < 4; ++r) {
      int t = wm2 + i * 16 + q * 4 + r;
      size_t row = (tb + t) * DI;
      #pragma unroll
      for (int j = 0; j < 8; ++j) {
        int pg = ph * 256 + wp + j * 16 + c;
        y[row + pg] = acc[i][j][r] + dp * xb[row + pg];
      }
    }
  }
}

// y = rmsnorm(y * silu(z)) * w   (z = zx[...,0:512]), in place
__global__ __launch_bounds__(256) void gated_rmsnorm(float* __restrict__ y,
    const float* __restrict__ zx, const float* __restrict__ w) {
  int t = blockIdx.x, tid = threadIdx.x;
  const float* zr = zx + (size_t)t * DIP;
  float* yr = y + (size_t)t * DI;
  int c0 = tid, c1 = tid + 256;
  float z0 = zr[c0], z1 = zr[c1];
  float g0 = yr[c0] * (z0 / (1.f + expf(-z0)));
  float g1 = yr[c1] * (z1 / (1.f + expf(-z1)));
  float ss = block_reduce_sum256(g0 * g0 + g1 * g1);
  float r = rsqrtf(ss * (1.f / DI) + 1e-5f);
  yr[c0] = g0 * r * w[c0];
  yr[c1] = g1 * r * w[c1];
}

// last token only
__global__ __launch_bounds__(256) void finalize(const float* __restrict__ resid,
    const float* __restrict__ hidden, const float* __restrict__ embed,
    const float* __restrict__ nfw, float* __restrict__ out) {
  int b = blockIdx.x, tid = threadIdx.x;
  __shared__ float fin[DM];
  size_t off = ((size_t)b * LSEQ + (LSEQ - 1)) * DM;
  float r = resid[off + tid] + hidden[off + tid];
  float ss = block_reduce_sum256(r * r);
  fin[tid] = r * rsqrtf(ss * (1.f / DM) + 1e-5f) * nfw[tid];
  __syncthreads();
  if (tid < VOC) {
    float acc = 0.f;
    #pragma unroll 8
    for (int d = 0; d < DM; ++d) acc += fin[d] * embed[(size_t)tid * DM + d];
    out[b * VOC + tid] = acc;
  }
}

extern "C" void kernel_launch(void* const* d_in, const int* in_sizes, int n_in,
                              void* d_out, int out_size, void* d_ws, size_t ws_size,
                              hipStream_t stream) {
  const int*   ids   = (const int*)d_in[0];
  const float* embed = (const float*)d_in[1];
  const float* ipw   = (const float*)d_in[2];
  const float* cw    = (const float*)d_in[3];
  const float* cb    = (const float*)d_in[4];
  const float* dtbias= (const float*)d_in[5];
  const float* alog  = (const float*)d_in[6];
  const float* dpar  = (const float*)d_in[7];
  const float* ngw   = (const float*)d_in[8];
  const float* opw   = (const float*)d_in[9];
  const float* bnw   = (const float*)d_in[10];
  const float* nfw   = (const float*)d_in[11];
  float* out = (float*)d_out;

  // workspace layout
  float* ws    = (float*)d_ws;
  float* resid = ws;
  float* hidden= resid  + (size_t)TKN * DM;
  float* zx    = hidden + (size_t)TKN * DM;
  float* xb    = zx     + (size_t)TKN * DIP;
  float* yb    = xb     + (size_t)TKN * DI;
  float* dtb   = yb     + (size_t)TKN * DI;
  float* csumb = dtb    + (size_t)TKN;
  unsigned short* Bb  = (unsigned short*)(csumb + (size_t)TKN);
  unsigned short* Cb  = Bb + (size_t)TKN * DS;
  unsigned short* Ut  = Cb + (size_t)TKN * DS;
  unsigned short* hin = Ut + (size_t)TKN * DI;
  // hst (local chunk states, fp32) aliases yb: hst consumed before yb written
  float* hst = yb;

  embed_init<<<TKN, 256, 0, stream>>>(ids, embed, hidden, resid);

  for (int i = 0; i < NL; ++i) {
    add_rmsnorm<<<TKN, 256, 0, stream>>>(resid, hidden, bnw + (size_t)i * DM);
    gemm_nt_mfma<<<dim3((DIP + 127) / 128, TKN / 128), 256, 0, stream>>>(
        hidden, ipw + (size_t)i * DIP * DM, zx, DIP, DM);
    conv_silu<<<(TKN * CDIM + 255) / 256, 256, 0, stream>>>(
        zx, cw + (size_t)i * CDIM * 4, cb + (size_t)i * CDIM, dtbias + i,
        xb, Bb, Cb, dtb);
    csum_k<<<32, 256, 0, stream>>>(dtb, csumb);
    transpose_u<<<dim3(DI / 64, LSEQ / 64, NB), 256, 0, stream>>>(xb, dtb, Ut);
    state_gemm<<<dim3(2, NC, NB), 256, 0, stream>>>(Bb, Ut, csumb, alog + i, hst);
    combine2<<<dim3(DI / 64, NB), 256, 0, stream>>>(hst, csumb, alog + i, hin);
    y_gemm<<<dim3(2, NC, NB), 256, 0, stream>>>(Bb, Cb, Ut, hin, csumb, alog + i,
                                                dpar + i, xb, yb);
    gated_rmsnorm<<<TKN, 256, 0, stream>>>(yb, zx, ngw + (size_t)i * DI);
    gemm_nt_mfma<<<dim3(DM / 128, TKN / 128), 256, 0, stream>>>(
        yb, opw + (size_t)i * DM * DI, hidden, DM, DI);
  }

  finalize<<<NB, 256, 0, stream>>>(resid, hidden, embed, nfw, out);
}

// Round 4
// 872.217 us; speedup vs baseline: 2.3952x; 1.1415x over previous
//
#include <hip/hip_runtime.h>
#include <math.h>

// ---- problem constants ----
#define NB    8        // batch
#define LSEQ  2048     // seq len
#define TKN   16384    // NB*LSEQ tokens
#define DM    256      // d_model
#define DI    512      // d_inner
#define DS    64       // d_state
#define DIP   1153     // 2*DI + 2*DS + 1
#define DIPP  1160     // padded row stride for zx (bf16, 16B-aligned rows)
#define CDIM  640      // DI + 2*DS
#define NL    4
#define NC    16       // scan chunks
#define CL    128      // LSEQ/NC
#define VOC   100

typedef short bf16x8 __attribute__((ext_vector_type(8)));
typedef float f32x4  __attribute__((ext_vector_type(4)));
typedef unsigned short ushort_t;

__device__ __forceinline__ float block_reduce_sum256(float v) {
  __shared__ float sred[4];
  #pragma unroll
  for (int off = 32; off > 0; off >>= 1) v += __shfl_down(v, off, 64);
  int lane = threadIdx.x & 63, wid = threadIdx.x >> 6;
  if (lane == 0) sred[wid] = v;
  __syncthreads();
  return sred[0] + sred[1] + sred[2] + sred[3];
}

__device__ __forceinline__ unsigned short f2bf(float f) {
  unsigned int u = __float_as_uint(f);
  unsigned int r = u + 0x7FFFu + ((u >> 16) & 1u);   // RNE
  return (unsigned short)(r >> 16);
}
__device__ __forceinline__ float bf2f(unsigned short u) {
  return __uint_as_float(((unsigned int)u) << 16);
}

__device__ __forceinline__ bf16x8 pack8(float4 x, float4 y) {
  bf16x8 v;
  v[0] = (short)f2bf(x.x); v[1] = (short)f2bf(x.y);
  v[2] = (short)f2bf(x.z); v[3] = (short)f2bf(x.w);
  v[4] = (short)f2bf(y.x); v[5] = (short)f2bf(y.y);
  v[6] = (short)f2bf(y.z); v[7] = (short)f2bf(y.w);
  return v;
}

// hidden = embed[ids], resid = 0
__global__ __launch_bounds__(256) void embed_init(const int* __restrict__ ids,
    const float* __restrict__ embed, float* __restrict__ hidden, float* __restrict__ resid) {
  int t = blockIdx.x, tid = threadIdx.x;
  int id = ids[t];
  hidden[(size_t)t * DM + tid] = embed[(size_t)id * DM + tid];
  resid[(size_t)t * DM + tid] = 0.f;
}

// resid += hidden; hidden = rmsnorm(resid)*w
__global__ __launch_bounds__(256) void add_rmsnorm(float* __restrict__ resid,
    float* __restrict__ hidden, const float* __restrict__ w) {
  int t = blockIdx.x, tid = threadIdx.x;
  size_t o = (size_t)t * DM + tid;
  float r = resid[o] + hidden[o];
  resid[o] = r;
  float ss = block_reduce_sum256(r * r);
  hidden[o] = r * rsqrtf(ss * (1.f / DM) + 1e-5f) * w[tid];
}

// ---------------- bf16 MFMA GEMM, templated on A dtype and C dtype ----------------
// C[M,N](row stride ldc) = A[M,K] @ Bw[N,K]^T. Tile 128x128, BK=32, block 256.
#define LSTR 40
template<typename TA, typename TC>
__global__ __launch_bounds__(256) void gemm_nt_mfma(const TA* __restrict__ A,
    const float* __restrict__ Bw, TC* __restrict__ C, int N, int K, int ldc) {
  __shared__ short sA[128 * LSTR];
  __shared__ short sB[128 * LSTR];
  int tid = threadIdx.x;
  int bn = blockIdx.x * 128;
  int bm = blockIdx.y * 128;
  int wave = tid >> 6, lane = tid & 63;
  int wm = (wave >> 1) * 64, wn = (wave & 1) * 64;
  int q = lane >> 4, c = lane & 15;

  f32x4 acc[4][4];
  #pragma unroll
  for (int i = 0; i < 4; ++i)
    #pragma unroll
    for (int j = 0; j < 4; ++j) acc[i][j] = (f32x4)0.f;

  int sr = tid >> 1;
  int sc = (tid & 1) * 16;
  const TA* Ag = A + (size_t)(bm + sr) * K + sc;
  const float* Bg = Bw + (size_t)(bn + sr) * K + sc;
  bool bok = (bn + sr) < N;
  short* sAp = &sA[sr * LSTR + sc];
  short* sBp = &sB[sr * LSTR + sc];

  for (int k0 = 0; k0 < K; k0 += 32) {
    bf16x8 apk0, apk1;
    if constexpr (sizeof(TA) == 4) {
      float4 a0 = *(const float4*)((const float*)Ag + k0);
      float4 a1 = *(const float4*)((const float*)Ag + k0 + 4);
      float4 a2 = *(const float4*)((const float*)Ag + k0 + 8);
      float4 a3 = *(const float4*)((const float*)Ag + k0 + 12);
      apk0 = pack8(a0, a1);
      apk1 = pack8(a2, a3);
    } else {
      apk0 = *(const bf16x8*)((const ushort_t*)Ag + k0);
      apk1 = *(const bf16x8*)((const ushort_t*)Ag + k0 + 8);
    }
    float4 z4 = make_float4(0.f, 0.f, 0.f, 0.f);
    float4 b0 = z4, b1 = z4, b2 = z4, b3 = z4;
    if (bok) {
      b0 = *(const float4*)(Bg + k0);
      b1 = *(const float4*)(Bg + k0 + 4);
      b2 = *(const float4*)(Bg + k0 + 8);
      b3 = *(const float4*)(Bg + k0 + 12);
    }
    __syncthreads();
    ((bf16x8*)sAp)[0] = apk0;
    ((bf16x8*)sAp)[1] = apk1;
    ((bf16x8*)sBp)[0] = pack8(b0, b1);
    ((bf16x8*)sBp)[1] = pack8(b2, b3);
    __syncthreads();
    bf16x8 af[4], bfr[4];
    #pragma unroll
    for (int i = 0; i < 4; ++i)
      af[i] = *(const bf16x8*)&sA[(wm + i * 16 + c) * LSTR + q * 8];
    #pragma unroll
    for (int j = 0; j < 4; ++j)
      bfr[j] = *(const bf16x8*)&sB[(wn + j * 16 + c) * LSTR + q * 8];
    #pragma unroll
    for (int i = 0; i < 4; ++i)
      #pragma unroll
      for (int j = 0; j < 4; ++j)
        acc[i][j] = __builtin_amdgcn_mfma_f32_16x16x32_bf16(af[i], bfr[j], acc[i][j], 0, 0, 0);
  }
  #pragma unroll
  for (int i = 0; i < 4; ++i) {
    int m = bm + wm + i * 16 + q * 4;
    #pragma unroll
    for (int j = 0; j < 4; ++j) {
      int n = bn + wn + j * 16 + c;
      if (n < N) {
        #pragma unroll
        for (int r = 0; r < 4; ++r) {
          if constexpr (sizeof(TC) == 2)
            C[(size_t)(m + r) * ldc + n] = (TC)f2bf(acc[i][j][r]);
          else
            C[(size_t)(m + r) * ldc + n] = acc[i][j][r];
        }
      }
    }
  }
}

// LDS-tiled depthwise causal conv(4)+bias+silu. zx bf16 (stride DIPP).
// grid (CDIM/128, LSEQ/64, NB), block 256. Tile: 64 tokens x 128 channels.
__global__ __launch_bounds__(256) void conv_silu(const ushort_t* __restrict__ zx,
    const float* __restrict__ cw, const float* __restrict__ cb,
    ushort_t* __restrict__ xo, ushort_t* __restrict__ Bo, ushort_t* __restrict__ Co) {
  __shared__ float tile[67 * 128];
  int tid = threadIdx.x;
  int ct = blockIdx.x, tt = blockIdx.y, b = blockIdx.z;
  int c0 = ct * 128;
  int l0 = tt * 64;
  size_t rowb = (size_t)b * LSEQ;
  int cl = tid & 127;
  int cg = c0 + cl;
  // stage 67 rows (3 halo + 64)
  for (int tr = tid >> 7; tr < 67; tr += 2) {
    int l = l0 + tr - 3;
    float v = 0.f;
    if (l >= 0) v = bf2f(zx[(rowb + l) * DIPP + DI + cg]);
    tile[tr * 128 + cl] = v;
  }
  float w0 = cw[cg * 4 + 0], w1 = cw[cg * 4 + 1];
  float w2 = cw[cg * 4 + 2], w3 = cw[cg * 4 + 3];
  float bias = cb[cg];
  __syncthreads();
  #pragma unroll 4
  for (int t = tid >> 7; t < 64; t += 2) {
    float s = bias + w0 * tile[t * 128 + cl] + w1 * tile[(t + 1) * 128 + cl]
                   + w2 * tile[(t + 2) * 128 + cl] + w3 * tile[(t + 3) * 128 + cl];
    float v = s / (1.f + __expf(-s));
    size_t tl = rowb + l0 + t;
    if (cg < DI)            xo[tl * DI + cg] = f2bf(v);
    else if (cg < DI + DS)  Bo[tl * DS + (cg - DI)] = f2bf(v);
    else                    Co[tl * DS + (cg - DI - DS)] = f2bf(v);
  }
}

// dt = softplus(dt_raw + bias); per-chunk inclusive prefix sum. one wave per chunk.
__global__ __launch_bounds__(256) void csum_k(const ushort_t* __restrict__ zx,
    const float* __restrict__ dtbias, float* __restrict__ dtb, float* __restrict__ csumb) {
  int tid = threadIdx.x;
  int wave = tid >> 6, lane = tid & 63;
  int cg = blockIdx.x * 4 + wave;          // global chunk 0..127
  int b = cg >> 4, ch = cg & 15;
  size_t base = (size_t)b * LSEQ + ch * CL;
  float bias = dtbias[0];
  float x0 = bf2f(zx[(base + 2 * lane) * DIPP + (DIP - 1)]) + bias;
  float x1 = bf2f(zx[(base + 2 * lane + 1) * DIPP + (DIP - 1)]) + bias;
  float d0 = (x0 > 20.f) ? x0 : log1pf(__expf(x0));
  float d1 = (x1 > 20.f) ? x1 : log1pf(__expf(x1));
  dtb[base + 2 * lane] = d0;
  dtb[base + 2 * lane + 1] = d1;
  float p = d0 + d1;
  #pragma unroll
  for (int off = 1; off < 64; off <<= 1) {
    float t = __shfl_up(p, off, 64);
    if (lane >= off) p += t;
  }
  csumb[base + 2 * lane]     = p - d1;
  csumb[base + 2 * lane + 1] = p;
}

// Ut[b][p][s_global] bf16 = dt[s]*x[s][p]  (transpose). block: 64s x 64p tile.
__global__ __launch_bounds__(256) void transpose_u(const ushort_t* __restrict__ xb,
    const float* __restrict__ dtb, ushort_t* __restrict__ Ut) {
  __shared__ ushort_t tile[64 * 65];
  int tid = threadIdx.x;
  int pt = blockIdx.x, st = blockIdx.y, b = blockIdx.z;
  int s0 = st * 64, p0 = pt * 64;
  #pragma unroll
  for (int i = 0; i < 16; ++i) {
    int sl = (tid >> 6) * 16 + i;
    int pl = tid & 63;
    float dt = dtb[(size_t)b * LSEQ + s0 + sl];
    float v = bf2f(xb[((size_t)b * LSEQ + s0 + sl) * DI + p0 + pl]) * dt;
    tile[pl * 65 + sl] = f2bf(v);
  }
  __syncthreads();
  #pragma unroll
  for (int i = 0; i < 16; ++i) {
    int op = (tid >> 6) * 16 + i;
    int os = tid & 63;
    Ut[((size_t)b * DI + p0 + op) * LSEQ + s0 + os] = tile[op * 65 + os];
  }
}

// state GEMM: Hloc[bc][n][p] = sum_s exp(A(S - cs[s])) * B[s][n] * U[s][p]
// grid (2, NC, NB), block 256.
__global__ __launch_bounds__(256) void state_gemm(const ushort_t* __restrict__ Bb,
    const ushort_t* __restrict__ Ut, const float* __restrict__ csumb,
    const float* __restrict__ alog, float* __restrict__ hst) {
  __shared__ short sW[64 * 144];
  __shared__ short sX[256 * 40];
  __shared__ float scs[128];
  int tid = threadIdx.x;
  int ph = blockIdx.x, ch = blockIdx.y, b = blockIdx.z;
  int bc = b * NC + ch;
  size_t tb = (size_t)b * LSEQ + ch * CL;
  float Aval = -expf(alog[0]);
  if (tid < 128) scs[tid] = csumb[tb + tid];
  __syncthreads();
  float Stot = scs[127];
  {
    int s = tid >> 1, noff = (tid & 1) * 32;
    float scale = __expf(Aval * (Stot - scs[s]));
    #pragma unroll
    for (int blk = 0; blk < 4; ++blk) {
      bf16x8 v = *(const bf16x8*)&Bb[(tb + s) * DS + noff + blk * 8];
      #pragma unroll
      for (int e = 0; e < 8; ++e)
        sW[(noff + blk * 8 + e) * 144 + s] = (short)f2bf(bf2f((ushort_t)v[e]) * scale);
    }
  }
  int wave = tid >> 6, lane = tid & 63;
  int wp = wave * 64;
  int q = lane >> 4, c = lane & 15;
  f32x4 acc[4][4];
  #pragma unroll
  for (int i = 0; i < 4; ++i)
    #pragma unroll
    for (int j = 0; j < 4; ++j) acc[i][j] = (f32x4)0.f;

  for (int ks = 0; ks < 4; ++ks) {
    __syncthreads();
    {
      size_t ua = ((size_t)b * DI + ph * 256 + tid) * LSEQ + ch * CL + ks * 32;
      bf16x8 u0 = *(const bf16x8*)&Ut[ua];
      bf16x8 u1 = *(const bf16x8*)&Ut[ua + 8];
      bf16x8 u2 = *(const bf16x8*)&Ut[ua + 16];
      bf16x8 u3 = *(const bf16x8*)&Ut[ua + 24];
      *(bf16x8*)&sX[tid * 40]      = u0;
      *(bf16x8*)&sX[tid * 40 + 8]  = u1;
      *(bf16x8*)&sX[tid * 40 + 16] = u2;
      *(bf16x8*)&sX[tid * 40 + 24] = u3;
    }
    __syncthreads();
    bf16x8 af[4], bfr[4];
    #pragma unroll
    for (int i = 0; i < 4; ++i)
      af[i] = *(const bf16x8*)&sW[(i * 16 + c) * 144 + ks * 32 + q * 8];
    #pragma unroll
    for (int j = 0; j < 4; ++j)
      bfr[j] = *(const bf16x8*)&sX[(wp + j * 16 + c) * 40 + q * 8];
    #pragma unroll
    for (int i = 0; i < 4; ++i)
      #pragma unroll
      for (int j = 0; j < 4; ++j)
        acc[i][j] = __builtin_amdgcn_mfma_f32_16x16x32_bf16(af[i], bfr[j], acc[i][j], 0, 0, 0);
  }
  #pragma unroll
  for (int i = 0; i < 4; ++i) {
    int n = i * 16 + q * 4;
    #pragma unroll
    for (int j = 0; j < 4; ++j) {
      int pg = ph * 256 + wp + j * 16 + c;
      #pragma unroll
      for (int r = 0; r < 4; ++r)
        hst[((size_t)bc * DS + n + r) * DI + pg] = acc[i][j][r];
    }
  }
}

// combine: sequential over chunks; outputs carry-in states hin[bc][p][n] bf16
__global__ __launch_bounds__(256) void combine2(const float* __restrict__ hst,
    const float* __restrict__ csumb, const float* __restrict__ alog,
    ushort_t* __restrict__ hin) {
  __shared__ ushort_t ts[64 * 65];
  int tid = threadIdx.x;
  int pt = blockIdx.x, b = blockIdx.y;
  int p0 = pt * 64;
  int pl = tid & 63, ng = tid >> 6;
  float Aval = -expf(alog[0]);
  float h[16];
  #pragma unroll
  for (int i = 0; i < 16; ++i) h[i] = 0.f;
  for (int c = 0; c < NC; ++c) {
    int bc = b * NC + c;
    #pragma unroll
    for (int i = 0; i < 16; ++i)
      ts[pl * 65 + ng * 16 + i] = f2bf(h[i]);
    __syncthreads();
    {
      int on = tid & 63;
      #pragma unroll
      for (int i = 0; i < 16; ++i) {
        int op = (tid >> 6) * 16 + i;
        hin[((size_t)bc * DI + p0 + op) * DS + on] = ts[op * 65 + on];
      }
    }
    __syncthreads();
    float Sc = csumb[(size_t)b * LSEQ + c * CL + CL - 1];
    float dec = __expf(Aval * Sc);
    #pragma unroll
    for (int i = 0; i < 16; ++i) {
      float loc = hst[((size_t)bc * DS + ng * 16 + i) * DI + p0 + pl];
      h[i] = h[i] * dec + loc;
    }
  }
}

// y GEMM: G=C@B^T -> M masked-decayed -> Y = M@U + Chat@Hin; y = Y + dp*x (bf16 out)
__global__ __launch_bounds__(256) void y_gemm(const ushort_t* __restrict__ Bb,
    const ushort_t* __restrict__ Cb, const ushort_t* __restrict__ Ut,
    const ushort_t* __restrict__ hin, const float* __restrict__ csumb,
    const float* __restrict__ alog, const float* __restrict__ dpar,
    const ushort_t* __restrict__ xb, ushort_t* __restrict__ y) {
  __shared__ short sC[128 * 72];
  __shared__ short sBX[256 * 40];
  __shared__ short sM[128 * 136];
  __shared__ float scs[128];
  int tid = threadIdx.x;
  int ph = blockIdx.x, ch = blockIdx.y, b = blockIdx.z;
  int bc = b * NC + ch;
  size_t tb = (size_t)b * LSEQ + ch * CL;
  float Aval = -expf(alog[0]);
  float dp = dpar[0];
  int wave = tid >> 6, lane = tid & 63;
  int q = lane >> 4, c = lane & 15;

  {
    int r = tid >> 1, off = (tid & 1) * 32;
    #pragma unroll
    for (int blk = 0; blk < 4; ++blk) {
      *(bf16x8*)&sC[r * 72 + off + blk * 8]  = *(const bf16x8*)&Cb[(tb + r) * DS + off + blk * 8];
      *(bf16x8*)&sBX[r * 80 + off + blk * 8] = *(const bf16x8*)&Bb[(tb + r) * DS + off + blk * 8];
    }
  }
  if (tid < 128) scs[tid] = csumb[tb + tid];
  __syncthreads();

  // phase 1: G = C @ B^T
  {
    int wm = (wave >> 1) * 64, wss = (wave & 1) * 64;
    f32x4 g[4][4];
    #pragma unroll
    for (int i = 0; i < 4; ++i)
      #pragma unroll
      for (int j = 0; j < 4; ++j) g[i][j] = (f32x4)0.f;
    #pragma unroll
    for (int k0 = 0; k0 < 64; k0 += 32) {
      bf16x8 af[4], bfr[4];
      #pragma unroll
      for (int i = 0; i < 4; ++i)
        af[i] = *(const bf16x8*)&sC[(wm + i * 16 + c) * 72 + k0 + q * 8];
      #pragma unroll
      for (int j = 0; j < 4; ++j)
        bfr[j] = *(const bf16x8*)&sBX[(wss + j * 16 + c) * 80 + k0 + q * 8];
      #pragma unroll
      for (int i = 0; i < 4; ++i)
        #pragma unroll
        for (int j = 0; j < 4; ++j)
          g[i][j] = __builtin_amdgcn_mfma_f32_16x16x32_bf16(af[i], bfr[j], g[i][j], 0, 0, 0);
    }
    #pragma unroll
    for (int i = 0; i < 4; ++i) {
      #pragma unroll
      for (int r = 0; r < 4; ++r) {
        int t = wm + i * 16 + q * 4 + r;
        float ct = scs[t];
        #pragma unroll
        for (int j = 0; j < 4; ++j) {
          int s = wss + j * 16 + c;
          float v = g[i][j][r];
          float m = (s <= t) ? v * __expf(Aval * (ct - scs[s])) : 0.f;
          sM[t * 136 + s] = (short)f2bf(m);
        }
      }
    }
  }

  // phase 2: Y = M @ U^T' + Chat @ Hin
  int wm2 = (wave >> 1) * 64, wp = (wave & 1) * 128;
  f32x4 acc[4][8];
  #pragma unroll
  for (int i = 0; i < 4; ++i)
    #pragma unroll
    for (int j = 0; j < 8; ++j) acc[i][j] = (f32x4)0.f;

  for (int ks = 0; ks < 4; ++ks) {
    __syncthreads();
    {
      size_t ua = ((size_t)b * DI + ph * 256 + tid) * LSEQ + ch * CL + ks * 32;
      bf16x8 u0 = *(const bf16x8*)&Ut[ua];
      bf16x8 u1 = *(const bf16x8*)&Ut[ua + 8];
      bf16x8 u2 = *(const bf16x8*)&Ut[ua + 16];
      bf16x8 u3 = *(const bf16x8*)&Ut[ua + 24];
      *(bf16x8*)&sBX[tid * 40]      = u0;
      *(bf16x8*)&sBX[tid * 40 + 8]  = u1;
      *(bf16x8*)&sBX[tid * 40 + 16] = u2;
      *(bf16x8*)&sBX[tid * 40 + 24] = u3;
    }
    __syncthreads();
    bf16x8 af[4], bfr[8];
    #pragma unroll
    for (int i = 0; i < 4; ++i)
      af[i] = *(const bf16x8*)&sM[(wm2 + i * 16 + c) * 136 + ks * 32 + q * 8];
    #pragma unroll
    for (int j = 0; j < 8; ++j)
      bfr[j] = *(const bf16x8*)&sBX[(wp + j * 16 + c) * 40 + q * 8];
    #pragma unroll
    for (int i = 0; i < 4; ++i)
      #pragma unroll
      for (int j = 0; j < 8; ++j)
        acc[i][j] = __builtin_amdgcn_mfma_f32_16x16x32_bf16(af[i], bfr[j], acc[i][j], 0, 0, 0);
  }

  __syncthreads();
  {
    int r = tid >> 1, off = (tid & 1) * 32;
    float sc_t = __expf(Aval * scs[r]);
    #pragma unroll
    for (int blk = 0; blk < 4; ++blk) {
      bf16x8 v = *(const bf16x8*)&sC[r * 72 + off + blk * 8];
      bf16x8 o;
      #pragma unroll
      for (int e = 0; e < 8; ++e)
        o[e] = (short)f2bf(bf2f((ushort_t)v[e]) * sc_t);
      *(bf16x8*)&sM[r * 80 + off + blk * 8] = o;
    }
  }
  for (int ks = 4; ks < 6; ++ks) {
    __syncthreads();
    {
      size_t ha = ((size_t)bc * DI + ph * 256 + tid) * DS + (ks - 4) * 32;
      bf16x8 h0 = *(const bf16x8*)&hin[ha];
      bf16x8 h1 = *(const bf16x8*)&hin[ha + 8];
      bf16x8 h2 = *(const bf16x8*)&hin[ha + 16];
      bf16x8 h3 = *(const bf16x8*)&hin[ha + 24];
      *(bf16x8*)&sBX[tid * 40]      = h0;
      *(bf16x8*)&sBX[tid * 40 + 8]  = h1;
      *(bf16x8*)&sBX[tid * 40 + 16] = h2;
      *(bf16x8*)&sBX[tid * 40 + 24] = h3;
    }
    __syncthreads();
    bf16x8 af[4], bfr[8];
    #pragma unroll
    for (int i = 0; i < 4; ++i)
      af[i] = *(const bf16x8*)&sM[(wm2 + i * 16 + c) * 80 + (ks - 4) * 32 + q * 8];
    #pragma unroll
    for (int j = 0; j < 8; ++j)
      bfr[j] = *(const bf16x8*)&sBX[(wp + j * 16 + c) * 40 + q * 8];
    #pragma unroll
    for (int i = 0; i < 4; ++i)
      #pragma unroll
      for (int j = 0; j < 8; ++j)
        acc[i][j] = __builtin_amdgcn_mfma_f32_16x16x32_bf16(af[i], bfr[j], acc[i][j], 0, 0, 0);
  }

  #pragma unroll
  for (int i = 0; i < 4; ++i) {
    #pragma unroll
    for (int r = 0; r < 4; ++r) {
      int t = wm2 + i * 16 + q * 4 + r;
      size_t row = (tb + t) * DI;
      #pragma unroll
      for (int j = 0; j < 8; ++j) {
        int pg = ph * 256 + wp + j * 16 + c;
        y[row + pg] = f2bf(acc[i][j][r] + dp * bf2f(xb[row + pg]));
      }
    }
  }
}

// y = rmsnorm(y * silu(z)) * w   (z = zx[...,0:512] bf16), y bf16 in/out
__global__ __launch_bounds__(256) void gated_rmsnorm(ushort_t* __restrict__ y,
    const ushort_t* __restrict__ zx, const float* __restrict__ w) {
  int t = blockIdx.x, tid = threadIdx.x;
  const ushort_t* zr = zx + (size_t)t * DIPP;
  ushort_t* yr = y + (size_t)t * DI;
  int c0 = tid, c1 = tid + 256;
  float z0 = bf2f(zr[c0]), z1 = bf2f(zr[c1]);
  float g0 = bf2f(yr[c0]) * (z0 / (1.f + __expf(-z0)));
  float g1 = bf2f(yr[c1]) * (z1 / (1.f + __expf(-z1)));
  float ss = block_reduce_sum256(g0 * g0 + g1 * g1);
  float r = rsqrtf(ss * (1.f / DI) + 1e-5f);
  yr[c0] = f2bf(g0 * r * w[c0]);
  yr[c1] = f2bf(g1 * r * w[c1]);
}

// last token only
__global__ __launch_bounds__(256) void finalize(const float* __restrict__ resid,
    const float* __restrict__ hidden, const float* __restrict__ embed,
    const float* __restrict__ nfw, float* __restrict__ out) {
  int b = blockIdx.x, tid = threadIdx.x;
  __shared__ float fin[DM];
  size_t off = ((size_t)b * LSEQ + (LSEQ - 1)) * DM;
  float r = resid[off + tid] + hidden[off + tid];
  float ss = block_reduce_sum256(r * r);
  fin[tid] = r * rsqrtf(ss * (1.f / DM) + 1e-5f) * nfw[tid];
  __syncthreads();
  if (tid < VOC) {
    float acc = 0.f;
    #pragma unroll 8
    for (int d = 0; d < DM; ++d) acc += fin[d] * embed[(size_t)tid * DM + d];
    out[b * VOC + tid] = acc;
  }
}

extern "C" void kernel_launch(void* const* d_in, const int* in_sizes, int n_in,
                              void* d_out, int out_size, void* d_ws, size_t ws_size,
                              hipStream_t stream) {
  const int*   ids   = (const int*)d_in[0];
  const float* embed = (const float*)d_in[1];
  const float* ipw   = (const float*)d_in[2];
  const float* cw    = (const float*)d_in[3];
  const float* cb    = (const float*)d_in[4];
  const float* dtbias= (const float*)d_in[5];
  const float* alog  = (const float*)d_in[6];
  const float* dpar  = (const float*)d_in[7];
  const float* ngw   = (const float*)d_in[8];
  const float* opw   = (const float*)d_in[9];
  const float* bnw   = (const float*)d_in[10];
  const float* nfw   = (const float*)d_in[11];
  float* out = (float*)d_out;

  // workspace layout (~151 MB)
  char* p = (char*)d_ws;
  float* resid = (float*)p;            p += (size_t)TKN * DM * 4;
  float* hidden= (float*)p;            p += (size_t)TKN * DM * 4;
  ushort_t* zx = (ushort_t*)p;         p += (size_t)TKN * DIPP * 2;
  float* dtb   = (float*)p;            p += (size_t)TKN * 4;
  float* csumb = (float*)p;            p += (size_t)TKN * 4;
  ushort_t* xb = (ushort_t*)p;         p += (size_t)TKN * DI * 2;
  ushort_t* yb = (ushort_t*)p;         p += (size_t)TKN * DI * 2;
  ushort_t* Bb = (ushort_t*)p;         p += (size_t)TKN * DS * 2;
  ushort_t* Cb = (ushort_t*)p;         p += (size_t)TKN * DS * 2;
  ushort_t* Ut = (ushort_t*)p;         p += (size_t)TKN * DI * 2;
  ushort_t* hin= (ushort_t*)p;         p += (size_t)NB * NC * DI * DS * 2;
  // hst (fp32, 16.78MB) aliases yb (bf16, 16.78MB): consumed by combine2 before y_gemm writes yb
  float* hst = (float*)yb;

  embed_init<<<TKN, 256, 0, stream>>>(ids, embed, hidden, resid);

  for (int i = 0; i < NL; ++i) {
    add_rmsnorm<<<TKN, 256, 0, stream>>>(resid, hidden, bnw + (size_t)i * DM);
    gemm_nt_mfma<float, ushort_t><<<dim3((DIP + 127) / 128, TKN / 128), 256, 0, stream>>>(
        hidden, ipw + (size_t)i * DIP * DM, zx, DIP, DM, DIPP);
    csum_k<<<32, 256, 0, stream>>>(zx, dtbias + i, dtb, csumb);
    conv_silu<<<dim3(CDIM / 128, LSEQ / 64, NB), 256, 0, stream>>>(
        zx, cw + (size_t)i * CDIM * 4, cb + (size_t)i * CDIM, xb, Bb, Cb);
    transpose_u<<<dim3(DI / 64, LSEQ / 64, NB), 256, 0, stream>>>(xb, dtb, Ut);
    state_gemm<<<dim3(2, NC, NB), 256, 0, stream>>>(Bb, Ut, csumb, alog + i, hst);
    combine2<<<dim3(DI / 64, NB), 256, 0, stream>>>(hst, csumb, alog + i, hin);
    y_gemm<<<dim3(2, NC, NB), 256, 0, stream>>>(Bb, Cb, Ut, hin, csumb, alog + i,
                                                dpar + i, xb, yb);
    gated_rmsnorm<<<TKN, 256, 0, stream>>>(yb, zx, ngw + (size_t)i * DI);
    gemm_nt_mfma<ushort_t, float><<<dim3(DM / 128, TKN / 128), 256, 0, stream>>>(
        yb, opw + (size_t)i * DM * DI, hidden, DM, DI, DM);
  }

  finalize<<<NB, 256, 0, stream>>>(resid, hidden, embed, nfw, out);
}

// Round 5
// 721.850 us; speedup vs baseline: 2.8941x; 1.2083x over previous
//
#include <hip/hip_runtime.h>
#include <math.h>

// ---- problem constants ----
#define NB    8        // batch
#define LSEQ  2048     // seq len
#define TKN   16384    // NB*LSEQ tokens
#define DM    256      // d_model
#define DI    512      // d_inner
#define DS    64       // d_state
#define DIP   1153     // 2*DI + 2*DS + 1
#define DIPP  1160     // padded row stride for zx (bf16)
#define CDIM  640      // DI + 2*DS
#define NL    4
#define NC    16       // scan chunks
#define CL    128      // LSEQ/NC
#define VOC   100

typedef short bf16x8 __attribute__((ext_vector_type(8)));
typedef float f32x4  __attribute__((ext_vector_type(4)));
typedef unsigned short ushort_t;

__device__ __forceinline__ float block_reduce_sum256(float v) {
  __shared__ float sred[4];
  #pragma unroll
  for (int off = 32; off > 0; off >>= 1) v += __shfl_down(v, off, 64);
  int lane = threadIdx.x & 63, wid = threadIdx.x >> 6;
  if (lane == 0) sred[wid] = v;
  __syncthreads();
  return sred[0] + sred[1] + sred[2] + sred[3];
}

__device__ __forceinline__ unsigned short f2bf(float f) {
  unsigned int u = __float_as_uint(f);
  unsigned int r = u + 0x7FFFu + ((u >> 16) & 1u);   // RNE
  return (unsigned short)(r >> 16);
}
__device__ __forceinline__ float bf2f(unsigned short u) {
  return __uint_as_float(((unsigned int)u) << 16);
}

__device__ __forceinline__ bf16x8 pack8(float4 x, float4 y) {
  bf16x8 v;
  v[0] = (short)f2bf(x.x); v[1] = (short)f2bf(x.y);
  v[2] = (short)f2bf(x.z); v[3] = (short)f2bf(x.w);
  v[4] = (short)f2bf(y.x); v[5] = (short)f2bf(y.y);
  v[6] = (short)f2bf(y.z); v[7] = (short)f2bf(y.w);
  return v;
}

// mixo = embed[ids], resid = 0
__global__ __launch_bounds__(256) void embed_init(const int* __restrict__ ids,
    const float* __restrict__ embed, float* __restrict__ mixo, float* __restrict__ resid) {
  int t = blockIdx.x, tid = threadIdx.x;
  int id = ids[t];
  mixo[(size_t)t * DM + tid] = embed[(size_t)id * DM + tid];
  resid[(size_t)t * DM + tid] = 0.f;
}

// resid += mixo; hn = bf16(rmsnorm(resid)*w)
__global__ __launch_bounds__(256) void add_rmsnorm(float* __restrict__ resid,
    const float* __restrict__ mixo, ushort_t* __restrict__ hn, const float* __restrict__ w) {
  int t = blockIdx.x, tid = threadIdx.x;
  size_t o = (size_t)t * DM + tid;
  float r = resid[o] + mixo[o];
  resid[o] = r;
  float ss = block_reduce_sum256(r * r);
  hn[o] = f2bf(r * rsqrtf(ss * (1.f / DM) + 1e-5f) * w[tid]);
}

// ---------------- bf16 MFMA GEMM, templated on A dtype and C dtype ----------------
// C[M,N](row stride ldc) = A[M,K] @ Bw[N,K]^T. Tile 128x128, BK=32, block 256.
#define LSTR 40
template<typename TA, typename TC>
__global__ __launch_bounds__(256) void gemm_nt_mfma(const TA* __restrict__ A,
    const float* __restrict__ Bw, TC* __restrict__ C, int N, int K, int ldc) {
  __shared__ short sA[128 * LSTR];
  __shared__ short sB[128 * LSTR];
  int tid = threadIdx.x;
  int bn = blockIdx.x * 128;
  int bm = blockIdx.y * 128;
  int wave = tid >> 6, lane = tid & 63;
  int wm = (wave >> 1) * 64, wn = (wave & 1) * 64;
  int q = lane >> 4, c = lane & 15;

  f32x4 acc[4][4];
  #pragma unroll
  for (int i = 0; i < 4; ++i)
    #pragma unroll
    for (int j = 0; j < 4; ++j) acc[i][j] = (f32x4)0.f;

  int sr = tid >> 1;
  int sc = (tid & 1) * 16;
  const TA* Ag = A + (size_t)(bm + sr) * K + sc;
  const float* Bg = Bw + (size_t)(bn + sr) * K + sc;
  bool bok = (bn + sr) < N;
  short* sAp = &sA[sr * LSTR + sc];
  short* sBp = &sB[sr * LSTR + sc];

  for (int k0 = 0; k0 < K; k0 += 32) {
    bf16x8 apk0, apk1;
    if constexpr (sizeof(TA) == 4) {
      float4 a0 = *(const float4*)((const float*)Ag + k0);
      float4 a1 = *(const float4*)((const float*)Ag + k0 + 4);
      float4 a2 = *(const float4*)((const float*)Ag + k0 + 8);
      float4 a3 = *(const float4*)((const float*)Ag + k0 + 12);
      apk0 = pack8(a0, a1);
      apk1 = pack8(a2, a3);
    } else {
      apk0 = *(const bf16x8*)((const ushort_t*)Ag + k0);
      apk1 = *(const bf16x8*)((const ushort_t*)Ag + k0 + 8);
    }
    float4 z4 = make_float4(0.f, 0.f, 0.f, 0.f);
    float4 b0 = z4, b1 = z4, b2 = z4, b3 = z4;
    if (bok) {
      b0 = *(const float4*)(Bg + k0);
      b1 = *(const float4*)(Bg + k0 + 4);
      b2 = *(const float4*)(Bg + k0 + 8);
      b3 = *(const float4*)(Bg + k0 + 12);
    }
    __syncthreads();
    ((bf16x8*)sAp)[0] = apk0;
    ((bf16x8*)sAp)[1] = apk1;
    ((bf16x8*)sBp)[0] = pack8(b0, b1);
    ((bf16x8*)sBp)[1] = pack8(b2, b3);
    __syncthreads();
    bf16x8 af[4], bfr[4];
    #pragma unroll
    for (int i = 0; i < 4; ++i)
      af[i] = *(const bf16x8*)&sA[(wm + i * 16 + c) * LSTR + q * 8];
    #pragma unroll
    for (int j = 0; j < 4; ++j)
      bfr[j] = *(const bf16x8*)&sB[(wn + j * 16 + c) * LSTR + q * 8];
    #pragma unroll
    for (int i = 0; i < 4; ++i)
      #pragma unroll
      for (int j = 0; j < 4; ++j)
        acc[i][j] = __builtin_amdgcn_mfma_f32_16x16x32_bf16(af[i], bfr[j], acc[i][j], 0, 0, 0);
  }
  #pragma unroll
  for (int i = 0; i < 4; ++i) {
    int m = bm + wm + i * 16 + q * 4;
    #pragma unroll
    for (int j = 0; j < 4; ++j) {
      int n = bn + wn + j * 16 + c;
      if (n < N) {
        #pragma unroll
        for (int r = 0; r < 4; ++r) {
          if constexpr (sizeof(TC) == 2)
            C[(size_t)(m + r) * ldc + n] = (TC)f2bf(acc[i][j][r]);
          else
            C[(size_t)(m + r) * ldc + n] = acc[i][j][r];
        }
      }
    }
  }
}

// LDS-tiled depthwise causal conv(4)+bias+silu. zx bf16 (stride DIPP).
__global__ __launch_bounds__(256) void conv_silu(const ushort_t* __restrict__ zx,
    const float* __restrict__ cw, const float* __restrict__ cb,
    ushort_t* __restrict__ xo, ushort_t* __restrict__ Bo, ushort_t* __restrict__ Co) {
  __shared__ float tile[67 * 128];
  int tid = threadIdx.x;
  int ct = blockIdx.x, tt = blockIdx.y, b = blockIdx.z;
  int c0 = ct * 128;
  int l0 = tt * 64;
  size_t rowb = (size_t)b * LSEQ;
  int cl = tid & 127;
  int cg = c0 + cl;
  for (int tr = tid >> 7; tr < 67; tr += 2) {
    int l = l0 + tr - 3;
    float v = 0.f;
    if (l >= 0) v = bf2f(zx[(rowb + l) * DIPP + DI + cg]);
    tile[tr * 128 + cl] = v;
  }
  float w0 = cw[cg * 4 + 0], w1 = cw[cg * 4 + 1];
  float w2 = cw[cg * 4 + 2], w3 = cw[cg * 4 + 3];
  float bias = cb[cg];
  __syncthreads();
  #pragma unroll 4
  for (int t = tid >> 7; t < 64; t += 2) {
    float s = bias + w0 * tile[t * 128 + cl] + w1 * tile[(t + 1) * 128 + cl]
                   + w2 * tile[(t + 2) * 128 + cl] + w3 * tile[(t + 3) * 128 + cl];
    float v = s / (1.f + __expf(-s));
    size_t tl = rowb + l0 + t;
    if (cg < DI)            xo[tl * DI + cg] = f2bf(v);
    else if (cg < DI + DS)  Bo[tl * DS + (cg - DI)] = f2bf(v);
    else                    Co[tl * DS + (cg - DI - DS)] = f2bf(v);
  }
}

// dt = softplus(dt_raw + bias); per-chunk inclusive prefix sum. one wave per chunk.
__global__ __launch_bounds__(256) void csum_k(const ushort_t* __restrict__ zx,
    const float* __restrict__ dtbias, float* __restrict__ dtb, float* __restrict__ csumb) {
  int tid = threadIdx.x;
  int wave = tid >> 6, lane = tid & 63;
  int cg = blockIdx.x * 4 + wave;
  int b = cg >> 4, ch = cg & 15;
  size_t base = (size_t)b * LSEQ + ch * CL;
  float bias = dtbias[0];
  float x0 = bf2f(zx[(base + 2 * lane) * DIPP + (DIP - 1)]) + bias;
  float x1 = bf2f(zx[(base + 2 * lane + 1) * DIPP + (DIP - 1)]) + bias;
  float d0 = (x0 > 20.f) ? x0 : log1pf(__expf(x0));
  float d1 = (x1 > 20.f) ? x1 : log1pf(__expf(x1));
  dtb[base + 2 * lane] = d0;
  dtb[base + 2 * lane + 1] = d1;
  float p = d0 + d1;
  #pragma unroll
  for (int off = 1; off < 64; off <<= 1) {
    float t = __shfl_up(p, off, 64);
    if (lane >= off) p += t;
  }
  csumb[base + 2 * lane]     = p - d1;
  csumb[base + 2 * lane + 1] = p;
}

// Ut[b][p][s_global] bf16 = dt[s]*x[s][p]  (transpose). block: 64s x 64p tile.
__global__ __launch_bounds__(256) void transpose_u(const ushort_t* __restrict__ xb,
    const float* __restrict__ dtb, ushort_t* __restrict__ Ut) {
  __shared__ ushort_t tile[64 * 65];
  int tid = threadIdx.x;
  int pt = blockIdx.x, st = blockIdx.y, b = blockIdx.z;
  int s0 = st * 64, p0 = pt * 64;
  #pragma unroll
  for (int i = 0; i < 16; ++i) {
    int sl = (tid >> 6) * 16 + i;
    int pl = tid & 63;
    float dt = dtb[(size_t)b * LSEQ + s0 + sl];
    float v = bf2f(xb[((size_t)b * LSEQ + s0 + sl) * DI + p0 + pl]) * dt;
    tile[pl * 65 + sl] = f2bf(v);
  }
  __syncthreads();
  #pragma unroll
  for (int i = 0; i < 16; ++i) {
    int op = (tid >> 6) * 16 + i;
    int os = tid & 63;
    Ut[((size_t)b * DI + p0 + op) * LSEQ + s0 + os] = tile[op * 65 + os];
  }
}

// state GEMM: Hloc[bc][n][p] = sum_s exp(A(S - cs[s])) * B[s][n] * U[s][p]
// grid (4, NC, NB), block 256. Tile n=64, p=128, K=128.
__global__ __launch_bounds__(256) void state_gemm(const ushort_t* __restrict__ Bb,
    const ushort_t* __restrict__ Ut, const float* __restrict__ csumb,
    const float* __restrict__ alog, float* __restrict__ hst) {
  __shared__ short sW[64 * 144];
  __shared__ short sX[128 * 40];
  __shared__ float scs[128];
  int tid = threadIdx.x;
  int ph = blockIdx.x, ch = blockIdx.y, b = blockIdx.z;
  int bc = b * NC + ch;
  size_t tb = (size_t)b * LSEQ + ch * CL;
  float Aval = -expf(alog[0]);
  if (tid < 128) scs[tid] = csumb[tb + tid];
  __syncthreads();
  float Stot = scs[127];
  {
    int s = tid >> 1, noff = (tid & 1) * 32;
    float scale = __expf(Aval * (Stot - scs[s]));
    #pragma unroll
    for (int blk = 0; blk < 4; ++blk) {
      bf16x8 v = *(const bf16x8*)&Bb[(tb + s) * DS + noff + blk * 8];
      #pragma unroll
      for (int e = 0; e < 8; ++e)
        sW[(noff + blk * 8 + e) * 144 + s] = (short)f2bf(bf2f((ushort_t)v[e]) * scale);
    }
  }
  int wave = tid >> 6, lane = tid & 63;
  int wn = (wave >> 1) * 32, wp = (wave & 1) * 64;
  int q = lane >> 4, c = lane & 15;
  f32x4 acc[2][4];
  #pragma unroll
  for (int i = 0; i < 2; ++i)
    #pragma unroll
    for (int j = 0; j < 4; ++j) acc[i][j] = (f32x4)0.f;

  for (int ks = 0; ks < 4; ++ks) {
    __syncthreads();
    {
      int r = tid >> 1, off = (tid & 1) * 16;
      size_t ua = ((size_t)b * DI + ph * 128 + r) * LSEQ + ch * CL + ks * 32 + off;
      bf16x8 u0 = *(const bf16x8*)&Ut[ua];
      bf16x8 u1 = *(const bf16x8*)&Ut[ua + 8];
      *(bf16x8*)&sX[r * 40 + off]     = u0;
      *(bf16x8*)&sX[r * 40 + off + 8] = u1;
    }
    __syncthreads();
    bf16x8 af[2], bfr[4];
    #pragma unroll
    for (int i = 0; i < 2; ++i)
      af[i] = *(const bf16x8*)&sW[(wn + i * 16 + c) * 144 + ks * 32 + q * 8];
    #pragma unroll
    for (int j = 0; j < 4; ++j)
      bfr[j] = *(const bf16x8*)&sX[(wp + j * 16 + c) * 40 + q * 8];
    #pragma unroll
    for (int i = 0; i < 2; ++i)
      #pragma unroll
      for (int j = 0; j < 4; ++j)
        acc[i][j] = __builtin_amdgcn_mfma_f32_16x16x32_bf16(af[i], bfr[j], acc[i][j], 0, 0, 0);
  }
  #pragma unroll
  for (int i = 0; i < 2; ++i) {
    int n = wn + i * 16 + q * 4;
    #pragma unroll
    for (int j = 0; j < 4; ++j) {
      int pg = ph * 128 + wp + j * 16 + c;
      #pragma unroll
      for (int r = 0; r < 4; ++r)
        hst[((size_t)bc * DS + n + r) * DI + pg] = acc[i][j][r];
    }
  }
}

// combine: sequential over chunks; outputs carry-in states hin[bc][p][n] bf16
// grid (8 p-tiles of 64, 4 n-tiles of 16, NB), block 256.
__global__ __launch_bounds__(256) void combine2(const float* __restrict__ hst,
    const float* __restrict__ csumb, const float* __restrict__ alog,
    ushort_t* __restrict__ hin) {
  __shared__ ushort_t ts[64 * 17];
  int tid = threadIdx.x;
  int pt = blockIdx.x, nt = blockIdx.y, b = blockIdx.z;
  int p0 = pt * 64, n0 = nt * 16;
  int pl = tid & 63, ng = tid >> 6;   // thread: p = p0+pl, n = n0 + ng*4 + i
  float Aval = -expf(alog[0]);
  float h[4];
  #pragma unroll
  for (int i = 0; i < 4; ++i) h[i] = 0.f;
  for (int c = 0; c < NC; ++c) {
    int bc = b * NC + c;
    #pragma unroll
    for (int i = 0; i < 4; ++i)
      ts[pl * 17 + ng * 4 + i] = f2bf(h[i]);
    __syncthreads();
    {
      int on = tid & 15;
      #pragma unroll
      for (int pass = 0; pass < 4; ++pass) {
        int op = (tid >> 4) + pass * 16;
        hin[((size_t)bc * DI + p0 + op) * DS + n0 + on] = ts[op * 17 + on];
      }
    }
    __syncthreads();
    float Sc = csumb[(size_t)b * LSEQ + c * CL + CL - 1];
    float dec = __expf(Aval * Sc);
    #pragma unroll
    for (int i = 0; i < 4; ++i) {
      float loc = hst[((size_t)bc * DS + n0 + ng * 4 + i) * DI + p0 + pl];
      h[i] = h[i] * dec + loc;
    }
  }
}

// y GEMM: G=C@B^T -> M masked-decayed -> Y = M@U + Chat@Hin; y = Y + dp*x (bf16)
// grid (4 p-tiles of 128, NC, NB), block 256.
__global__ __launch_bounds__(256) void y_gemm(const ushort_t* __restrict__ Bb,
    const ushort_t* __restrict__ Cb, const ushort_t* __restrict__ Ut,
    const ushort_t* __restrict__ hin, const float* __restrict__ csumb,
    const float* __restrict__ alog, const float* __restrict__ dpar,
    const ushort_t* __restrict__ xb, ushort_t* __restrict__ y) {
  __shared__ short sC[128 * 72];
  __shared__ short sM[128 * 136];  // phase2a: M str 136; phase2b: Chat str 80
  __shared__ short sU[128 * 80];   // phase1: B str 80; phase2: U/Hin slices str 40
  __shared__ float scs[128];
  int tid = threadIdx.x;
  int ph = blockIdx.x, ch = blockIdx.y, b = blockIdx.z;
  int bc = b * NC + ch;
  size_t tb = (size_t)b * LSEQ + ch * CL;
  float Aval = -expf(alog[0]);
  float dp = dpar[0];
  int wave = tid >> 6, lane = tid & 63;
  int q = lane >> 4, c = lane & 15;

  {
    int r = tid >> 1, off = (tid & 1) * 32;
    #pragma unroll
    for (int blk = 0; blk < 4; ++blk) {
      *(bf16x8*)&sC[r * 72 + off + blk * 8] = *(const bf16x8*)&Cb[(tb + r) * DS + off + blk * 8];
      *(bf16x8*)&sU[r * 80 + off + blk * 8] = *(const bf16x8*)&Bb[(tb + r) * DS + off + blk * 8];
    }
  }
  if (tid < 128) scs[tid] = csumb[tb + tid];
  __syncthreads();

  // phase 1: G = C @ B^T (128t x 128s, K=64)
  {
    int wm = (wave >> 1) * 64, wss = (wave & 1) * 64;
    f32x4 g[4][4];
    #pragma unroll
    for (int i = 0; i < 4; ++i)
      #pragma unroll
      for (int j = 0; j < 4; ++j) g[i][j] = (f32x4)0.f;
    #pragma unroll
    for (int k0 = 0; k0 < 64; k0 += 32) {
      bf16x8 af[4], bfr[4];
      #pragma unroll
      for (int i = 0; i < 4; ++i)
        af[i] = *(const bf16x8*)&sC[(wm + i * 16 + c) * 72 + k0 + q * 8];
      #pragma unroll
      for (int j = 0; j < 4; ++j)
        bfr[j] = *(const bf16x8*)&sU[(wss + j * 16 + c) * 80 + k0 + q * 8];
      #pragma unroll
      for (int i = 0; i < 4; ++i)
        #pragma unroll
        for (int j = 0; j < 4; ++j)
          g[i][j] = __builtin_amdgcn_mfma_f32_16x16x32_bf16(af[i], bfr[j], g[i][j], 0, 0, 0);
    }
    #pragma unroll
    for (int i = 0; i < 4; ++i) {
      #pragma unroll
      for (int r = 0; r < 4; ++r) {
        int t = wm + i * 16 + q * 4 + r;
        float ct = scs[t];
        #pragma unroll
        for (int j = 0; j < 4; ++j) {
          int s = wss + j * 16 + c;
          float v = g[i][j][r];
          float m = (s <= t) ? v * __expf(Aval * (ct - scs[s])) : 0.f;
          sM[t * 136 + s] = (short)f2bf(m);
        }
      }
    }
  }

  // phase 2: Y (128t x 128p) = M @ U + Chat @ Hin
  int wm2 = (wave >> 1) * 64, wp = (wave & 1) * 64;
  f32x4 acc[4][4];
  #pragma unroll
  for (int i = 0; i < 4; ++i)
    #pragma unroll
    for (int j = 0; j < 4; ++j) acc[i][j] = (f32x4)0.f;

  for (int ks = 0; ks < 4; ++ks) {
    __syncthreads();   // covers M-writes (ks=0) / prior sU reads
    {
      int r = tid >> 1, off = (tid & 1) * 16;
      size_t ua = ((size_t)b * DI + ph * 128 + r) * LSEQ + ch * CL + ks * 32 + off;
      bf16x8 u0 = *(const bf16x8*)&Ut[ua];
      bf16x8 u1 = *(const bf16x8*)&Ut[ua + 8];
      *(bf16x8*)&sU[r * 40 + off]     = u0;
      *(bf16x8*)&sU[r * 40 + off + 8] = u1;
    }
    __syncthreads();
    bf16x8 af[4], bfr[4];
    #pragma unroll
    for (int i = 0; i < 4; ++i)
      af[i] = *(const bf16x8*)&sM[(wm2 + i * 16 + c) * 136 + ks * 32 + q * 8];
    #pragma unroll
    for (int j = 0; j < 4; ++j)
      bfr[j] = *(const bf16x8*)&sU[(wp + j * 16 + c) * 40 + q * 8];
    #pragma unroll
    for (int i = 0; i < 4; ++i)
      #pragma unroll
      for (int j = 0; j < 4; ++j)
        acc[i][j] = __builtin_amdgcn_mfma_f32_16x16x32_bf16(af[i], bfr[j], acc[i][j], 0, 0, 0);
  }

  // build Chat[t][n] = exp(A*cs[t]) * C[t][n] into sM (str 80)
  __syncthreads();
  {
    int r = tid >> 1, off = (tid & 1) * 32;
    float sc_t = __expf(Aval * scs[r]);
    #pragma unroll
    for (int blk = 0; blk < 4; ++blk) {
      bf16x8 v = *(const bf16x8*)&sC[r * 72 + off + blk * 8];
      bf16x8 o;
      #pragma unroll
      for (int e = 0; e < 8; ++e)
        o[e] = (short)f2bf(bf2f((ushort_t)v[e]) * sc_t);
      *(bf16x8*)&sM[r * 80 + off + blk * 8] = o;
    }
  }
  for (int ks = 4; ks < 6; ++ks) {
    __syncthreads();
    {
      int r = tid >> 1, off = (tid & 1) * 16;
      size_t ha = ((size_t)bc * DI + ph * 128 + r) * DS + (ks - 4) * 32 + off;
      bf16x8 h0 = *(const bf16x8*)&hin[ha];
      bf16x8 h1 = *(const bf16x8*)&hin[ha + 8];
      *(bf16x8*)&sU[r * 40 + off]     = h0;
      *(bf16x8*)&sU[r * 40 + off + 8] = h1;
    }
    __syncthreads();
    bf16x8 af[4], bfr[4];
    #pragma unroll
    for (int i = 0; i < 4; ++i)
      af[i] = *(const bf16x8*)&sM[(wm2 + i * 16 + c) * 80 + (ks - 4) * 32 + q * 8];
    #pragma unroll
    for (int j = 0; j < 4; ++j)
      bfr[j] = *(const bf16x8*)&sU[(wp + j * 16 + c) * 40 + q * 8];
    #pragma unroll
    for (int i = 0; i < 4; ++i)
      #pragma unroll
      for (int j = 0; j < 4; ++j)
        acc[i][j] = __builtin_amdgcn_mfma_f32_16x16x32_bf16(af[i], bfr[j], acc[i][j], 0, 0, 0);
  }

  #pragma unroll
  for (int i = 0; i < 4; ++i) {
    #pragma unroll
    for (int r = 0; r < 4; ++r) {
      int t = wm2 + i * 16 + q * 4 + r;
      size_t row = (tb + t) * DI;
      #pragma unroll
      for (int j = 0; j < 4; ++j) {
        int pg = ph * 128 + wp + j * 16 + c;
        y[row + pg] = f2bf(acc[i][j][r] + dp * bf2f(xb[row + pg]));
      }
    }
  }
}

// y = rmsnorm(y * silu(z)) * w   (z = zx[...,0:512] bf16), y bf16 in/out
__global__ __launch_bounds__(256) void gated_rmsnorm(ushort_t* __restrict__ y,
    const ushort_t* __restrict__ zx, const float* __restrict__ w) {
  int t = blockIdx.x, tid = threadIdx.x;
  const ushort_t* zr = zx + (size_t)t * DIPP;
  ushort_t* yr = y + (size_t)t * DI;
  int c0 = tid, c1 = tid + 256;
  float z0 = bf2f(zr[c0]), z1 = bf2f(zr[c1]);
  float g0 = bf2f(yr[c0]) * (z0 / (1.f + __expf(-z0)));
  float g1 = bf2f(yr[c1]) * (z1 / (1.f + __expf(-z1)));
  float ss = block_reduce_sum256(g0 * g0 + g1 * g1);
  float r = rsqrtf(ss * (1.f / DI) + 1e-5f);
  yr[c0] = f2bf(g0 * r * w[c0]);
  yr[c1] = f2bf(g1 * r * w[c1]);
}

// last token only
__global__ __launch_bounds__(256) void finalize(const float* __restrict__ resid,
    const float* __restrict__ mixo, const float* __restrict__ embed,
    const float* __restrict__ nfw, float* __restrict__ out) {
  int b = blockIdx.x, tid = threadIdx.x;
  __shared__ float fin[DM];
  size_t off = ((size_t)b * LSEQ + (LSEQ - 1)) * DM;
  float r = resid[off + tid] + mixo[off + tid];
  float ss = block_reduce_sum256(r * r);
  fin[tid] = r * rsqrtf(ss * (1.f / DM) + 1e-5f) * nfw[tid];
  __syncthreads();
  if (tid < VOC) {
    float acc = 0.f;
    #pragma unroll 8
    for (int d = 0; d < DM; ++d) acc += fin[d] * embed[(size_t)tid * DM + d];
    out[b * VOC + tid] = acc;
  }
}

extern "C" void kernel_launch(void* const* d_in, const int* in_sizes, int n_in,
                              void* d_out, int out_size, void* d_ws, size_t ws_size,
                              hipStream_t stream) {
  const int*   ids   = (const int*)d_in[0];
  const float* embed = (const float*)d_in[1];
  const float* ipw   = (const float*)d_in[2];
  const float* cw    = (const float*)d_in[3];
  const float* cb    = (const float*)d_in[4];
  const float* dtbias= (const float*)d_in[5];
  const float* alog  = (const float*)d_in[6];
  const float* dpar  = (const float*)d_in[7];
  const float* ngw   = (const float*)d_in[8];
  const float* opw   = (const float*)d_in[9];
  const float* bnw   = (const float*)d_in[10];
  const float* nfw   = (const float*)d_in[11];
  float* out = (float*)d_out;

  // workspace layout (~152 MB)
  char* p = (char*)d_ws;
  float* resid = (float*)p;            p += (size_t)TKN * DM * 4;
  float* mixo  = (float*)p;            p += (size_t)TKN * DM * 4;
  ushort_t* hn = (ushort_t*)p;         p += (size_t)TKN * DM * 2;
  ushort_t* zx = (ushort_t*)p;         p += (size_t)TKN * DIPP * 2;
  float* dtb   = (float*)p;            p += (size_t)TKN * 4;
  float* csumb = (float*)p;            p += (size_t)TKN * 4;
  ushort_t* xb = (ushort_t*)p;         p += (size_t)TKN * DI * 2;
  ushort_t* yb = (ushort_t*)p;         p += (size_t)TKN * DI * 2;
  ushort_t* Bb = (ushort_t*)p;         p += (size_t)TKN * DS * 2;
  ushort_t* Cb = (ushort_t*)p;         p += (size_t)TKN * DS * 2;
  ushort_t* Ut = (ushort_t*)p;         p += (size_t)TKN * DI * 2;
  ushort_t* hin= (ushort_t*)p;         p += (size_t)NB * NC * DI * DS * 2;
  // hst (fp32) aliases yb (bf16): consumed by combine2 before y_gemm writes yb
  float* hst = (float*)yb;

  embed_init<<<TKN, 256, 0, stream>>>(ids, embed, mixo, resid);

  for (int i = 0; i < NL; ++i) {
    add_rmsnorm<<<TKN, 256, 0, stream>>>(resid, mixo, hn, bnw + (size_t)i * DM);
    gemm_nt_mfma<ushort_t, ushort_t><<<dim3((DIP + 127) / 128, TKN / 128), 256, 0, stream>>>(
        hn, ipw + (size_t)i * DIP * DM, zx, DIP, DM, DIPP);
    csum_k<<<32, 256, 0, stream>>>(zx, dtbias + i, dtb, csumb);
    conv_silu<<<dim3(CDIM / 128, LSEQ / 64, NB), 256, 0, stream>>>(
        zx, cw + (size_t)i * CDIM * 4, cb + (size_t)i * CDIM, xb, Bb, Cb);
    transpose_u<<<dim3(DI / 64, LSEQ / 64, NB), 256, 0, stream>>>(xb, dtb, Ut);
    state_gemm<<<dim3(4, NC, NB), 256, 0, stream>>>(Bb, Ut, csumb, alog + i, hst);
    combine2<<<dim3(DI / 64, 4, NB), 256, 0, stream>>>(hst, csumb, alog + i, hin);
    y_gemm<<<dim3(4, NC, NB), 256, 0, stream>>>(Bb, Cb, Ut, hin, csumb, alog + i,
                                                dpar + i, xb, yb);
    gated_rmsnorm<<<TKN, 256, 0, stream>>>(yb, zx, ngw + (size_t)i * DI);
    gemm_nt_mfma<ushort_t, float><<<dim3(DM / 128, TKN / 128), 256, 0, stream>>>(
        yb, opw + (size_t)i * DM * DI, mixo, DM, DI, DM);
  }

  finalize<<<NB, 256, 0, stream>>>(resid, mixo, embed, nfw, out);
}

// Round 6
// 706.632 us; speedup vs baseline: 2.9564x; 1.0215x over previous
//
#include <hip/hip_runtime.h>
#include <math.h>

// ---- problem constants ----
#define NB    8        // batch
#define LSEQ  2048     // seq len
#define TKN   16384    // NB*LSEQ tokens
#define DM    256      // d_model
#define DI    512      // d_inner
#define DS    64       // d_state
#define DIP   1153     // 2*DI + 2*DS + 1
#define DIPP  1160     // padded row stride for zx (bf16)
#define CDIM  640      // DI + 2*DS
#define NL    4
#define NC    16       // scan chunks
#define CL    128      // LSEQ/NC
#define VOC   100

typedef short bf16x8 __attribute__((ext_vector_type(8)));
typedef short bf16x4 __attribute__((ext_vector_type(4)));
typedef float f32x4  __attribute__((ext_vector_type(4)));
typedef unsigned short ushort_t;

__device__ __forceinline__ float block_reduce_sum256(float v) {
  __shared__ float sred[4];
  #pragma unroll
  for (int off = 32; off > 0; off >>= 1) v += __shfl_down(v, off, 64);
  int lane = threadIdx.x & 63, wid = threadIdx.x >> 6;
  if (lane == 0) sred[wid] = v;
  __syncthreads();
  return sred[0] + sred[1] + sred[2] + sred[3];
}

__device__ __forceinline__ unsigned short f2bf(float f) {
  unsigned int u = __float_as_uint(f);
  unsigned int r = u + 0x7FFFu + ((u >> 16) & 1u);   // RNE
  return (unsigned short)(r >> 16);
}
__device__ __forceinline__ float bf2f(unsigned short u) {
  return __uint_as_float(((unsigned int)u) << 16);
}

// convert fp32 weights -> bf16 once per call
__global__ __launch_bounds__(256) void convert_w(const float* __restrict__ ipw,
    const float* __restrict__ opw, ushort_t* __restrict__ wbi, ushort_t* __restrict__ wbo) {
  const int n1 = NL * DIP * DM;      // 1,180,672
  const int n2 = NL * DM * DI;       // 524,288
  int i4 = (blockIdx.x * 256 + threadIdx.x) * 4;
  if (i4 < n1) {
    float4 v = *(const float4*)(ipw + i4);
    bf16x4 o; o[0] = (short)f2bf(v.x); o[1] = (short)f2bf(v.y);
    o[2] = (short)f2bf(v.z); o[3] = (short)f2bf(v.w);
    *(bf16x4*)(wbi + i4) = o;
  } else {
    int j = i4 - n1;
    if (j < n2) {
      float4 v = *(const float4*)(opw + j);
      bf16x4 o; o[0] = (short)f2bf(v.x); o[1] = (short)f2bf(v.y);
      o[2] = (short)f2bf(v.z); o[3] = (short)f2bf(v.w);
      *(bf16x4*)(wbo + j) = o;
    }
  }
}

// mixo = embed[ids], resid = 0
__global__ __launch_bounds__(256) void embed_init(const int* __restrict__ ids,
    const float* __restrict__ embed, float* __restrict__ mixo, float* __restrict__ resid) {
  int t = blockIdx.x, tid = threadIdx.x;
  int id = ids[t];
  mixo[(size_t)t * DM + tid] = embed[(size_t)id * DM + tid];
  resid[(size_t)t * DM + tid] = 0.f;
}

// resid += mixo; hn = bf16(rmsnorm(resid)*w)
__global__ __launch_bounds__(256) void add_rmsnorm(float* __restrict__ resid,
    const float* __restrict__ mixo, ushort_t* __restrict__ hn, const float* __restrict__ w) {
  int t = blockIdx.x, tid = threadIdx.x;
  size_t o = (size_t)t * DM + tid;
  float r = resid[o] + mixo[o];
  resid[o] = r;
  float ss = block_reduce_sum256(r * r);
  hn[o] = f2bf(r * rsqrtf(ss * (1.f / DM) + 1e-5f) * w[tid]);
}

// ---------------- bf16 MFMA GEMM (A bf16, B bf16) ----------------
// C[M,N](row stride ldc) = A[M,K] @ Bw[N,K]^T. Tile 128x128, BK=32, block 256.
#define LSTR 40
template<typename TC>
__global__ __launch_bounds__(256) void gemm_nt_bf16(const ushort_t* __restrict__ A,
    const ushort_t* __restrict__ Bw, TC* __restrict__ C, int N, int K, int ldc) {
  __shared__ short sA[128 * LSTR];
  __shared__ short sB[128 * LSTR];
  int tid = threadIdx.x;
  int bn = blockIdx.x * 128;
  int bm = blockIdx.y * 128;
  int wave = tid >> 6, lane = tid & 63;
  int wm = (wave >> 1) * 64, wn = (wave & 1) * 64;
  int q = lane >> 4, c = lane & 15;

  f32x4 acc[4][4];
  #pragma unroll
  for (int i = 0; i < 4; ++i)
    #pragma unroll
    for (int j = 0; j < 4; ++j) acc[i][j] = (f32x4)0.f;

  int sr = tid >> 1;
  int sc = (tid & 1) * 16;
  const ushort_t* Ag = A + (size_t)(bm + sr) * K + sc;
  const ushort_t* Bg = Bw + (size_t)(bn + sr) * K + sc;
  bool bok = (bn + sr) < N;
  short* sAp = &sA[sr * LSTR + sc];
  short* sBp = &sB[sr * LSTR + sc];

  for (int k0 = 0; k0 < K; k0 += 32) {
    bf16x8 a0 = *(const bf16x8*)(Ag + k0);
    bf16x8 a1 = *(const bf16x8*)(Ag + k0 + 8);
    bf16x8 b0 = (bf16x8)(short)0, b1 = (bf16x8)(short)0;
    if (bok) {
      b0 = *(const bf16x8*)(Bg + k0);
      b1 = *(const bf16x8*)(Bg + k0 + 8);
    }
    __syncthreads();
    *(bf16x8*)(sAp)     = a0;
    *(bf16x8*)(sAp + 8) = a1;
    *(bf16x8*)(sBp)     = b0;
    *(bf16x8*)(sBp + 8) = b1;
    __syncthreads();
    bf16x8 af[4], bfr[4];
    #pragma unroll
    for (int i = 0; i < 4; ++i)
      af[i] = *(const bf16x8*)&sA[(wm + i * 16 + c) * LSTR + q * 8];
    #pragma unroll
    for (int j = 0; j < 4; ++j)
      bfr[j] = *(const bf16x8*)&sB[(wn + j * 16 + c) * LSTR + q * 8];
    #pragma unroll
    for (int i = 0; i < 4; ++i)
      #pragma unroll
      for (int j = 0; j < 4; ++j)
        acc[i][j] = __builtin_amdgcn_mfma_f32_16x16x32_bf16(af[i], bfr[j], acc[i][j], 0, 0, 0);
  }
  #pragma unroll
  for (int i = 0; i < 4; ++i) {
    int m = bm + wm + i * 16 + q * 4;
    #pragma unroll
    for (int j = 0; j < 4; ++j) {
      int n = bn + wn + j * 16 + c;
      if (n < N) {
        #pragma unroll
        for (int r = 0; r < 4; ++r) {
          if constexpr (sizeof(TC) == 2)
            C[(size_t)(m + r) * ldc + n] = (TC)f2bf(acc[i][j][r]);
          else
            C[(size_t)(m + r) * ldc + n] = acc[i][j][r];
        }
      }
    }
  }
}

// fused out_proj: C = rownorm * ((y*silu(z))*w) @ Wb^T ; grid (2, TKN/128), block 256.
// N = DM = 256, K = DI = 512 fixed.
__global__ __launch_bounds__(256) void outproj_fused(const ushort_t* __restrict__ yb,
    const ushort_t* __restrict__ zx, const ushort_t* __restrict__ Bw,
    const float* __restrict__ gw, float* __restrict__ Cout) {
  __shared__ short sA[128 * LSTR];
  __shared__ short sB[128 * LSTR];
  __shared__ float swl[DI];
  __shared__ float rs[256];
  int tid = threadIdx.x;
  int bn = blockIdx.x * 128;
  int bm = blockIdx.y * 128;
  int wave = tid >> 6, lane = tid & 63;
  int wm = (wave >> 1) * 64, wn = (wave & 1) * 64;
  int q = lane >> 4, c = lane & 15;
  swl[tid] = gw[tid];
  swl[tid + 256] = gw[tid + 256];

  f32x4 acc[4][4];
  #pragma unroll
  for (int i = 0; i < 4; ++i)
    #pragma unroll
    for (int j = 0; j < 4; ++j) acc[i][j] = (f32x4)0.f;

  int sr = tid >> 1;
  int sc = (tid & 1) * 16;
  const ushort_t* yrow = yb + (size_t)(bm + sr) * DI + sc;
  const ushort_t* zrow = zx + (size_t)(bm + sr) * DIPP + sc;
  const ushort_t* Bg = Bw + (size_t)(bn + sr) * DI + sc;
  short* sAp = &sA[sr * LSTR + sc];
  short* sBp = &sB[sr * LSTR + sc];
  float sumsq = 0.f;
  __syncthreads();   // swl visible

  for (int k0 = 0; k0 < DI; k0 += 32) {
    bf16x8 y0 = *(const bf16x8*)(yrow + k0);
    bf16x8 y1 = *(const bf16x8*)(yrow + k0 + 8);
    bf16x8 z0 = *(const bf16x8*)(zrow + k0);
    bf16x8 z1 = *(const bf16x8*)(zrow + k0 + 8);
    bf16x8 b0 = *(const bf16x8*)(Bg + k0);
    bf16x8 b1 = *(const bf16x8*)(Bg + k0 + 8);
    bf16x8 g0, g1;
    #pragma unroll
    for (int e = 0; e < 8; ++e) {
      float zz0 = bf2f((ushort_t)z0[e]);
      float gg0 = bf2f((ushort_t)y0[e]) * (zz0 / (1.f + __expf(-zz0)));
      sumsq += gg0 * gg0;
      g0[e] = (short)f2bf(gg0 * swl[k0 + sc + e]);
      float zz1 = bf2f((ushort_t)z1[e]);
      float gg1 = bf2f((ushort_t)y1[e]) * (zz1 / (1.f + __expf(-zz1)));
      sumsq += gg1 * gg1;
      g1[e] = (short)f2bf(gg1 * swl[k0 + sc + 8 + e]);
    }
    __syncthreads();
    *(bf16x8*)(sAp)     = g0;
    *(bf16x8*)(sAp + 8) = g1;
    *(bf16x8*)(sBp)     = b0;
    *(bf16x8*)(sBp + 8) = b1;
    __syncthreads();
    bf16x8 af[4], bfr[4];
    #pragma unroll
    for (int i = 0; i < 4; ++i)
      af[i] = *(const bf16x8*)&sA[(wm + i * 16 + c) * LSTR + q * 8];
    #pragma unroll
    for (int j = 0; j < 4; ++j)
      bfr[j] = *(const bf16x8*)&sB[(wn + j * 16 + c) * LSTR + q * 8];
    #pragma unroll
    for (int i = 0; i < 4; ++i)
      #pragma unroll
      for (int j = 0; j < 4; ++j)
        acc[i][j] = __builtin_amdgcn_mfma_f32_16x16x32_bf16(af[i], bfr[j], acc[i][j], 0, 0, 0);
  }
  rs[tid] = sumsq;     // rs[sr*2 + (tid&1)]
  __syncthreads();
  #pragma unroll
  for (int i = 0; i < 4; ++i) {
    #pragma unroll
    for (int r = 0; r < 4; ++r) {
      int ml = wm + i * 16 + q * 4 + r;
      float rtot = rs[ml * 2] + rs[ml * 2 + 1];
      float scale = rsqrtf(rtot * (1.f / DI) + 1e-5f);
      #pragma unroll
      for (int j = 0; j < 4; ++j) {
        int n = bn + wn + j * 16 + c;
        Cout[(size_t)(bm + ml) * DM + n] = scale * acc[i][j][r];
      }
    }
  }
}

// LDS-tiled conv(4)+bias+silu, fused with U^T = dt*x transpose.
// grid (CDIM/128, LSEQ/64, NB), block 256. Tile: 64 tokens x 128 channels.
__global__ __launch_bounds__(256) void conv_silu(const ushort_t* __restrict__ zx,
    const float* __restrict__ cw, const float* __restrict__ cb,
    const float* __restrict__ dtb, ushort_t* __restrict__ xo,
    ushort_t* __restrict__ Bo, ushort_t* __restrict__ Co, ushort_t* __restrict__ Ut) {
  __shared__ float tile[67 * 128];
  __shared__ ushort_t tt[128 * 65];
  __shared__ float sdt[64];
  int tid = threadIdx.x;
  int ct = blockIdx.x, tb_ = blockIdx.y, b = blockIdx.z;
  int c0 = ct * 128;
  int l0 = tb_ * 64;
  size_t rowb = (size_t)b * LSEQ;
  int cl = tid & 127;
  int cg = c0 + cl;
  for (int tr = tid >> 7; tr < 67; tr += 2) {
    int l = l0 + tr - 3;
    float v = 0.f;
    if (l >= 0) v = bf2f(zx[(rowb + l) * DIPP + DI + cg]);
    tile[tr * 128 + cl] = v;
  }
  if (tid < 64) sdt[tid] = dtb[rowb + l0 + tid];
  float w0 = cw[cg * 4 + 0], w1 = cw[cg * 4 + 1];
  float w2 = cw[cg * 4 + 2], w3 = cw[cg * 4 + 3];
  float bias = cb[cg];
  __syncthreads();
  bool isx = (ct < 4);
  int tg = tid >> 7;
  #pragma unroll 4
  for (int t2 = 0; t2 < 32; ++t2) {
    int t = tg * 32 + t2;
    float s = bias + w0 * tile[t * 128 + cl] + w1 * tile[(t + 1) * 128 + cl]
                   + w2 * tile[(t + 2) * 128 + cl] + w3 * tile[(t + 3) * 128 + cl];
    float v = s / (1.f + __expf(-s));
    size_t tl = rowb + l0 + t;
    if (isx) {
      xo[tl * DI + cg] = f2bf(v);
      tt[cl * 65 + t] = f2bf(v * sdt[t]);
    } else if (cg < DI + DS) {
      Bo[tl * DS + (cg - DI)] = f2bf(v);
    } else {
      Co[tl * DS + (cg - DI - DS)] = f2bf(v);
    }
  }
  if (isx) {
    __syncthreads();
    int os = tid & 63;
    #pragma unroll
    for (int pass = 0; pass < 32; ++pass) {
      int op = (tid >> 6) + pass * 4;
      Ut[((size_t)b * DI + c0 + op) * LSEQ + l0 + os] = tt[op * 65 + os];
    }
  }
}

// dt = softplus(dt_raw + bias); per-chunk inclusive prefix sum. one wave per chunk.
__global__ __launch_bounds__(256) void csum_k(const ushort_t* __restrict__ zx,
    const float* __restrict__ dtbias, float* __restrict__ dtb, float* __restrict__ csumb) {
  int tid = threadIdx.x;
  int wave = tid >> 6, lane = tid & 63;
  int cg = blockIdx.x * 4 + wave;
  int b = cg >> 4, ch = cg & 15;
  size_t base = (size_t)b * LSEQ + ch * CL;
  float bias = dtbias[0];
  float x0 = bf2f(zx[(base + 2 * lane) * DIPP + (DIP - 1)]) + bias;
  float x1 = bf2f(zx[(base + 2 * lane + 1) * DIPP + (DIP - 1)]) + bias;
  float d0 = (x0 > 20.f) ? x0 : log1pf(__expf(x0));
  float d1 = (x1 > 20.f) ? x1 : log1pf(__expf(x1));
  dtb[base + 2 * lane] = d0;
  dtb[base + 2 * lane + 1] = d1;
  float p = d0 + d1;
  #pragma unroll
  for (int off = 1; off < 64; off <<= 1) {
    float t = __shfl_up(p, off, 64);
    if (lane >= off) p += t;
  }
  csumb[base + 2 * lane]     = p - d1;
  csumb[base + 2 * lane + 1] = p;
}

// state GEMM: Hloc[bc][n][p] = sum_s exp(A(S - cs[s])) * B[s][n] * U[s][p]
// grid (4, NC, NB), block 256. Tile n=64, p=128, K=128.
__global__ __launch_bounds__(256) void state_gemm(const ushort_t* __restrict__ Bb,
    const ushort_t* __restrict__ Ut, const float* __restrict__ csumb,
    const float* __restrict__ alog, float* __restrict__ hst) {
  __shared__ short sW[64 * 144];
  __shared__ short sX[128 * 40];
  __shared__ float scs[128];
  int tid = threadIdx.x;
  int ph = blockIdx.x, ch = blockIdx.y, b = blockIdx.z;
  int bc = b * NC + ch;
  size_t tb = (size_t)b * LSEQ + ch * CL;
  float Aval = -expf(alog[0]);
  if (tid < 128) scs[tid] = csumb[tb + tid];
  __syncthreads();
  float Stot = scs[127];
  {
    int s = tid >> 1, noff = (tid & 1) * 32;
    float scale = __expf(Aval * (Stot - scs[s]));
    #pragma unroll
    for (int blk = 0; blk < 4; ++blk) {
      bf16x8 v = *(const bf16x8*)&Bb[(tb + s) * DS + noff + blk * 8];
      #pragma unroll
      for (int e = 0; e < 8; ++e)
        sW[(noff + blk * 8 + e) * 144 + s] = (short)f2bf(bf2f((ushort_t)v[e]) * scale);
    }
  }
  int wave = tid >> 6, lane = tid & 63;
  int wn = (wave >> 1) * 32, wp = (wave & 1) * 64;
  int q = lane >> 4, c = lane & 15;
  f32x4 acc[2][4];
  #pragma unroll
  for (int i = 0; i < 2; ++i)
    #pragma unroll
    for (int j = 0; j < 4; ++j) acc[i][j] = (f32x4)0.f;

  for (int ks = 0; ks < 4; ++ks) {
    __syncthreads();
    {
      int r = tid >> 1, off = (tid & 1) * 16;
      size_t ua = ((size_t)b * DI + ph * 128 + r) * LSEQ + ch * CL + ks * 32 + off;
      bf16x8 u0 = *(const bf16x8*)&Ut[ua];
      bf16x8 u1 = *(const bf16x8*)&Ut[ua + 8];
      *(bf16x8*)&sX[r * 40 + off]     = u0;
      *(bf16x8*)&sX[r * 40 + off + 8] = u1;
    }
    __syncthreads();
    bf16x8 af[2], bfr[4];
    #pragma unroll
    for (int i = 0; i < 2; ++i)
      af[i] = *(const bf16x8*)&sW[(wn + i * 16 + c) * 144 + ks * 32 + q * 8];
    #pragma unroll
    for (int j = 0; j < 4; ++j)
      bfr[j] = *(const bf16x8*)&sX[(wp + j * 16 + c) * 40 + q * 8];
    #pragma unroll
    for (int i = 0; i < 2; ++i)
      #pragma unroll
      for (int j = 0; j < 4; ++j)
        acc[i][j] = __builtin_amdgcn_mfma_f32_16x16x32_bf16(af[i], bfr[j], acc[i][j], 0, 0, 0);
  }
  #pragma unroll
  for (int i = 0; i < 2; ++i) {
    int n = wn + i * 16 + q * 4;
    #pragma unroll
    for (int j = 0; j < 4; ++j) {
      int pg = ph * 128 + wp + j * 16 + c;
      #pragma unroll
      for (int r = 0; r < 4; ++r)
        hst[((size_t)bc * DS + n + r) * DI + pg] = acc[i][j][r];
    }
  }
}

// combine: sequential over chunks; outputs carry-in states hin[bc][p][n] bf16
// grid (8 p-tiles of 64, 4 n-tiles of 16, NB), block 256.
__global__ __launch_bounds__(256) void combine2(const float* __restrict__ hst,
    const float* __restrict__ csumb, const float* __restrict__ alog,
    ushort_t* __restrict__ hin) {
  __shared__ ushort_t ts[64 * 17];
  int tid = threadIdx.x;
  int pt = blockIdx.x, nt = blockIdx.y, b = blockIdx.z;
  int p0 = pt * 64, n0 = nt * 16;
  int pl = tid & 63, ng = tid >> 6;
  float Aval = -expf(alog[0]);
  float h[4];
  #pragma unroll
  for (int i = 0; i < 4; ++i) h[i] = 0.f;
  for (int c = 0; c < NC; ++c) {
    int bc = b * NC + c;
    #pragma unroll
    for (int i = 0; i < 4; ++i)
      ts[pl * 17 + ng * 4 + i] = f2bf(h[i]);
    __syncthreads();
    {
      int on = tid & 15;
      #pragma unroll
      for (int pass = 0; pass < 4; ++pass) {
        int op = (tid >> 4) + pass * 16;
        hin[((size_t)bc * DI + p0 + op) * DS + n0 + on] = ts[op * 17 + on];
      }
    }
    __syncthreads();
    float Sc = csumb[(size_t)b * LSEQ + c * CL + CL - 1];
    float dec = __expf(Aval * Sc);
    #pragma unroll
    for (int i = 0; i < 4; ++i) {
      float loc = hst[((size_t)bc * DS + n0 + ng * 4 + i) * DI + p0 + pl];
      h[i] = h[i] * dec + loc;
    }
  }
}

// y GEMM: G=C@B^T -> M masked-decayed -> Y = M@U + Chat@Hin; y = Y + dp*x (bf16)
// grid (4 p-tiles of 128, NC, NB), block 256.
__global__ __launch_bounds__(256) void y_gemm(const ushort_t* __restrict__ Bb,
    const ushort_t* __restrict__ Cb, const ushort_t* __restrict__ Ut,
    const ushort_t* __restrict__ hin, const float* __restrict__ csumb,
    const float* __restrict__ alog, const float* __restrict__ dpar,
    const ushort_t* __restrict__ xb, ushort_t* __restrict__ y) {
  __shared__ short sC[128 * 72];
  __shared__ short sM[128 * 136];
  __shared__ short sU[128 * 80];
  __shared__ float scs[128];
  int tid = threadIdx.x;
  int ph = blockIdx.x, ch = blockIdx.y, b = blockIdx.z;
  int bc = b * NC + ch;
  size_t tb = (size_t)b * LSEQ + ch * CL;
  float Aval = -expf(alog[0]);
  float dp = dpar[0];
  int wave = tid >> 6, lane = tid & 63;
  int q = lane >> 4, c = lane & 15;

  {
    int r = tid >> 1, off = (tid & 1) * 32;
    #pragma unroll
    for (int blk = 0; blk < 4; ++blk) {
      *(bf16x8*)&sC[r * 72 + off + blk * 8] = *(const bf16x8*)&Cb[(tb + r) * DS + off + blk * 8];
      *(bf16x8*)&sU[r * 80 + off + blk * 8] = *(const bf16x8*)&Bb[(tb + r) * DS + off + blk * 8];
    }
  }
  if (tid < 128) scs[tid] = csumb[tb + tid];
  __syncthreads();

  // phase 1: G = C @ B^T (128t x 128s, K=64)
  {
    int wm = (wave >> 1) * 64, wss = (wave & 1) * 64;
    f32x4 g[4][4];
    #pragma unroll
    for (int i = 0; i < 4; ++i)
      #pragma unroll
      for (int j = 0; j < 4; ++j) g[i][j] = (f32x4)0.f;
    #pragma unroll
    for (int k0 = 0; k0 < 64; k0 += 32) {
      bf16x8 af[4], bfr[4];
      #pragma unroll
      for (int i = 0; i < 4; ++i)
        af[i] = *(const bf16x8*)&sC[(wm + i * 16 + c) * 72 + k0 + q * 8];
      #pragma unroll
      for (int j = 0; j < 4; ++j)
        bfr[j] = *(const bf16x8*)&sU[(wss + j * 16 + c) * 80 + k0 + q * 8];
      #pragma unroll
      for (int i = 0; i < 4; ++i)
        #pragma unroll
        for (int j = 0; j < 4; ++j)
          g[i][j] = __builtin_amdgcn_mfma_f32_16x16x32_bf16(af[i], bfr[j], g[i][j], 0, 0, 0);
    }
    #pragma unroll
    for (int i = 0; i < 4; ++i) {
      #pragma unroll
      for (int r = 0; r < 4; ++r) {
        int t = wm + i * 16 + q * 4 + r;
        float ct = scs[t];
        #pragma unroll
        for (int j = 0; j < 4; ++j) {
          int s = wss + j * 16 + c;
          float v = g[i][j][r];
          float m = (s <= t) ? v * __expf(Aval * (ct - scs[s])) : 0.f;
          sM[t * 136 + s] = (short)f2bf(m);
        }
      }
    }
  }

  // phase 2: Y (128t x 128p) = M @ U + Chat @ Hin
  int wm2 = (wave >> 1) * 64, wp = (wave & 1) * 64;
  f32x4 acc[4][4];
  #pragma unroll
  for (int i = 0; i < 4; ++i)
    #pragma unroll
    for (int j = 0; j < 4; ++j) acc[i][j] = (f32x4)0.f;

  for (int ks = 0; ks < 4; ++ks) {
    __syncthreads();
    {
      int r = tid >> 1, off = (tid & 1) * 16;
      size_t ua = ((size_t)b * DI + ph * 128 + r) * LSEQ + ch * CL + ks * 32 + off;
      bf16x8 u0 = *(const bf16x8*)&Ut[ua];
      bf16x8 u1 = *(const bf16x8*)&Ut[ua + 8];
      *(bf16x8*)&sU[r * 40 + off]     = u0;
      *(bf16x8*)&sU[r * 40 + off + 8] = u1;
    }
    __syncthreads();
    bf16x8 af[4], bfr[4];
    #pragma unroll
    for (int i = 0; i < 4; ++i)
      af[i] = *(const bf16x8*)&sM[(wm2 + i * 16 + c) * 136 + ks * 32 + q * 8];
    #pragma unroll
    for (int j = 0; j < 4; ++j)
      bfr[j] = *(const bf16x8*)&sU[(wp + j * 16 + c) * 40 + q * 8];
    #pragma unroll
    for (int i = 0; i < 4; ++i)
      #pragma unroll
      for (int j = 0; j < 4; ++j)
        acc[i][j] = __builtin_amdgcn_mfma_f32_16x16x32_bf16(af[i], bfr[j], acc[i][j], 0, 0, 0);
  }

  __syncthreads();
  {
    int r = tid >> 1, off = (tid & 1) * 32;
    float sc_t = __expf(Aval * scs[r]);
    #pragma unroll
    for (int blk = 0; blk < 4; ++blk) {
      bf16x8 v = *(const bf16x8*)&sC[r * 72 + off + blk * 8];
      bf16x8 o;
      #pragma unroll
      for (int e = 0; e < 8; ++e)
        o[e] = (short)f2bf(bf2f((ushort_t)v[e]) * sc_t);
      *(bf16x8*)&sM[r * 80 + off + blk * 8] = o;
    }
  }
  for (int ks = 4; ks < 6; ++ks) {
    __syncthreads();
    {
      int r = tid >> 1, off = (tid & 1) * 16;
      size_t ha = ((size_t)bc * DI + ph * 128 + r) * DS + (ks - 4) * 32 + off;
      bf16x8 h0 = *(const bf16x8*)&hin[ha];
      bf16x8 h1 = *(const bf16x8*)&hin[ha + 8];
      *(bf16x8*)&sU[r * 40 + off]     = h0;
      *(bf16x8*)&sU[r * 40 + off + 8] = h1;
    }
    __syncthreads();
    bf16x8 af[4], bfr[4];
    #pragma unroll
    for (int i = 0; i < 4; ++i)
      af[i] = *(const bf16x8*)&sM[(wm2 + i * 16 + c) * 80 + (ks - 4) * 32 + q * 8];
    #pragma unroll
    for (int j = 0; j < 4; ++j)
      bfr[j] = *(const bf16x8*)&sU[(wp + j * 16 + c) * 40 + q * 8];
    #pragma unroll
    for (int i = 0; i < 4; ++i)
      #pragma unroll
      for (int j = 0; j < 4; ++j)
        acc[i][j] = __builtin_amdgcn_mfma_f32_16x16x32_bf16(af[i], bfr[j], acc[i][j], 0, 0, 0);
  }

  #pragma unroll
  for (int i = 0; i < 4; ++i) {
    #pragma unroll
    for (int r = 0; r < 4; ++r) {
      int t = wm2 + i * 16 + q * 4 + r;
      size_t row = (tb + t) * DI;
      #pragma unroll
      for (int j = 0; j < 4; ++j) {
        int pg = ph * 128 + wp + j * 16 + c;
        y[row + pg] = f2bf(acc[i][j][r] + dp * bf2f(xb[row + pg]));
      }
    }
  }
}

// last token only
__global__ __launch_bounds__(256) void finalize(const float* __restrict__ resid,
    const float* __restrict__ mixo, const float* __restrict__ embed,
    const float* __restrict__ nfw, float* __restrict__ out) {
  int b = blockIdx.x, tid = threadIdx.x;
  __shared__ float fin[DM];
  size_t off = ((size_t)b * LSEQ + (LSEQ - 1)) * DM;
  float r = resid[off + tid] + mixo[off + tid];
  float ss = block_reduce_sum256(r * r);
  fin[tid] = r * rsqrtf(ss * (1.f / DM) + 1e-5f) * nfw[tid];
  __syncthreads();
  if (tid < VOC) {
    float acc = 0.f;
    #pragma unroll 8
    for (int d = 0; d < DM; ++d) acc += fin[d] * embed[(size_t)tid * DM + d];
    out[b * VOC + tid] = acc;
  }
}

extern "C" void kernel_launch(void* const* d_in, const int* in_sizes, int n_in,
                              void* d_out, int out_size, void* d_ws, size_t ws_size,
                              hipStream_t stream) {
  const int*   ids   = (const int*)d_in[0];
  const float* embed = (const float*)d_in[1];
  const float* ipw   = (const float*)d_in[2];
  const float* cw    = (const float*)d_in[3];
  const float* cb    = (const float*)d_in[4];
  const float* dtbias= (const float*)d_in[5];
  const float* alog  = (const float*)d_in[6];
  const float* dpar  = (const float*)d_in[7];
  const float* ngw   = (const float*)d_in[8];
  const float* opw   = (const float*)d_in[9];
  const float* bnw   = (const float*)d_in[10];
  const float* nfw   = (const float*)d_in[11];
  float* out = (float*)d_out;

  // workspace layout (~156 MB)
  char* p = (char*)d_ws;
  float* resid = (float*)p;            p += (size_t)TKN * DM * 4;
  float* mixo  = (float*)p;            p += (size_t)TKN * DM * 4;
  ushort_t* hn = (ushort_t*)p;         p += (size_t)TKN * DM * 2;
  ushort_t* zx = (ushort_t*)p;         p += (size_t)TKN * DIPP * 2;
  float* dtb   = (float*)p;            p += (size_t)TKN * 4;
  float* csumb = (float*)p;            p += (size_t)TKN * 4;
  ushort_t* xb = (ushort_t*)p;         p += (size_t)TKN * DI * 2;
  ushort_t* yb = (ushort_t*)p;         p += (size_t)TKN * DI * 2;
  ushort_t* Bb = (ushort_t*)p;         p += (size_t)TKN * DS * 2;
  ushort_t* Cb = (ushort_t*)p;         p += (size_t)TKN * DS * 2;
  ushort_t* Ut = (ushort_t*)p;         p += (size_t)TKN * DI * 2;
  ushort_t* hin= (ushort_t*)p;         p += (size_t)NB * NC * DI * DS * 2;
  ushort_t* wbi= (ushort_t*)p;         p += (size_t)NL * DIP * DM * 2;
  ushort_t* wbo= (ushort_t*)p;         p += (size_t)NL * DM * DI * 2;
  // hst (fp32) aliases yb (bf16): consumed by combine2 before y_gemm writes yb
  float* hst = (float*)yb;

  convert_w<<<(NL * DIP * DM + NL * DM * DI + 1023) / 1024, 256, 0, stream>>>(
      ipw, opw, wbi, wbo);
  embed_init<<<TKN, 256, 0, stream>>>(ids, embed, mixo, resid);

  for (int i = 0; i < NL; ++i) {
    add_rmsnorm<<<TKN, 256, 0, stream>>>(resid, mixo, hn, bnw + (size_t)i * DM);
    gemm_nt_bf16<ushort_t><<<dim3((DIP + 127) / 128, TKN / 128), 256, 0, stream>>>(
        hn, wbi + (size_t)i * DIP * DM, zx, DIP, DM, DIPP);
    csum_k<<<32, 256, 0, stream>>>(zx, dtbias + i, dtb, csumb);
    conv_silu<<<dim3(CDIM / 128, LSEQ / 64, NB), 256, 0, stream>>>(
        zx, cw + (size_t)i * CDIM * 4, cb + (size_t)i * CDIM, dtb, xb, Bb, Cb, Ut);
    state_gemm<<<dim3(4, NC, NB), 256, 0, stream>>>(Bb, Ut, csumb, alog + i, hst);
    combine2<<<dim3(DI / 64, 4, NB), 256, 0, stream>>>(hst, csumb, alog + i, hin);
    y_gemm<<<dim3(4, NC, NB), 256, 0, stream>>>(Bb, Cb, Ut, hin, csumb, alog + i,
                                                dpar + i, xb, yb);
    outproj_fused<<<dim3(2, TKN / 128), 256, 0, stream>>>(
        yb, zx, wbo + (size_t)i * DM * DI, ngw + (size_t)i * DI, mixo);
  }

  finalize<<<NB, 256, 0, stream>>>(resid, mixo, embed, nfw, out);
}

// Round 7
// 673.761 us; speedup vs baseline: 3.1007x; 1.0488x over previous
//
#include <hip/hip_runtime.h>
#include <math.h>

// ---- problem constants ----
#define NB    8        // batch
#define LSEQ  2048     // seq len
#define TKN   16384    // NB*LSEQ tokens
#define DM    256      // d_model
#define DI    512      // d_inner
#define DS    64       // d_state
#define DIP   1153     // 2*DI + 2*DS + 1
#define DIPP  1160     // padded row stride for zx (bf16)
#define CDIM  640      // DI + 2*DS
#define NL    4
#define NC    16       // scan chunks
#define CL    128      // LSEQ/NC
#define VOC   100

typedef short bf16x8 __attribute__((ext_vector_type(8)));
typedef short bf16x4 __attribute__((ext_vector_type(4)));
typedef float f32x4  __attribute__((ext_vector_type(4)));
typedef unsigned short ushort_t;

__device__ __forceinline__ float block_reduce_sum256(float v) {
  __shared__ float sred[4];
  #pragma unroll
  for (int off = 32; off > 0; off >>= 1) v += __shfl_down(v, off, 64);
  int lane = threadIdx.x & 63, wid = threadIdx.x >> 6;
  if (lane == 0) sred[wid] = v;
  __syncthreads();
  return sred[0] + sred[1] + sred[2] + sred[3];
}

__device__ __forceinline__ unsigned short f2bf(float f) {
  unsigned int u = __float_as_uint(f);
  unsigned int r = u + 0x7FFFu + ((u >> 16) & 1u);   // RNE
  return (unsigned short)(r >> 16);
}
__device__ __forceinline__ float bf2f(unsigned short u) {
  return __uint_as_float(((unsigned int)u) << 16);
}

// convert fp32 weights -> bf16 once per call
__global__ __launch_bounds__(256) void convert_w(const float* __restrict__ ipw,
    const float* __restrict__ opw, ushort_t* __restrict__ wbi, ushort_t* __restrict__ wbo) {
  const int n1 = NL * DIP * DM;
  const int n2 = NL * DM * DI;
  int i4 = (blockIdx.x * 256 + threadIdx.x) * 4;
  if (i4 < n1) {
    float4 v = *(const float4*)(ipw + i4);
    bf16x4 o; o[0] = (short)f2bf(v.x); o[1] = (short)f2bf(v.y);
    o[2] = (short)f2bf(v.z); o[3] = (short)f2bf(v.w);
    *(bf16x4*)(wbi + i4) = o;
  } else {
    int j = i4 - n1;
    if (j < n2) {
      float4 v = *(const float4*)(opw + j);
      bf16x4 o; o[0] = (short)f2bf(v.x); o[1] = (short)f2bf(v.y);
      o[2] = (short)f2bf(v.z); o[3] = (short)f2bf(v.w);
      *(bf16x4*)(wbo + j) = o;
    }
  }
}

// mixo = embed[ids], resid = 0
__global__ __launch_bounds__(256) void embed_init(const int* __restrict__ ids,
    const float* __restrict__ embed, float* __restrict__ mixo, float* __restrict__ resid) {
  int t = blockIdx.x, tid = threadIdx.x;
  int id = ids[t];
  mixo[(size_t)t * DM + tid] = embed[(size_t)id * DM + tid];
  resid[(size_t)t * DM + tid] = 0.f;
}

// resid += mixo; hn = bf16(rmsnorm(resid)*w)
__global__ __launch_bounds__(256) void add_rmsnorm(float* __restrict__ resid,
    const float* __restrict__ mixo, ushort_t* __restrict__ hn, const float* __restrict__ w) {
  int t = blockIdx.x, tid = threadIdx.x;
  size_t o = (size_t)t * DM + tid;
  float r = resid[o] + mixo[o];
  resid[o] = r;
  float ss = block_reduce_sum256(r * r);
  hn[o] = f2bf(r * rsqrtf(ss * (1.f / DM) + 1e-5f) * w[tid]);
}

// ---------------- bf16 MFMA GEMM (A bf16, B bf16) ----------------
#define LSTR 40
template<typename TC>
__global__ __launch_bounds__(256) void gemm_nt_bf16(const ushort_t* __restrict__ A,
    const ushort_t* __restrict__ Bw, TC* __restrict__ C, int N, int K, int ldc) {
  __shared__ short sA[128 * LSTR];
  __shared__ short sB[128 * LSTR];
  int tid = threadIdx.x;
  int bn = blockIdx.x * 128;
  int bm = blockIdx.y * 128;
  int wave = tid >> 6, lane = tid & 63;
  int wm = (wave >> 1) * 64, wn = (wave & 1) * 64;
  int q = lane >> 4, c = lane & 15;

  f32x4 acc[4][4];
  #pragma unroll
  for (int i = 0; i < 4; ++i)
    #pragma unroll
    for (int j = 0; j < 4; ++j) acc[i][j] = (f32x4)0.f;

  int sr = tid >> 1;
  int sc = (tid & 1) * 16;
  const ushort_t* Ag = A + (size_t)(bm + sr) * K + sc;
  const ushort_t* Bg = Bw + (size_t)(bn + sr) * K + sc;
  bool bok = (bn + sr) < N;
  short* sAp = &sA[sr * LSTR + sc];
  short* sBp = &sB[sr * LSTR + sc];

  for (int k0 = 0; k0 < K; k0 += 32) {
    bf16x8 a0 = *(const bf16x8*)(Ag + k0);
    bf16x8 a1 = *(const bf16x8*)(Ag + k0 + 8);
    bf16x8 b0 = (bf16x8)(short)0, b1 = (bf16x8)(short)0;
    if (bok) {
      b0 = *(const bf16x8*)(Bg + k0);
      b1 = *(const bf16x8*)(Bg + k0 + 8);
    }
    __syncthreads();
    *(bf16x8*)(sAp)     = a0;
    *(bf16x8*)(sAp + 8) = a1;
    *(bf16x8*)(sBp)     = b0;
    *(bf16x8*)(sBp + 8) = b1;
    __syncthreads();
    bf16x8 af[4], bfr[4];
    #pragma unroll
    for (int i = 0; i < 4; ++i)
      af[i] = *(const bf16x8*)&sA[(wm + i * 16 + c) * LSTR + q * 8];
    #pragma unroll
    for (int j = 0; j < 4; ++j)
      bfr[j] = *(const bf16x8*)&sB[(wn + j * 16 + c) * LSTR + q * 8];
    #pragma unroll
    for (int i = 0; i < 4; ++i)
      #pragma unroll
      for (int j = 0; j < 4; ++j)
        acc[i][j] = __builtin_amdgcn_mfma_f32_16x16x32_bf16(af[i], bfr[j], acc[i][j], 0, 0, 0);
  }
  #pragma unroll
  for (int i = 0; i < 4; ++i) {
    int m = bm + wm + i * 16 + q * 4;
    #pragma unroll
    for (int j = 0; j < 4; ++j) {
      int n = bn + wn + j * 16 + c;
      if (n < N) {
        #pragma unroll
        for (int r = 0; r < 4; ++r) {
          if constexpr (sizeof(TC) == 2)
            C[(size_t)(m + r) * ldc + n] = (TC)f2bf(acc[i][j][r]);
          else
            C[(size_t)(m + r) * ldc + n] = acc[i][j][r];
        }
      }
    }
  }
}

// fused out_proj: C = rownorm * ((y*silu(z))*w) @ Wb^T
// Tile M=64 x N=128, grid (2, TKN/64) = 512 blocks, block 256 (2x2 waves).
__global__ __launch_bounds__(256) void outproj_fused(const ushort_t* __restrict__ yb,
    const ushort_t* __restrict__ zx, const ushort_t* __restrict__ Bw,
    const float* __restrict__ gw, float* __restrict__ Cout) {
  __shared__ short sA[64 * LSTR];
  __shared__ short sB[128 * LSTR];
  __shared__ float swl[DI];
  __shared__ float rs[256];
  int tid = threadIdx.x;
  int bn = blockIdx.x * 128;
  int bm = blockIdx.y * 64;
  int wave = tid >> 6, lane = tid & 63;
  int wm = (wave >> 1) * 32, wn = (wave & 1) * 64;
  int q = lane >> 4, c = lane & 15;
  swl[tid] = gw[tid];
  swl[tid + 256] = gw[tid + 256];

  f32x4 acc[2][4];
  #pragma unroll
  for (int i = 0; i < 2; ++i)
    #pragma unroll
    for (int j = 0; j < 4; ++j) acc[i][j] = (f32x4)0.f;

  int ar = tid >> 2, ak = (tid & 3) * 8;    // A row 0..63, k-off 0/8/16/24
  int br = tid >> 1, bk = (tid & 1) * 16;   // B row 0..127, k-off 0/16
  const ushort_t* yrow = yb + (size_t)(bm + ar) * DI + ak;
  const ushort_t* zrow = zx + (size_t)(bm + ar) * DIPP + ak;
  const ushort_t* Bg = Bw + (size_t)(bn + br) * DI + bk;
  short* sAp = &sA[ar * LSTR + ak];
  short* sBp = &sB[br * LSTR + bk];
  float sumsq = 0.f;
  __syncthreads();   // swl visible

  for (int k0 = 0; k0 < DI; k0 += 32) {
    bf16x8 y8 = *(const bf16x8*)(yrow + k0);
    bf16x8 z8 = *(const bf16x8*)(zrow + k0);
    bf16x8 b0 = *(const bf16x8*)(Bg + k0);
    bf16x8 b1 = *(const bf16x8*)(Bg + k0 + 8);
    bf16x8 g8;
    #pragma unroll
    for (int e = 0; e < 8; ++e) {
      float zz = bf2f((ushort_t)z8[e]);
      float gg = bf2f((ushort_t)y8[e]) * (zz / (1.f + __expf(-zz)));
      sumsq += gg * gg;
      g8[e] = (short)f2bf(gg * swl[k0 + ak + e]);
    }
    __syncthreads();
    *(bf16x8*)(sAp)     = g8;
    *(bf16x8*)(sBp)     = b0;
    *(bf16x8*)(sBp + 8) = b1;
    __syncthreads();
    bf16x8 af[2], bfr[4];
    #pragma unroll
    for (int i = 0; i < 2; ++i)
      af[i] = *(const bf16x8*)&sA[(wm + i * 16 + c) * LSTR + q * 8];
    #pragma unroll
    for (int j = 0; j < 4; ++j)
      bfr[j] = *(const bf16x8*)&sB[(wn + j * 16 + c) * LSTR + q * 8];
    #pragma unroll
    for (int i = 0; i < 2; ++i)
      #pragma unroll
      for (int j = 0; j < 4; ++j)
        acc[i][j] = __builtin_amdgcn_mfma_f32_16x16x32_bf16(af[i], bfr[j], acc[i][j], 0, 0, 0);
  }
  rs[tid] = sumsq;          // 4 partials per row: rs[row*4 + (tid&3)]
  __syncthreads();
  #pragma unroll
  for (int i = 0; i < 2; ++i) {
    #pragma unroll
    for (int r = 0; r < 4; ++r) {
      int ml = wm + i * 16 + q * 4 + r;
      float rtot = rs[ml * 4] + rs[ml * 4 + 1] + rs[ml * 4 + 2] + rs[ml * 4 + 3];
      float scale = rsqrtf(rtot * (1.f / DI) + 1e-5f);
      #pragma unroll
      for (int j = 0; j < 4; ++j) {
        int n = bn + wn + j * 16 + c;
        Cout[(size_t)(bm + ml) * DM + n] = scale * acc[i][j][r];
      }
    }
  }
}

// LDS-tiled conv(4)+bias+silu, fused with U^T = dt*x transpose.
__global__ __launch_bounds__(256) void conv_silu(const ushort_t* __restrict__ zx,
    const float* __restrict__ cw, const float* __restrict__ cb,
    const float* __restrict__ dtb, ushort_t* __restrict__ xo,
    ushort_t* __restrict__ Bo, ushort_t* __restrict__ Co, ushort_t* __restrict__ Ut) {
  __shared__ float tile[67 * 128];
  __shared__ ushort_t tt[128 * 65];
  __shared__ float sdt[64];
  int tid = threadIdx.x;
  int ct = blockIdx.x, tb_ = blockIdx.y, b = blockIdx.z;
  int c0 = ct * 128;
  int l0 = tb_ * 64;
  size_t rowb = (size_t)b * LSEQ;
  int cl = tid & 127;
  int cg = c0 + cl;
  for (int tr = tid >> 7; tr < 67; tr += 2) {
    int l = l0 + tr - 3;
    float v = 0.f;
    if (l >= 0) v = bf2f(zx[(rowb + l) * DIPP + DI + cg]);
    tile[tr * 128 + cl] = v;
  }
  if (tid < 64) sdt[tid] = dtb[rowb + l0 + tid];
  float w0 = cw[cg * 4 + 0], w1 = cw[cg * 4 + 1];
  float w2 = cw[cg * 4 + 2], w3 = cw[cg * 4 + 3];
  float bias = cb[cg];
  __syncthreads();
  bool isx = (ct < 4);
  int tg = tid >> 7;
  #pragma unroll 4
  for (int t2 = 0; t2 < 32; ++t2) {
    int t = tg * 32 + t2;
    float s = bias + w0 * tile[t * 128 + cl] + w1 * tile[(t + 1) * 128 + cl]
                   + w2 * tile[(t + 2) * 128 + cl] + w3 * tile[(t + 3) * 128 + cl];
    float v = s / (1.f + __expf(-s));
    size_t tl = rowb + l0 + t;
    if (isx) {
      xo[tl * DI + cg] = f2bf(v);
      tt[cl * 65 + t] = f2bf(v * sdt[t]);
    } else if (cg < DI + DS) {
      Bo[tl * DS + (cg - DI)] = f2bf(v);
    } else {
      Co[tl * DS + (cg - DI - DS)] = f2bf(v);
    }
  }
  if (isx) {
    __syncthreads();
    int os = tid & 63;
    #pragma unroll
    for (int pass = 0; pass < 32; ++pass) {
      int op = (tid >> 6) + pass * 4;
      Ut[((size_t)b * DI + c0 + op) * LSEQ + l0 + os] = tt[op * 65 + os];
    }
  }
}

// dt = softplus(dt_raw + bias); per-chunk inclusive prefix sum. one wave per chunk.
__global__ __launch_bounds__(256) void csum_k(const ushort_t* __restrict__ zx,
    const float* __restrict__ dtbias, float* __restrict__ dtb, float* __restrict__ csumb) {
  int tid = threadIdx.x;
  int wave = tid >> 6, lane = tid & 63;
  int cg = blockIdx.x * 4 + wave;
  int b = cg >> 4, ch = cg & 15;
  size_t base = (size_t)b * LSEQ + ch * CL;
  float bias = dtbias[0];
  float x0 = bf2f(zx[(base + 2 * lane) * DIPP + (DIP - 1)]) + bias;
  float x1 = bf2f(zx[(base + 2 * lane + 1) * DIPP + (DIP - 1)]) + bias;
  float d0 = (x0 > 20.f) ? x0 : log1pf(__expf(x0));
  float d1 = (x1 > 20.f) ? x1 : log1pf(__expf(x1));
  dtb[base + 2 * lane] = d0;
  dtb[base + 2 * lane + 1] = d1;
  float p = d0 + d1;
  #pragma unroll
  for (int off = 1; off < 64; off <<= 1) {
    float t = __shfl_up(p, off, 64);
    if (lane >= off) p += t;
  }
  csumb[base + 2 * lane]     = p - d1;
  csumb[base + 2 * lane + 1] = p;
}

// state GEMM: Hloc[bc][n][p] = sum_s exp(A(S - cs[s])) * B[s][n] * U[s][p]
__global__ __launch_bounds__(256) void state_gemm(const ushort_t* __restrict__ Bb,
    const ushort_t* __restrict__ Ut, const float* __restrict__ csumb,
    const float* __restrict__ alog, float* __restrict__ hst) {
  __shared__ short sW[64 * 144];
  __shared__ short sX[128 * 40];
  __shared__ float scs[128];
  int tid = threadIdx.x;
  int ph = blockIdx.x, ch = blockIdx.y, b = blockIdx.z;
  int bc = b * NC + ch;
  size_t tb = (size_t)b * LSEQ + ch * CL;
  float Aval = -expf(alog[0]);
  if (tid < 128) scs[tid] = csumb[tb + tid];
  __syncthreads();
  float Stot = scs[127];
  {
    int s = tid >> 1, noff = (tid & 1) * 32;
    float scale = __expf(Aval * (Stot - scs[s]));
    #pragma unroll
    for (int blk = 0; blk < 4; ++blk) {
      bf16x8 v = *(const bf16x8*)&Bb[(tb + s) * DS + noff + blk * 8];
      #pragma unroll
      for (int e = 0; e < 8; ++e)
        sW[(noff + blk * 8 + e) * 144 + s] = (short)f2bf(bf2f((ushort_t)v[e]) * scale);
    }
  }
  int wave = tid >> 6, lane = tid & 63;
  int wn = (wave >> 1) * 32, wp = (wave & 1) * 64;
  int q = lane >> 4, c = lane & 15;
  f32x4 acc[2][4];
  #pragma unroll
  for (int i = 0; i < 2; ++i)
    #pragma unroll
    for (int j = 0; j < 4; ++j) acc[i][j] = (f32x4)0.f;

  for (int ks = 0; ks < 4; ++ks) {
    __syncthreads();
    {
      int r = tid >> 1, off = (tid & 1) * 16;
      size_t ua = ((size_t)b * DI + ph * 128 + r) * LSEQ + ch * CL + ks * 32 + off;
      bf16x8 u0 = *(const bf16x8*)&Ut[ua];
      bf16x8 u1 = *(const bf16x8*)&Ut[ua + 8];
      *(bf16x8*)&sX[r * 40 + off]     = u0;
      *(bf16x8*)&sX[r * 40 + off + 8] = u1;
    }
    __syncthreads();
    bf16x8 af[2], bfr[4];
    #pragma unroll
    for (int i = 0; i < 2; ++i)
      af[i] = *(const bf16x8*)&sW[(wn + i * 16 + c) * 144 + ks * 32 + q * 8];
    #pragma unroll
    for (int j = 0; j < 4; ++j)
      bfr[j] = *(const bf16x8*)&sX[(wp + j * 16 + c) * 40 + q * 8];
    #pragma unroll
    for (int i = 0; i < 2; ++i)
      #pragma unroll
      for (int j = 0; j < 4; ++j)
        acc[i][j] = __builtin_amdgcn_mfma_f32_16x16x32_bf16(af[i], bfr[j], acc[i][j], 0, 0, 0);
  }
  #pragma unroll
  for (int i = 0; i < 2; ++i) {
    int n = wn + i * 16 + q * 4;
    #pragma unroll
    for (int j = 0; j < 4; ++j) {
      int pg = ph * 128 + wp + j * 16 + c;
      #pragma unroll
      for (int r = 0; r < 4; ++r)
        hst[((size_t)bc * DS + n + r) * DI + pg] = acc[i][j][r];
    }
  }
}

// combine: sequential over chunks; outputs carry-in states hin[bc][p][n] bf16
__global__ __launch_bounds__(256) void combine2(const float* __restrict__ hst,
    const float* __restrict__ csumb, const float* __restrict__ alog,
    ushort_t* __restrict__ hin) {
  __shared__ ushort_t ts[64 * 17];
  int tid = threadIdx.x;
  int pt = blockIdx.x, nt = blockIdx.y, b = blockIdx.z;
  int p0 = pt * 64, n0 = nt * 16;
  int pl = tid & 63, ng = tid >> 6;
  float Aval = -expf(alog[0]);
  float h[4];
  #pragma unroll
  for (int i = 0; i < 4; ++i) h[i] = 0.f;
  for (int c = 0; c < NC; ++c) {
    int bc = b * NC + c;
    #pragma unroll
    for (int i = 0; i < 4; ++i)
      ts[pl * 17 + ng * 4 + i] = f2bf(h[i]);
    __syncthreads();
    {
      int on = tid & 15;
      #pragma unroll
      for (int pass = 0; pass < 4; ++pass) {
        int op = (tid >> 4) + pass * 16;
        hin[((size_t)bc * DI + p0 + op) * DS + n0 + on] = ts[op * 17 + on];
      }
    }
    __syncthreads();
    float Sc = csumb[(size_t)b * LSEQ + c * CL + CL - 1];
    float dec = __expf(Aval * Sc);
    #pragma unroll
    for (int i = 0; i < 4; ++i) {
      float loc = hst[((size_t)bc * DS + n0 + ng * 4 + i) * DI + p0 + pl];
      h[i] = h[i] * dec + loc;
    }
  }
}

// y GEMM: G=C@B^T -> M masked-decayed -> Y = M@U + Chat@Hin; y = Y + dp*x (bf16)
__global__ __launch_bounds__(256) void y_gemm(const ushort_t* __restrict__ Bb,
    const ushort_t* __restrict__ Cb, const ushort_t* __restrict__ Ut,
    const ushort_t* __restrict__ hin, const float* __restrict__ csumb,
    const float* __restrict__ alog, const float* __restrict__ dpar,
    const ushort_t* __restrict__ xb, ushort_t* __restrict__ y) {
  __shared__ short sC[128 * 72];
  __shared__ short sM[128 * 136];
  __shared__ short sU[128 * 80];
  __shared__ float scs[128];
  int tid = threadIdx.x;
  int ph = blockIdx.x, ch = blockIdx.y, b = blockIdx.z;
  int bc = b * NC + ch;
  size_t tb = (size_t)b * LSEQ + ch * CL;
  float Aval = -expf(alog[0]);
  float dp = dpar[0];
  int wave = tid >> 6, lane = tid & 63;
  int q = lane >> 4, c = lane & 15;

  {
    int r = tid >> 1, off = (tid & 1) * 32;
    #pragma unroll
    for (int blk = 0; blk < 4; ++blk) {
      *(bf16x8*)&sC[r * 72 + off + blk * 8] = *(const bf16x8*)&Cb[(tb + r) * DS + off + blk * 8];
      *(bf16x8*)&sU[r * 80 + off + blk * 8] = *(const bf16x8*)&Bb[(tb + r) * DS + off + blk * 8];
    }
  }
  if (tid < 128) scs[tid] = csumb[tb + tid];
  __syncthreads();

  // phase 1: G = C @ B^T (128t x 128s, K=64)
  {
    int wm = (wave >> 1) * 64, wss = (wave & 1) * 64;
    f32x4 g[4][4];
    #pragma unroll
    for (int i = 0; i < 4; ++i)
      #pragma unroll
      for (int j = 0; j < 4; ++j) g[i][j] = (f32x4)0.f;
    #pragma unroll
    for (int k0 = 0; k0 < 64; k0 += 32) {
      bf16x8 af[4], bfr[4];
      #pragma unroll
      for (int i = 0; i < 4; ++i)
        af[i] = *(const bf16x8*)&sC[(wm + i * 16 + c) * 72 + k0 + q * 8];
      #pragma unroll
      for (int j = 0; j < 4; ++j)
        bfr[j] = *(const bf16x8*)&sU[(wss + j * 16 + c) * 80 + k0 + q * 8];
      #pragma unroll
      for (int i = 0; i < 4; ++i)
        #pragma unroll
        for (int j = 0; j < 4; ++j)
          g[i][j] = __builtin_amdgcn_mfma_f32_16x16x32_bf16(af[i], bfr[j], g[i][j], 0, 0, 0);
    }
    #pragma unroll
    for (int i = 0; i < 4; ++i) {
      #pragma unroll
      for (int r = 0; r < 4; ++r) {
        int t = wm + i * 16 + q * 4 + r;
        float ct = scs[t];
        #pragma unroll
        for (int j = 0; j < 4; ++j) {
          int s = wss + j * 16 + c;
          float v = g[i][j][r];
          float m = (s <= t) ? v * __expf(Aval * (ct - scs[s])) : 0.f;
          sM[t * 136 + s] = (short)f2bf(m);
        }
      }
    }
  }

  // phase 2: Y (128t x 128p) = M @ U + Chat @ Hin
  int wm2 = (wave >> 1) * 64, wp = (wave & 1) * 64;
  f32x4 acc[4][4];
  #pragma unroll
  for (int i = 0; i < 4; ++i)
    #pragma unroll
    for (int j = 0; j < 4; ++j) acc[i][j] = (f32x4)0.f;

  for (int ks = 0; ks < 4; ++ks) {
    __syncthreads();
    {
      int r = tid >> 1, off = (tid & 1) * 16;
      size_t ua = ((size_t)b * DI + ph * 128 + r) * LSEQ + ch * CL + ks * 32 + off;
      bf16x8 u0 = *(const bf16x8*)&Ut[ua];
      bf16x8 u1 = *(const bf16x8*)&Ut[ua + 8];
      *(bf16x8*)&sU[r * 40 + off]     = u0;
      *(bf16x8*)&sU[r * 40 + off + 8] = u1;
    }
    __syncthreads();
    bf16x8 af[4], bfr[4];
    #pragma unroll
    for (int i = 0; i < 4; ++i)
      af[i] = *(const bf16x8*)&sM[(wm2 + i * 16 + c) * 136 + ks * 32 + q * 8];
    #pragma unroll
    for (int j = 0; j < 4; ++j)
      bfr[j] = *(const bf16x8*)&sU[(wp + j * 16 + c) * 40 + q * 8];
    #pragma unroll
    for (int i = 0; i < 4; ++i)
      #pragma unroll
      for (int j = 0; j < 4; ++j)
        acc[i][j] = __builtin_amdgcn_mfma_f32_16x16x32_bf16(af[i], bfr[j], acc[i][j], 0, 0, 0);
  }

  __syncthreads();
  {
    int r = tid >> 1, off = (tid & 1) * 32;
    float sc_t = __expf(Aval * scs[r]);
    #pragma unroll
    for (int blk = 0; blk < 4; ++blk) {
      bf16x8 v = *(const bf16x8*)&sC[r * 72 + off + blk * 8];
      bf16x8 o;
      #pragma unroll
      for (int e = 0; e < 8; ++e)
        o[e] = (short)f2bf(bf2f((ushort_t)v[e]) * sc_t);
      *(bf16x8*)&sM[r * 80 + off + blk * 8] = o;
    }
  }
  for (int ks = 4; ks < 6; ++ks) {
    __syncthreads();
    {
      int r = tid >> 1, off = (tid & 1) * 16;
      size_t ha = ((size_t)bc * DI + ph * 128 + r) * DS + (ks - 4) * 32 + off;
      bf16x8 h0 = *(const bf16x8*)&hin[ha];
      bf16x8 h1 = *(const bf16x8*)&hin[ha + 8];
      *(bf16x8*)&sU[r * 40 + off]     = h0;
      *(bf16x8*)&sU[r * 40 + off + 8] = h1;
    }
    __syncthreads();
    bf16x8 af[4], bfr[4];
    #pragma unroll
    for (int i = 0; i < 4; ++i)
      af[i] = *(const bf16x8*)&sM[(wm2 + i * 16 + c) * 80 + (ks - 4) * 32 + q * 8];
    #pragma unroll
    for (int j = 0; j < 4; ++j)
      bfr[j] = *(const bf16x8*)&sU[(wp + j * 16 + c) * 40 + q * 8];
    #pragma unroll
    for (int i = 0; i < 4; ++i)
      #pragma unroll
      for (int j = 0; j < 4; ++j)
        acc[i][j] = __builtin_amdgcn_mfma_f32_16x16x32_bf16(af[i], bfr[j], acc[i][j], 0, 0, 0);
  }

  #pragma unroll
  for (int i = 0; i < 4; ++i) {
    #pragma unroll
    for (int r = 0; r < 4; ++r) {
      int t = wm2 + i * 16 + q * 4 + r;
      size_t row = (tb + t) * DI;
      #pragma unroll
      for (int j = 0; j < 4; ++j) {
        int pg = ph * 128 + wp + j * 16 + c;
        y[row + pg] = f2bf(acc[i][j][r] + dp * bf2f(xb[row + pg]));
      }
    }
  }
}

// last token only
__global__ __launch_bounds__(256) void finalize(const float* __restrict__ resid,
    const float* __restrict__ mixo, const float* __restrict__ embed,
    const float* __restrict__ nfw, float* __restrict__ out) {
  int b = blockIdx.x, tid = threadIdx.x;
  __shared__ float fin[DM];
  size_t off = ((size_t)b * LSEQ + (LSEQ - 1)) * DM;
  float r = resid[off + tid] + mixo[off + tid];
  float ss = block_reduce_sum256(r * r);
  fin[tid] = r * rsqrtf(ss * (1.f / DM) + 1e-5f) * nfw[tid];
  __syncthreads();
  if (tid < VOC) {
    float acc = 0.f;
    #pragma unroll 8
    for (int d = 0; d < DM; ++d) acc += fin[d] * embed[(size_t)tid * DM + d];
    out[b * VOC + tid] = acc;
  }
}

extern "C" void kernel_launch(void* const* d_in, const int* in_sizes, int n_in,
                              void* d_out, int out_size, void* d_ws, size_t ws_size,
                              hipStream_t stream) {
  const int*   ids   = (const int*)d_in[0];
  const float* embed = (const float*)d_in[1];
  const float* ipw   = (const float*)d_in[2];
  const float* cw    = (const float*)d_in[3];
  const float* cb    = (const float*)d_in[4];
  const float* dtbias= (const float*)d_in[5];
  const float* alog  = (const float*)d_in[6];
  const float* dpar  = (const float*)d_in[7];
  const float* ngw   = (const float*)d_in[8];
  const float* opw   = (const float*)d_in[9];
  const float* bnw   = (const float*)d_in[10];
  const float* nfw   = (const float*)d_in[11];
  float* out = (float*)d_out;

  // workspace layout (~156 MB)
  char* p = (char*)d_ws;
  float* resid = (float*)p;            p += (size_t)TKN * DM * 4;
  float* mixo  = (float*)p;            p += (size_t)TKN * DM * 4;
  ushort_t* hn = (ushort_t*)p;         p += (size_t)TKN * DM * 2;
  ushort_t* zx = (ushort_t*)p;         p += (size_t)TKN * DIPP * 2;
  float* dtb   = (float*)p;            p += (size_t)TKN * 4;
  float* csumb = (float*)p;            p += (size_t)TKN * 4;
  ushort_t* xb = (ushort_t*)p;         p += (size_t)TKN * DI * 2;
  ushort_t* yb = (ushort_t*)p;         p += (size_t)TKN * DI * 2;
  ushort_t* Bb = (ushort_t*)p;         p += (size_t)TKN * DS * 2;
  ushort_t* Cb = (ushort_t*)p;         p += (size_t)TKN * DS * 2;
  ushort_t* Ut = (ushort_t*)p;         p += (size_t)TKN * DI * 2;
  ushort_t* hin= (ushort_t*)p;         p += (size_t)NB * NC * DI * DS * 2;
  ushort_t* wbi= (ushort_t*)p;         p += (size_t)NL * DIP * DM * 2;
  ushort_t* wbo= (ushort_t*)p;         p += (size_t)NL * DM * DI * 2;
  // hst (fp32) aliases yb (bf16): consumed by combine2 before y_gemm writes yb
  float* hst = (float*)yb;

  convert_w<<<(NL * DIP * DM + NL * DM * DI + 1023) / 1024, 256, 0, stream>>>(
      ipw, opw, wbi, wbo);
  embed_init<<<TKN, 256, 0, stream>>>(ids, embed, mixo, resid);

  for (int i = 0; i < NL; ++i) {
    add_rmsnorm<<<TKN, 256, 0, stream>>>(resid, mixo, hn, bnw + (size_t)i * DM);
    gemm_nt_bf16<ushort_t><<<dim3((DIP + 127) / 128, TKN / 128), 256, 0, stream>>>(
        hn, wbi + (size_t)i * DIP * DM, zx, DIP, DM, DIPP);
    csum_k<<<32, 256, 0, stream>>>(zx, dtbias + i, dtb, csumb);
    conv_silu<<<dim3(CDIM / 128, LSEQ / 64, NB), 256, 0, stream>>>(
        zx, cw + (size_t)i * CDIM * 4, cb + (size_t)i * CDIM, dtb, xb, Bb, Cb, Ut);
    state_gemm<<<dim3(4, NC, NB), 256, 0, stream>>>(Bb, Ut, csumb, alog + i, hst);
    combine2<<<dim3(DI / 64, 4, NB), 256, 0, stream>>>(hst, csumb, alog + i, hin);
    y_gemm<<<dim3(4, NC, NB), 256, 0, stream>>>(Bb, Cb, Ut, hin, csumb, alog + i,
                                                dpar + i, xb, yb);
    outproj_fused<<<dim3(2, TKN / 64), 256, 0, stream>>>(
        yb, zx, wbo + (size_t)i * DM * DI, ngw + (size_t)i * DI, mixo);
  }

  finalize<<<NB, 256, 0, stream>>>(resid, mixo, embed, nfw, out);
}

// Round 8
// 600.839 us; speedup vs baseline: 3.4770x; 1.1214x over previous
//
#include <hip/hip_runtime.h>
#include <math.h>

// ---- problem constants ----
#define NB    8        // batch
#define LSEQ  2048     // seq len
#define TKN   16384    // NB*LSEQ tokens
#define DM    256      // d_model
#define DI    512      // d_inner
#define DS    64       // d_state
#define DIP   1153     // 2*DI + 2*DS + 1
#define DIPP  1160     // padded row stride for zx (bf16)
#define CDIM  640      // DI + 2*DS
#define NL    4
#define NC    16       // scan chunks
#define CL    128      // LSEQ/NC
#define VOC   100

typedef short bf16x8 __attribute__((ext_vector_type(8)));
typedef short bf16x4 __attribute__((ext_vector_type(4)));
typedef float f32x4  __attribute__((ext_vector_type(4)));
typedef unsigned short ushort_t;

__device__ __forceinline__ float block_reduce_sum256(float v) {
  __shared__ float sred[4];
  #pragma unroll
  for (int off = 32; off > 0; off >>= 1) v += __shfl_down(v, off, 64);
  int lane = threadIdx.x & 63, wid = threadIdx.x >> 6;
  if (lane == 0) sred[wid] = v;
  __syncthreads();
  return sred[0] + sred[1] + sred[2] + sred[3];
}

__device__ __forceinline__ unsigned short f2bf(float f) {
  unsigned int u = __float_as_uint(f);
  unsigned int r = u + 0x7FFFu + ((u >> 16) & 1u);   // RNE
  return (unsigned short)(r >> 16);
}
__device__ __forceinline__ float bf2f(unsigned short u) {
  return __uint_as_float(((unsigned int)u) << 16);
}

// convert fp32 weights -> bf16 once per call
__global__ __launch_bounds__(256) void convert_w(const float* __restrict__ ipw,
    const float* __restrict__ opw, ushort_t* __restrict__ wbi, ushort_t* __restrict__ wbo) {
  const int n1 = NL * DIP * DM;
  const int n2 = NL * DM * DI;
  int i4 = (blockIdx.x * 256 + threadIdx.x) * 4;
  if (i4 < n1) {
    float4 v = *(const float4*)(ipw + i4);
    bf16x4 o; o[0] = (short)f2bf(v.x); o[1] = (short)f2bf(v.y);
    o[2] = (short)f2bf(v.z); o[3] = (short)f2bf(v.w);
    *(bf16x4*)(wbi + i4) = o;
  } else {
    int j = i4 - n1;
    if (j < n2) {
      float4 v = *(const float4*)(opw + j);
      bf16x4 o; o[0] = (short)f2bf(v.x); o[1] = (short)f2bf(v.y);
      o[2] = (short)f2bf(v.z); o[3] = (short)f2bf(v.w);
      *(bf16x4*)(wbo + j) = o;
    }
  }
}

// mixo = embed[ids], resid = 0
__global__ __launch_bounds__(256) void embed_init(const int* __restrict__ ids,
    const float* __restrict__ embed, float* __restrict__ mixo, float* __restrict__ resid) {
  int t = blockIdx.x, tid = threadIdx.x;
  int id = ids[t];
  mixo[(size_t)t * DM + tid] = embed[(size_t)id * DM + tid];
  resid[(size_t)t * DM + tid] = 0.f;
}

// resid += mixo; hn = bf16(rmsnorm(resid)*w). One wave per token, 4 tokens/block.
__global__ __launch_bounds__(256) void add_rmsnorm(float* __restrict__ resid,
    const float* __restrict__ mixo, ushort_t* __restrict__ hn, const float* __restrict__ w) {
  int wave = threadIdx.x >> 6, lane = threadIdx.x & 63;
  int t = blockIdx.x * 4 + wave;
  size_t o = (size_t)t * DM + lane * 4;
  float4 r4 = *(const float4*)&resid[o];
  float4 m4 = *(const float4*)&mixo[o];
  r4.x += m4.x; r4.y += m4.y; r4.z += m4.z; r4.w += m4.w;
  *(float4*)&resid[o] = r4;
  float ss = r4.x * r4.x + r4.y * r4.y + r4.z * r4.z + r4.w * r4.w;
  #pragma unroll
  for (int m = 32; m >= 1; m >>= 1) ss += __shfl_xor(ss, m, 64);
  float sc = rsqrtf(ss * (1.f / DM) + 1e-5f);
  float4 w4 = *(const float4*)&w[lane * 4];
  bf16x4 o4;
  o4[0] = (short)f2bf(r4.x * sc * w4.x);
  o4[1] = (short)f2bf(r4.y * sc * w4.y);
  o4[2] = (short)f2bf(r4.z * sc * w4.z);
  o4[3] = (short)f2bf(r4.w * sc * w4.w);
  *(bf16x4*)&hn[o] = o4;
}

// ---------------- bf16 MFMA GEMM (A bf16, B bf16) ----------------
#define LSTR 40
template<typename TC>
__global__ __launch_bounds__(256) void gemm_nt_bf16(const ushort_t* __restrict__ A,
    const ushort_t* __restrict__ Bw, TC* __restrict__ C, int N, int K, int ldc) {
  __shared__ short sA[128 * LSTR];
  __shared__ short sB[128 * LSTR];
  int tid = threadIdx.x;
  int bn = blockIdx.x * 128;
  int bm = blockIdx.y * 128;
  int wave = tid >> 6, lane = tid & 63;
  int wm = (wave >> 1) * 64, wn = (wave & 1) * 64;
  int q = lane >> 4, c = lane & 15;

  f32x4 acc[4][4];
  #pragma unroll
  for (int i = 0; i < 4; ++i)
    #pragma unroll
    for (int j = 0; j < 4; ++j) acc[i][j] = (f32x4)0.f;

  int sr = tid >> 1;
  int sc = (tid & 1) * 16;
  const ushort_t* Ag = A + (size_t)(bm + sr) * K + sc;
  const ushort_t* Bg = Bw + (size_t)(bn + sr) * K + sc;
  bool bok = (bn + sr) < N;
  short* sAp = &sA[sr * LSTR + sc];
  short* sBp = &sB[sr * LSTR + sc];

  for (int k0 = 0; k0 < K; k0 += 32) {
    bf16x8 a0 = *(const bf16x8*)(Ag + k0);
    bf16x8 a1 = *(const bf16x8*)(Ag + k0 + 8);
    bf16x8 b0 = (bf16x8)(short)0, b1 = (bf16x8)(short)0;
    if (bok) {
      b0 = *(const bf16x8*)(Bg + k0);
      b1 = *(const bf16x8*)(Bg + k0 + 8);
    }
    __syncthreads();
    *(bf16x8*)(sAp)     = a0;
    *(bf16x8*)(sAp + 8) = a1;
    *(bf16x8*)(sBp)     = b0;
    *(bf16x8*)(sBp + 8) = b1;
    __syncthreads();
    bf16x8 af[4], bfr[4];
    #pragma unroll
    for (int i = 0; i < 4; ++i)
      af[i] = *(const bf16x8*)&sA[(wm + i * 16 + c) * LSTR + q * 8];
    #pragma unroll
    for (int j = 0; j < 4; ++j)
      bfr[j] = *(const bf16x8*)&sB[(wn + j * 16 + c) * LSTR + q * 8];
    #pragma unroll
    for (int i = 0; i < 4; ++i)
      #pragma unroll
      for (int j = 0; j < 4; ++j)
        acc[i][j] = __builtin_amdgcn_mfma_f32_16x16x32_bf16(af[i], bfr[j], acc[i][j], 0, 0, 0);
  }
  #pragma unroll
  for (int i = 0; i < 4; ++i) {
    int m = bm + wm + i * 16 + q * 4;
    #pragma unroll
    for (int j = 0; j < 4; ++j) {
      int n = bn + wn + j * 16 + c;
      if (n < N) {
        #pragma unroll
        for (int r = 0; r < 4; ++r) {
          if constexpr (sizeof(TC) == 2)
            C[(size_t)(m + r) * ldc + n] = (TC)f2bf(acc[i][j][r]);
          else
            C[(size_t)(m + r) * ldc + n] = acc[i][j][r];
        }
      }
    }
  }
}

// fused out_proj: C = rownorm * ((y*silu(z))*w) @ Wb^T
// Tile M=64 x N=128, grid (2, TKN/64) = 512 blocks, block 256 (2x2 waves).
__global__ __launch_bounds__(256) void outproj_fused(const ushort_t* __restrict__ yb,
    const ushort_t* __restrict__ zx, const ushort_t* __restrict__ Bw,
    const float* __restrict__ gw, float* __restrict__ Cout) {
  __shared__ short sA[64 * LSTR];
  __shared__ short sB[128 * LSTR];
  __shared__ float swl[DI];
  __shared__ float rs[256];
  int tid = threadIdx.x;
  int bn = blockIdx.x * 128;
  int bm = blockIdx.y * 64;
  int wave = tid >> 6, lane = tid & 63;
  int wm = (wave >> 1) * 32, wn = (wave & 1) * 64;
  int q = lane >> 4, c = lane & 15;
  swl[tid] = gw[tid];
  swl[tid + 256] = gw[tid + 256];

  f32x4 acc[2][4];
  #pragma unroll
  for (int i = 0; i < 2; ++i)
    #pragma unroll
    for (int j = 0; j < 4; ++j) acc[i][j] = (f32x4)0.f;

  int ar = tid >> 2, ak = (tid & 3) * 8;
  int br = tid >> 1, bk = (tid & 1) * 16;
  const ushort_t* yrow = yb + (size_t)(bm + ar) * DI + ak;
  const ushort_t* zrow = zx + (size_t)(bm + ar) * DIPP + ak;
  const ushort_t* Bg = Bw + (size_t)(bn + br) * DI + bk;
  short* sAp = &sA[ar * LSTR + ak];
  short* sBp = &sB[br * LSTR + bk];
  float sumsq = 0.f;
  __syncthreads();

  for (int k0 = 0; k0 < DI; k0 += 32) {
    bf16x8 y8 = *(const bf16x8*)(yrow + k0);
    bf16x8 z8 = *(const bf16x8*)(zrow + k0);
    bf16x8 b0 = *(const bf16x8*)(Bg + k0);
    bf16x8 b1 = *(const bf16x8*)(Bg + k0 + 8);
    bf16x8 g8;
    #pragma unroll
    for (int e = 0; e < 8; ++e) {
      float zz = bf2f((ushort_t)z8[e]);
      float gg = bf2f((ushort_t)y8[e]) * (zz / (1.f + __expf(-zz)));
      sumsq += gg * gg;
      g8[e] = (short)f2bf(gg * swl[k0 + ak + e]);
    }
    __syncthreads();
    *(bf16x8*)(sAp)     = g8;
    *(bf16x8*)(sBp)     = b0;
    *(bf16x8*)(sBp + 8) = b1;
    __syncthreads();
    bf16x8 af[2], bfr[4];
    #pragma unroll
    for (int i = 0; i < 2; ++i)
      af[i] = *(const bf16x8*)&sA[(wm + i * 16 + c) * LSTR + q * 8];
    #pragma unroll
    for (int j = 0; j < 4; ++j)
      bfr[j] = *(const bf16x8*)&sB[(wn + j * 16 + c) * LSTR + q * 8];
    #pragma unroll
    for (int i = 0; i < 2; ++i)
      #pragma unroll
      for (int j = 0; j < 4; ++j)
        acc[i][j] = __builtin_amdgcn_mfma_f32_16x16x32_bf16(af[i], bfr[j], acc[i][j], 0, 0, 0);
  }
  rs[tid] = sumsq;
  __syncthreads();
  #pragma unroll
  for (int i = 0; i < 2; ++i) {
    #pragma unroll
    for (int r = 0; r < 4; ++r) {
      int ml = wm + i * 16 + q * 4 + r;
      float rtot = rs[ml * 4] + rs[ml * 4 + 1] + rs[ml * 4 + 2] + rs[ml * 4 + 3];
      float scale = rsqrtf(rtot * (1.f / DI) + 1e-5f);
      #pragma unroll
      for (int j = 0; j < 4; ++j) {
        int n = bn + wn + j * 16 + c;
        Cout[(size_t)(bm + ml) * DM + n] = scale * acc[i][j][r];
      }
    }
  }
}

// LDS-tiled conv(4)+bias+silu + fused U^T transpose. bf16 tile, vectorized I/O.
// grid (CDIM/128, LSEQ/64, NB), block 256. Tile: 64 tokens x 128 channels.
__global__ __launch_bounds__(256) void conv_silu(const ushort_t* __restrict__ zx,
    const float* __restrict__ cw, const float* __restrict__ cb,
    const float* __restrict__ dtb, ushort_t* __restrict__ xo,
    ushort_t* __restrict__ Bo, ushort_t* __restrict__ Co, ushort_t* __restrict__ Ut) {
  __shared__ ushort_t tile[67 * 128];   // 17.2 KB
  __shared__ ushort_t tt[128 * 65];     // 16.6 KB (x-blocks only)
  __shared__ float sdt[64];
  int tid = threadIdx.x;
  int ct = blockIdx.x, tb_ = blockIdx.y, b = blockIdx.z;
  int c0 = ct * 128, l0 = tb_ * 64;
  size_t rowb = (size_t)b * LSEQ;
  bool isx = (ct < 4);
  // stage 67 rows x 128 ch as bf16x8 (16B/slot)
  for (int slot = tid; slot < 67 * 16; slot += 256) {
    int r = slot >> 4, gg = slot & 15;
    int l = l0 + r - 3;
    bf16x8 v = (bf16x8)(short)0;
    if (l >= 0) v = *(const bf16x8*)&zx[(rowb + l) * DIPP + DI + c0 + gg * 8];
    *(bf16x8*)&tile[r * 128 + gg * 8] = v;
  }
  if (isx && tid < 64) sdt[tid] = dtb[rowb + l0 + tid];
  int g = tid & 15, tq = tid >> 4;     // g: 8-ch group, tq: token quad
  int cbase = c0 + g * 8;
  float w[4][8], bias[8];
  #pragma unroll
  for (int e = 0; e < 8; ++e) {
    float4 wv = *(const float4*)&cw[(cbase + e) * 4];
    w[0][e] = wv.x; w[1][e] = wv.y; w[2][e] = wv.z; w[3][e] = wv.w;
    bias[e] = cb[cbase + e];
  }
  __syncthreads();
  // register window: rows tq*4 .. tq*4+6 (bf16, convert on use)
  bf16x8 rows[7];
  #pragma unroll
  for (int r = 0; r < 7; ++r)
    rows[r] = *(const bf16x8*)&tile[(tq * 4 + r) * 128 + g * 8];
  #pragma unroll
  for (int it = 0; it < 4; ++it) {
    int t = tq * 4 + it;
    size_t tl = rowb + l0 + t;
    float dtv = isx ? sdt[t] : 0.f;
    bf16x8 o;
    #pragma unroll
    for (int e = 0; e < 8; ++e) {
      float s = bias[e]
              + w[0][e] * bf2f((ushort_t)rows[it][e])
              + w[1][e] * bf2f((ushort_t)rows[it + 1][e])
              + w[2][e] * bf2f((ushort_t)rows[it + 2][e])
              + w[3][e] * bf2f((ushort_t)rows[it + 3][e]);
      float v = s / (1.f + __expf(-s));
      o[e] = (short)f2bf(v);
      if (isx) tt[(g * 8 + e) * 65 + t] = f2bf(v * dtv);
    }
    if (isx) {
      *(bf16x8*)&xo[tl * DI + cbase] = o;
    } else if (g < 8) {
      *(bf16x8*)&Bo[tl * DS + (cbase - DI)] = o;
    } else {
      *(bf16x8*)&Co[tl * DS + (cbase - DI - DS)] = o;
    }
  }
  if (isx) {
    __syncthreads();
    int os = tid & 63;
    #pragma unroll
    for (int pass = 0; pass < 32; ++pass) {
      int op = (tid >> 6) + pass * 4;
      Ut[((size_t)b * DI + c0 + op) * LSEQ + l0 + os] = tt[op * 65 + os];
    }
  }
}

// dt = softplus(dt_raw + bias); per-chunk inclusive prefix sum. one wave per chunk.
__global__ __launch_bounds__(256) void csum_k(const ushort_t* __restrict__ zx,
    const float* __restrict__ dtbias, float* __restrict__ dtb, float* __restrict__ csumb) {
  int tid = threadIdx.x;
  int wave = tid >> 6, lane = tid & 63;
  int cg = blockIdx.x * 4 + wave;
  int b = cg >> 4, ch = cg & 15;
  size_t base = (size_t)b * LSEQ + ch * CL;
  float bias = dtbias[0];
  float x0 = bf2f(zx[(base + 2 * lane) * DIPP + (DIP - 1)]) + bias;
  float x1 = bf2f(zx[(base + 2 * lane + 1) * DIPP + (DIP - 1)]) + bias;
  float d0 = (x0 > 20.f) ? x0 : log1pf(__expf(x0));
  float d1 = (x1 > 20.f) ? x1 : log1pf(__expf(x1));
  dtb[base + 2 * lane] = d0;
  dtb[base + 2 * lane + 1] = d1;
  float p = d0 + d1;
  #pragma unroll
  for (int off = 1; off < 64; off <<= 1) {
    float t = __shfl_up(p, off, 64);
    if (lane >= off) p += t;
  }
  csumb[base + 2 * lane]     = p - d1;
  csumb[base + 2 * lane + 1] = p;
}

// state GEMM: Hloc[bc][n][p] = sum_s exp(A(S - cs[s])) * B[s][n] * U[s][p]
__global__ __launch_bounds__(256) void state_gemm(const ushort_t* __restrict__ Bb,
    const ushort_t* __restrict__ Ut, const float* __restrict__ csumb,
    const float* __restrict__ alog, float* __restrict__ hst) {
  __shared__ short sW[64 * 144];
  __shared__ short sX[128 * 40];
  __shared__ float scs[128];
  int tid = threadIdx.x;
  int ph = blockIdx.x, ch = blockIdx.y, b = blockIdx.z;
  int bc = b * NC + ch;
  size_t tb = (size_t)b * LSEQ + ch * CL;
  float Aval = -expf(alog[0]);
  if (tid < 128) scs[tid] = csumb[tb + tid];
  __syncthreads();
  float Stot = scs[127];
  {
    int s = tid >> 1, noff = (tid & 1) * 32;
    float scale = __expf(Aval * (Stot - scs[s]));
    #pragma unroll
    for (int blk = 0; blk < 4; ++blk) {
      bf16x8 v = *(const bf16x8*)&Bb[(tb + s) * DS + noff + blk * 8];
      #pragma unroll
      for (int e = 0; e < 8; ++e)
        sW[(noff + blk * 8 + e) * 144 + s] = (short)f2bf(bf2f((ushort_t)v[e]) * scale);
    }
  }
  int wave = tid >> 6, lane = tid & 63;
  int wn = (wave >> 1) * 32, wp = (wave & 1) * 64;
  int q = lane >> 4, c = lane & 15;
  f32x4 acc[2][4];
  #pragma unroll
  for (int i = 0; i < 2; ++i)
    #pragma unroll
    for (int j = 0; j < 4; ++j) acc[i][j] = (f32x4)0.f;

  for (int ks = 0; ks < 4; ++ks) {
    __syncthreads();
    {
      int r = tid >> 1, off = (tid & 1) * 16;
      size_t ua = ((size_t)b * DI + ph * 128 + r) * LSEQ + ch * CL + ks * 32 + off;
      bf16x8 u0 = *(const bf16x8*)&Ut[ua];
      bf16x8 u1 = *(const bf16x8*)&Ut[ua + 8];
      *(bf16x8*)&sX[r * 40 + off]     = u0;
      *(bf16x8*)&sX[r * 40 + off + 8] = u1;
    }
    __syncthreads();
    bf16x8 af[2], bfr[4];
    #pragma unroll
    for (int i = 0; i < 2; ++i)
      af[i] = *(const bf16x8*)&sW[(wn + i * 16 + c) * 144 + ks * 32 + q * 8];
    #pragma unroll
    for (int j = 0; j < 4; ++j)
      bfr[j] = *(const bf16x8*)&sX[(wp + j * 16 + c) * 40 + q * 8];
    #pragma unroll
    for (int i = 0; i < 2; ++i)
      #pragma unroll
      for (int j = 0; j < 4; ++j)
        acc[i][j] = __builtin_amdgcn_mfma_f32_16x16x32_bf16(af[i], bfr[j], acc[i][j], 0, 0, 0);
  }
  #pragma unroll
  for (int i = 0; i < 2; ++i) {
    int n = wn + i * 16 + q * 4;
    #pragma unroll
    for (int j = 0; j < 4; ++j) {
      int pg = ph * 128 + wp + j * 16 + c;
      #pragma unroll
      for (int r = 0; r < 4; ++r)
        hst[((size_t)bc * DS + n + r) * DI + pg] = acc[i][j][r];
    }
  }
}

// combine: sequential over chunks; outputs carry-in states hin[bc][p][n] bf16
__global__ __launch_bounds__(256) void combine2(const float* __restrict__ hst,
    const float* __restrict__ csumb, const float* __restrict__ alog,
    ushort_t* __restrict__ hin) {
  __shared__ ushort_t ts[64 * 17];
  int tid = threadIdx.x;
  int pt = blockIdx.x, nt = blockIdx.y, b = blockIdx.z;
  int p0 = pt * 64, n0 = nt * 16;
  int pl = tid & 63, ng = tid >> 6;
  float Aval = -expf(alog[0]);
  float h[4];
  #pragma unroll
  for (int i = 0; i < 4; ++i) h[i] = 0.f;
  for (int c = 0; c < NC; ++c) {
    int bc = b * NC + c;
    #pragma unroll
    for (int i = 0; i < 4; ++i)
      ts[pl * 17 + ng * 4 + i] = f2bf(h[i]);
    __syncthreads();
    {
      int on = tid & 15;
      #pragma unroll
      for (int pass = 0; pass < 4; ++pass) {
        int op = (tid >> 4) + pass * 16;
        hin[((size_t)bc * DI + p0 + op) * DS + n0 + on] = ts[op * 17 + on];
      }
    }
    __syncthreads();
    float Sc = csumb[(size_t)b * LSEQ + c * CL + CL - 1];
    float dec = __expf(Aval * Sc);
    #pragma unroll
    for (int i = 0; i < 4; ++i) {
      float loc = hst[((size_t)bc * DS + n0 + ng * 4 + i) * DI + p0 + pl];
      h[i] = h[i] * dec + loc;
    }
  }
}

// y GEMM: G=C@B^T -> M masked-decayed -> Y = M@U + Chat@Hin; y = Y + dp*x (bf16)
__global__ __launch_bounds__(256) void y_gemm(const ushort_t* __restrict__ Bb,
    const ushort_t* __restrict__ Cb, const ushort_t* __restrict__ Ut,
    const ushort_t* __restrict__ hin, const float* __restrict__ csumb,
    const float* __restrict__ alog, const float* __restrict__ dpar,
    const ushort_t* __restrict__ xb, ushort_t* __restrict__ y) {
  __shared__ short sC[128 * 72];
  __shared__ short sM[128 * 136];
  __shared__ short sU[128 * 80];
  __shared__ float scs[128];
  int tid = threadIdx.x;
  int ph = blockIdx.x, ch = blockIdx.y, b = blockIdx.z;
  int bc = b * NC + ch;
  size_t tb = (size_t)b * LSEQ + ch * CL;
  float Aval = -expf(alog[0]);
  float dp = dpar[0];
  int wave = tid >> 6, lane = tid & 63;
  int q = lane >> 4, c = lane & 15;

  {
    int r = tid >> 1, off = (tid & 1) * 32;
    #pragma unroll
    for (int blk = 0; blk < 4; ++blk) {
      *(bf16x8*)&sC[r * 72 + off + blk * 8] = *(const bf16x8*)&Cb[(tb + r) * DS + off + blk * 8];
      *(bf16x8*)&sU[r * 80 + off + blk * 8] = *(const bf16x8*)&Bb[(tb + r) * DS + off + blk * 8];
    }
  }
  if (tid < 128) scs[tid] = csumb[tb + tid];
  __syncthreads();

  // phase 1: G = C @ B^T (128t x 128s, K=64)
  {
    int wm = (wave >> 1) * 64, wss = (wave & 1) * 64;
    f32x4 g[4][4];
    #pragma unroll
    for (int i = 0; i < 4; ++i)
      #pragma unroll
      for (int j = 0; j < 4; ++j) g[i][j] = (f32x4)0.f;
    #pragma unroll
    for (int k0 = 0; k0 < 64; k0 += 32) {
      bf16x8 af[4], bfr[4];
      #pragma unroll
      for (int i = 0; i < 4; ++i)
        af[i] = *(const bf16x8*)&sC[(wm + i * 16 + c) * 72 + k0 + q * 8];
      #pragma unroll
      for (int j = 0; j < 4; ++j)
        bfr[j] = *(const bf16x8*)&sU[(wss + j * 16 + c) * 80 + k0 + q * 8];
      #pragma unroll
      for (int i = 0; i < 4; ++i)
        #pragma unroll
        for (int j = 0; j < 4; ++j)
          g[i][j] = __builtin_amdgcn_mfma_f32_16x16x32_bf16(af[i], bfr[j], g[i][j], 0, 0, 0);
    }
    #pragma unroll
    for (int i = 0; i < 4; ++i) {
      #pragma unroll
      for (int r = 0; r < 4; ++r) {
        int t = wm + i * 16 + q * 4 + r;
        float ct = scs[t];
        #pragma unroll
        for (int j = 0; j < 4; ++j) {
          int s = wss + j * 16 + c;
          float v = g[i][j][r];
          float m = (s <= t) ? v * __expf(Aval * (ct - scs[s])) : 0.f;
          sM[t * 136 + s] = (short)f2bf(m);
        }
      }
    }
  }

  // phase 2: Y (128t x 128p) = M @ U + Chat @ Hin
  int wm2 = (wave >> 1) * 64, wp = (wave & 1) * 64;
  f32x4 acc[4][4];
  #pragma unroll
  for (int i = 0; i < 4; ++i)
    #pragma unroll
    for (int j = 0; j < 4; ++j) acc[i][j] = (f32x4)0.f;

  for (int ks = 0; ks < 4; ++ks) {
    __syncthreads();
    {
      int r = tid >> 1, off = (tid & 1) * 16;
      size_t ua = ((size_t)b * DI + ph * 128 + r) * LSEQ + ch * CL + ks * 32 + off;
      bf16x8 u0 = *(const bf16x8*)&Ut[ua];
      bf16x8 u1 = *(const bf16x8*)&Ut[ua + 8];
      *(bf16x8*)&sU[r * 40 + off]     = u0;
      *(bf16x8*)&sU[r * 40 + off + 8] = u1;
    }
    __syncthreads();
    bf16x8 af[4], bfr[4];
    #pragma unroll
    for (int i = 0; i < 4; ++i)
      af[i] = *(const bf16x8*)&sM[(wm2 + i * 16 + c) * 136 + ks * 32 + q * 8];
    #pragma unroll
    for (int j = 0; j < 4; ++j)
      bfr[j] = *(const bf16x8*)&sU[(wp + j * 16 + c) * 40 + q * 8];
    #pragma unroll
    for (int i = 0; i < 4; ++i)
      #pragma unroll
      for (int j = 0; j < 4; ++j)
        acc[i][j] = __builtin_amdgcn_mfma_f32_16x16x32_bf16(af[i], bfr[j], acc[i][j], 0, 0, 0);
  }

  __syncthreads();
  {
    int r = tid >> 1, off = (tid & 1) * 32;
    float sc_t = __expf(Aval * scs[r]);
    #pragma unroll
    for (int blk = 0; blk < 4; ++blk) {
      bf16x8 v = *(const bf16x8*)&sC[r * 72 + off + blk * 8];
      bf16x8 o;
      #pragma unroll
      for (int e = 0; e < 8; ++e)
        o[e] = (short)f2bf(bf2f((ushort_t)v[e]) * sc_t);
      *(bf16x8*)&sM[r * 80 + off + blk * 8] = o;
    }
  }
  for (int ks = 4; ks < 6; ++ks) {
    __syncthreads();
    {
      int r = tid >> 1, off = (tid & 1) * 16;
      size_t ha = ((size_t)bc * DI + ph * 128 + r) * DS + (ks - 4) * 32 + off;
      bf16x8 h0 = *(const bf16x8*)&hin[ha];
      bf16x8 h1 = *(const bf16x8*)&hin[ha + 8];
      *(bf16x8*)&sU[r * 40 + off]     = h0;
      *(bf16x8*)&sU[r * 40 + off + 8] = h1;
    }
    __syncthreads();
    bf16x8 af[4], bfr[4];
    #pragma unroll
    for (int i = 0; i < 4; ++i)
      af[i] = *(const bf16x8*)&sM[(wm2 + i * 16 + c) * 80 + (ks - 4) * 32 + q * 8];
    #pragma unroll
    for (int j = 0; j < 4; ++j)
      bfr[j] = *(const bf16x8*)&sU[(wp + j * 16 + c) * 40 + q * 8];
    #pragma unroll
    for (int i = 0; i < 4; ++i)
      #pragma unroll
      for (int j = 0; j < 4; ++j)
        acc[i][j] = __builtin_amdgcn_mfma_f32_16x16x32_bf16(af[i], bfr[j], acc[i][j], 0, 0, 0);
  }

  #pragma unroll
  for (int i = 0; i < 4; ++i) {
    #pragma unroll
    for (int r = 0; r < 4; ++r) {
      int t = wm2 + i * 16 + q * 4 + r;
      size_t row = (tb + t) * DI;
      #pragma unroll
      for (int j = 0; j < 4; ++j) {
        int pg = ph * 128 + wp + j * 16 + c;
        y[row + pg] = f2bf(acc[i][j][r] + dp * bf2f(xb[row + pg]));
      }
    }
  }
}

// last token only
__global__ __launch_bounds__(256) void finalize(const float* __restrict__ resid,
    const float* __restrict__ mixo, const float* __restrict__ embed,
    const float* __restrict__ nfw, float* __restrict__ out) {
  int b = blockIdx.x, tid = threadIdx.x;
  __shared__ float fin[DM];
  size_t off = ((size_t)b * LSEQ + (LSEQ - 1)) * DM;
  float r = resid[off + tid] + mixo[off + tid];
  float ss = block_reduce_sum256(r * r);
  fin[tid] = r * rsqrtf(ss * (1.f / DM) + 1e-5f) * nfw[tid];
  __syncthreads();
  if (tid < VOC) {
    float acc = 0.f;
    #pragma unroll 8
    for (int d = 0; d < DM; ++d) acc += fin[d] * embed[(size_t)tid * DM + d];
    out[b * VOC + tid] = acc;
  }
}

extern "C" void kernel_launch(void* const* d_in, const int* in_sizes, int n_in,
                              void* d_out, int out_size, void* d_ws, size_t ws_size,
                              hipStream_t stream) {
  const int*   ids   = (const int*)d_in[0];
  const float* embed = (const float*)d_in[1];
  const float* ipw   = (const float*)d_in[2];
  const float* cw    = (const float*)d_in[3];
  const float* cb    = (const float*)d_in[4];
  const float* dtbias= (const float*)d_in[5];
  const float* alog  = (const float*)d_in[6];
  const float* dpar  = (const float*)d_in[7];
  const float* ngw   = (const float*)d_in[8];
  const float* opw   = (const float*)d_in[9];
  const float* bnw   = (const float*)d_in[10];
  const float* nfw   = (const float*)d_in[11];
  float* out = (float*)d_out;

  // workspace layout (~156 MB)
  char* p = (char*)d_ws;
  float* resid = (float*)p;            p += (size_t)TKN * DM * 4;
  float* mixo  = (float*)p;            p += (size_t)TKN * DM * 4;
  ushort_t* hn = (ushort_t*)p;         p += (size_t)TKN * DM * 2;
  ushort_t* zx = (ushort_t*)p;         p += (size_t)TKN * DIPP * 2;
  float* dtb   = (float*)p;            p += (size_t)TKN * 4;
  float* csumb = (float*)p;            p += (size_t)TKN * 4;
  ushort_t* xb = (ushort_t*)p;         p += (size_t)TKN * DI * 2;
  ushort_t* yb = (ushort_t*)p;         p += (size_t)TKN * DI * 2;
  ushort_t* Bb = (ushort_t*)p;         p += (size_t)TKN * DS * 2;
  ushort_t* Cb = (ushort_t*)p;         p += (size_t)TKN * DS * 2;
  ushort_t* Ut = (ushort_t*)p;         p += (size_t)TKN * DI * 2;
  ushort_t* hin= (ushort_t*)p;         p += (size_t)NB * NC * DI * DS * 2;
  ushort_t* wbi= (ushort_t*)p;         p += (size_t)NL * DIP * DM * 2;
  ushort_t* wbo= (ushort_t*)p;         p += (size_t)NL * DM * DI * 2;
  // hst (fp32) aliases yb (bf16): consumed by combine2 before y_gemm writes yb
  float* hst = (float*)yb;

  convert_w<<<(NL * DIP * DM + NL * DM * DI + 1023) / 1024, 256, 0, stream>>>(
      ipw, opw, wbi, wbo);
  embed_init<<<TKN, 256, 0, stream>>>(ids, embed, mixo, resid);

  for (int i = 0; i < NL; ++i) {
    add_rmsnorm<<<TKN / 4, 256, 0, stream>>>(resid, mixo, hn, bnw + (size_t)i * DM);
    gemm_nt_bf16<ushort_t><<<dim3((DIP + 127) / 128, TKN / 128), 256, 0, stream>>>(
        hn, wbi + (size_t)i * DIP * DM, zx, DIP, DM, DIPP);
    csum_k<<<32, 256, 0, stream>>>(zx, dtbias + i, dtb, csumb);
    conv_silu<<<dim3(CDIM / 128, LSEQ / 64, NB), 256, 0, stream>>>(
        zx, cw + (size_t)i * CDIM * 4, cb + (size_t)i * CDIM, dtb, xb, Bb, Cb, Ut);
    state_gemm<<<dim3(4, NC, NB), 256, 0, stream>>>(Bb, Ut, csumb, alog + i, hst);
    combine2<<<dim3(DI / 64, 4, NB), 256, 0, stream>>>(hst, csumb, alog + i, hin);
    y_gemm<<<dim3(4, NC, NB), 256, 0, stream>>>(Bb, Cb, Ut, hin, csumb, alog + i,
                                                dpar + i, xb, yb);
    outproj_fused<<<dim3(2, TKN / 64), 256, 0, stream>>>(
        yb, zx, wbo + (size_t)i * DM * DI, ngw + (size_t)i * DI, mixo);
  }

  finalize<<<NB, 256, 0, stream>>>(resid, mixo, embed, nfw, out);
}

// Round 9
// 580.490 us; speedup vs baseline: 3.5989x; 1.0351x over previous
//
#include <hip/hip_runtime.h>
#include <math.h>

// ---- problem constants ----
#define NB    8        // batch
#define LSEQ  2048     // seq len
#define TKN   16384    // NB*LSEQ tokens
#define DM    256      // d_model
#define DI    512      // d_inner
#define DS    64       // d_state
#define DIP   1153     // 2*DI + 2*DS + 1
#define DIPP  1160     // padded row stride for zx (bf16)
#define CDIM  640      // DI + 2*DS
#define NL    4
#define NC    16       // scan chunks
#define CL    128      // LSEQ/NC
#define VOC   100

typedef short bf16x8 __attribute__((ext_vector_type(8)));
typedef short bf16x4 __attribute__((ext_vector_type(4)));
typedef float f32x4  __attribute__((ext_vector_type(4)));
typedef unsigned short ushort_t;

__device__ __forceinline__ float block_reduce_sum256(float v) {
  __shared__ float sred[4];
  #pragma unroll
  for (int off = 32; off > 0; off >>= 1) v += __shfl_down(v, off, 64);
  int lane = threadIdx.x & 63, wid = threadIdx.x >> 6;
  if (lane == 0) sred[wid] = v;
  __syncthreads();
  return sred[0] + sred[1] + sred[2] + sred[3];
}

__device__ __forceinline__ unsigned short f2bf(float f) {
  unsigned int u = __float_as_uint(f);
  unsigned int r = u + 0x7FFFu + ((u >> 16) & 1u);   // RNE
  return (unsigned short)(r >> 16);
}
__device__ __forceinline__ float bf2f(unsigned short u) {
  return __uint_as_float(((unsigned int)u) << 16);
}

// convert fp32 weights -> bf16 once per call
__global__ __launch_bounds__(256) void convert_w(const float* __restrict__ ipw,
    const float* __restrict__ opw, ushort_t* __restrict__ wbi, ushort_t* __restrict__ wbo) {
  const int n1 = NL * DIP * DM;
  const int n2 = NL * DM * DI;
  int i4 = (blockIdx.x * 256 + threadIdx.x) * 4;
  if (i4 < n1) {
    float4 v = *(const float4*)(ipw + i4);
    bf16x4 o; o[0] = (short)f2bf(v.x); o[1] = (short)f2bf(v.y);
    o[2] = (short)f2bf(v.z); o[3] = (short)f2bf(v.w);
    *(bf16x4*)(wbi + i4) = o;
  } else {
    int j = i4 - n1;
    if (j < n2) {
      float4 v = *(const float4*)(opw + j);
      bf16x4 o; o[0] = (short)f2bf(v.x); o[1] = (short)f2bf(v.y);
      o[2] = (short)f2bf(v.z); o[3] = (short)f2bf(v.w);
      *(bf16x4*)(wbo + j) = o;
    }
  }
}

// resid (+)= mixo (or embed gather when first); hn = bf16(rmsnorm(resid)*w).
// One wave per token, 4 tokens/block.
__global__ __launch_bounds__(256) void add_rmsnorm(float* __restrict__ resid,
    const float* __restrict__ mixo, ushort_t* __restrict__ hn, const float* __restrict__ w,
    const int* __restrict__ ids, const float* __restrict__ embed, int first) {
  int wave = threadIdx.x >> 6, lane = threadIdx.x & 63;
  int t = blockIdx.x * 4 + wave;
  size_t o = (size_t)t * DM + lane * 4;
  float4 r4;
  if (first) {
    int id = ids[t];
    r4 = *(const float4*)&embed[(size_t)id * DM + lane * 4];
  } else {
    float4 m4 = *(const float4*)&mixo[o];
    r4 = *(const float4*)&resid[o];
    r4.x += m4.x; r4.y += m4.y; r4.z += m4.z; r4.w += m4.w;
  }
  *(float4*)&resid[o] = r4;
  float ss = r4.x * r4.x + r4.y * r4.y + r4.z * r4.z + r4.w * r4.w;
  #pragma unroll
  for (int m = 32; m >= 1; m >>= 1) ss += __shfl_xor(ss, m, 64);
  float sc = rsqrtf(ss * (1.f / DM) + 1e-5f);
  float4 w4 = *(const float4*)&w[lane * 4];
  bf16x4 o4;
  o4[0] = (short)f2bf(r4.x * sc * w4.x);
  o4[1] = (short)f2bf(r4.y * sc * w4.y);
  o4[2] = (short)f2bf(r4.z * sc * w4.z);
  o4[3] = (short)f2bf(r4.w * sc * w4.w);
  *(bf16x4*)&hn[o] = o4;
}

// ---------------- bf16 MFMA GEMM (A bf16, B bf16), BK=64 ----------------
#define LSTR  40
#define LSTR2 72
template<typename TC>
__global__ __launch_bounds__(256) void gemm_nt_bf16(const ushort_t* __restrict__ A,
    const ushort_t* __restrict__ Bw, TC* __restrict__ C, int N, int K, int ldc) {
  __shared__ short sA[128 * LSTR2];
  __shared__ short sB[128 * LSTR2];
  int tid = threadIdx.x;
  int bn = blockIdx.x * 128;
  int bm = blockIdx.y * 128;
  int wave = tid >> 6, lane = tid & 63;
  int wm = (wave >> 1) * 64, wn = (wave & 1) * 64;
  int q = lane >> 4, c = lane & 15;

  f32x4 acc[4][4];
  #pragma unroll
  for (int i = 0; i < 4; ++i)
    #pragma unroll
    for (int j = 0; j < 4; ++j) acc[i][j] = (f32x4)0.f;

  int sr = tid >> 1;
  int sc = (tid & 1) * 32;
  const ushort_t* Ag = A + (size_t)(bm + sr) * K + sc;
  const ushort_t* Bg = Bw + (size_t)(bn + sr) * K + sc;
  bool bok = (bn + sr) < N;
  short* sAp = &sA[sr * LSTR2 + sc];
  short* sBp = &sB[sr * LSTR2 + sc];

  for (int k0 = 0; k0 < K; k0 += 64) {
    bf16x8 a0 = *(const bf16x8*)(Ag + k0);
    bf16x8 a1 = *(const bf16x8*)(Ag + k0 + 8);
    bf16x8 a2 = *(const bf16x8*)(Ag + k0 + 16);
    bf16x8 a3 = *(const bf16x8*)(Ag + k0 + 24);
    bf16x8 b0 = (bf16x8)(short)0, b1 = (bf16x8)(short)0;
    bf16x8 b2 = (bf16x8)(short)0, b3 = (bf16x8)(short)0;
    if (bok) {
      b0 = *(const bf16x8*)(Bg + k0);
      b1 = *(const bf16x8*)(Bg + k0 + 8);
      b2 = *(const bf16x8*)(Bg + k0 + 16);
      b3 = *(const bf16x8*)(Bg + k0 + 24);
    }
    __syncthreads();
    *(bf16x8*)(sAp)      = a0;
    *(bf16x8*)(sAp + 8)  = a1;
    *(bf16x8*)(sAp + 16) = a2;
    *(bf16x8*)(sAp + 24) = a3;
    *(bf16x8*)(sBp)      = b0;
    *(bf16x8*)(sBp + 8)  = b1;
    *(bf16x8*)(sBp + 16) = b2;
    *(bf16x8*)(sBp + 24) = b3;
    __syncthreads();
    #pragma unroll
    for (int ks = 0; ks < 2; ++ks) {
      bf16x8 af[4], bfr[4];
      #pragma unroll
      for (int i = 0; i < 4; ++i)
        af[i] = *(const bf16x8*)&sA[(wm + i * 16 + c) * LSTR2 + ks * 32 + q * 8];
      #pragma unroll
      for (int j = 0; j < 4; ++j)
        bfr[j] = *(const bf16x8*)&sB[(wn + j * 16 + c) * LSTR2 + ks * 32 + q * 8];
      #pragma unroll
      for (int i = 0; i < 4; ++i)
        #pragma unroll
        for (int j = 0; j < 4; ++j)
          acc[i][j] = __builtin_amdgcn_mfma_f32_16x16x32_bf16(af[i], bfr[j], acc[i][j], 0, 0, 0);
    }
  }
  #pragma unroll
  for (int i = 0; i < 4; ++i) {
    int m = bm + wm + i * 16 + q * 4;
    #pragma unroll
    for (int j = 0; j < 4; ++j) {
      int n = bn + wn + j * 16 + c;
      if (n < N) {
        #pragma unroll
        for (int r = 0; r < 4; ++r) {
          if constexpr (sizeof(TC) == 2)
            C[(size_t)(m + r) * ldc + n] = (TC)f2bf(acc[i][j][r]);
          else
            C[(size_t)(m + r) * ldc + n] = acc[i][j][r];
        }
      }
    }
  }
}

// fused out_proj: C = rownorm * ((y*silu(z))*w) @ Wb^T
// Tile M=64 x N=128, grid (2, TKN/64) = 512 blocks, block 256 (2x2 waves).
__global__ __launch_bounds__(256) void outproj_fused(const ushort_t* __restrict__ yb,
    const ushort_t* __restrict__ zx, const ushort_t* __restrict__ Bw,
    const float* __restrict__ gw, float* __restrict__ Cout) {
  __shared__ short sA[64 * LSTR];
  __shared__ short sB[128 * LSTR];
  __shared__ float swl[DI];
  __shared__ float rs[256];
  int tid = threadIdx.x;
  int bn = blockIdx.x * 128;
  int bm = blockIdx.y * 64;
  int wave = tid >> 6, lane = tid & 63;
  int wm = (wave >> 1) * 32, wn = (wave & 1) * 64;
  int q = lane >> 4, c = lane & 15;
  swl[tid] = gw[tid];
  swl[tid + 256] = gw[tid + 256];

  f32x4 acc[2][4];
  #pragma unroll
  for (int i = 0; i < 2; ++i)
    #pragma unroll
    for (int j = 0; j < 4; ++j) acc[i][j] = (f32x4)0.f;

  int ar = tid >> 2, ak = (tid & 3) * 8;
  int br = tid >> 1, bk = (tid & 1) * 16;
  const ushort_t* yrow = yb + (size_t)(bm + ar) * DI + ak;
  const ushort_t* zrow = zx + (size_t)(bm + ar) * DIPP + ak;
  const ushort_t* Bg = Bw + (size_t)(bn + br) * DI + bk;
  short* sAp = &sA[ar * LSTR + ak];
  short* sBp = &sB[br * LSTR + bk];
  float sumsq = 0.f;
  __syncthreads();

  for (int k0 = 0; k0 < DI; k0 += 32) {
    bf16x8 y8 = *(const bf16x8*)(yrow + k0);
    bf16x8 z8 = *(const bf16x8*)(zrow + k0);
    bf16x8 b0 = *(const bf16x8*)(Bg + k0);
    bf16x8 b1 = *(const bf16x8*)(Bg + k0 + 8);
    bf16x8 g8;
    #pragma unroll
    for (int e = 0; e < 8; ++e) {
      float zz = bf2f((ushort_t)z8[e]);
      float gg = bf2f((ushort_t)y8[e]) * (zz / (1.f + __expf(-zz)));
      sumsq += gg * gg;
      g8[e] = (short)f2bf(gg * swl[k0 + ak + e]);
    }
    __syncthreads();
    *(bf16x8*)(sAp)     = g8;
    *(bf16x8*)(sBp)     = b0;
    *(bf16x8*)(sBp + 8) = b1;
    __syncthreads();
    bf16x8 af[2], bfr[4];
    #pragma unroll
    for (int i = 0; i < 2; ++i)
      af[i] = *(const bf16x8*)&sA[(wm + i * 16 + c) * LSTR + q * 8];
    #pragma unroll
    for (int j = 0; j < 4; ++j)
      bfr[j] = *(const bf16x8*)&sB[(wn + j * 16 + c) * LSTR + q * 8];
    #pragma unroll
    for (int i = 0; i < 2; ++i)
      #pragma unroll
      for (int j = 0; j < 4; ++j)
        acc[i][j] = __builtin_amdgcn_mfma_f32_16x16x32_bf16(af[i], bfr[j], acc[i][j], 0, 0, 0);
  }
  rs[tid] = sumsq;
  __syncthreads();
  #pragma unroll
  for (int i = 0; i < 2; ++i) {
    #pragma unroll
    for (int r = 0; r < 4; ++r) {
      int ml = wm + i * 16 + q * 4 + r;
      float rtot = rs[ml * 4] + rs[ml * 4 + 1] + rs[ml * 4 + 2] + rs[ml * 4 + 3];
      float scale = rsqrtf(rtot * (1.f / DI) + 1e-5f);
      #pragma unroll
      for (int j = 0; j < 4; ++j) {
        int n = bn + wn + j * 16 + c;
        Cout[(size_t)(bm + ml) * DM + n] = scale * acc[i][j][r];
      }
    }
  }
}

// LDS-tiled conv(4)+bias+silu + fused U^T transpose. bf16 tile, vectorized I/O.
// grid (CDIM/128, LSEQ/64, NB), block 256. Tile: 64 tokens x 128 channels.
__global__ __launch_bounds__(256) void conv_silu(const ushort_t* __restrict__ zx,
    const float* __restrict__ cw, const float* __restrict__ cb,
    const float* __restrict__ dtb, ushort_t* __restrict__ xo,
    ushort_t* __restrict__ Bo, ushort_t* __restrict__ Co, ushort_t* __restrict__ Ut) {
  __shared__ ushort_t tile[67 * 128];   // 17.2 KB
  __shared__ ushort_t tt[128 * 72];     // 18.4 KB (x-blocks only), 16B-aligned rows
  __shared__ float sdt[64];
  int tid = threadIdx.x;
  int ct = blockIdx.x, tb_ = blockIdx.y, b = blockIdx.z;
  int c0 = ct * 128, l0 = tb_ * 64;
  size_t rowb = (size_t)b * LSEQ;
  bool isx = (ct < 4);
  for (int slot = tid; slot < 67 * 16; slot += 256) {
    int r = slot >> 4, gg = slot & 15;
    int l = l0 + r - 3;
    bf16x8 v = (bf16x8)(short)0;
    if (l >= 0) v = *(const bf16x8*)&zx[(rowb + l) * DIPP + DI + c0 + gg * 8];
    *(bf16x8*)&tile[r * 128 + gg * 8] = v;
  }
  if (isx && tid < 64) sdt[tid] = dtb[rowb + l0 + tid];
  int g = tid & 15, tq = tid >> 4;
  int cbase = c0 + g * 8;
  float w[4][8], bias[8];
  #pragma unroll
  for (int e = 0; e < 8; ++e) {
    float4 wv = *(const float4*)&cw[(cbase + e) * 4];
    w[0][e] = wv.x; w[1][e] = wv.y; w[2][e] = wv.z; w[3][e] = wv.w;
    bias[e] = cb[cbase + e];
  }
  __syncthreads();
  bf16x8 rows[7];
  #pragma unroll
  for (int r = 0; r < 7; ++r)
    rows[r] = *(const bf16x8*)&tile[(tq * 4 + r) * 128 + g * 8];
  #pragma unroll
  for (int it = 0; it < 4; ++it) {
    int t = tq * 4 + it;
    size_t tl = rowb + l0 + t;
    float dtv = isx ? sdt[t] : 0.f;
    bf16x8 o;
    #pragma unroll
    for (int e = 0; e < 8; ++e) {
      float s = bias[e]
              + w[0][e] * bf2f((ushort_t)rows[it][e])
              + w[1][e] * bf2f((ushort_t)rows[it + 1][e])
              + w[2][e] * bf2f((ushort_t)rows[it + 2][e])
              + w[3][e] * bf2f((ushort_t)rows[it + 3][e]);
      float v = s / (1.f + __expf(-s));
      o[e] = (short)f2bf(v);
      if (isx) tt[(g * 8 + e) * 72 + t] = f2bf(v * dtv);
    }
    if (isx) {
      *(bf16x8*)&xo[tl * DI + cbase] = o;
    } else if (g < 8) {
      *(bf16x8*)&Bo[tl * DS + (cbase - DI)] = o;
    } else {
      *(bf16x8*)&Co[tl * DS + (cbase - DI - DS)] = o;
    }
  }
  if (isx) {
    __syncthreads();
    // vectorized transpose store: 1024 slots of 16B, 4 per thread
    #pragma unroll
    for (int pass = 0; pass < 4; ++pass) {
      int slot = pass * 256 + tid;
      int op = slot >> 3, sg = slot & 7;
      bf16x8 v = *(const bf16x8*)&tt[op * 72 + sg * 8];
      *(bf16x8*)&Ut[((size_t)b * DI + c0 + op) * LSEQ + l0 + sg * 8] = v;
    }
  }
}

// dt = softplus(dt_raw + bias); per-chunk inclusive prefix sum. one wave per chunk.
__global__ __launch_bounds__(256) void csum_k(const ushort_t* __restrict__ zx,
    const float* __restrict__ dtbias, float* __restrict__ dtb, float* __restrict__ csumb) {
  int tid = threadIdx.x;
  int wave = tid >> 6, lane = tid & 63;
  int cg = blockIdx.x * 4 + wave;
  int b = cg >> 4, ch = cg & 15;
  size_t base = (size_t)b * LSEQ + ch * CL;
  float bias = dtbias[0];
  float x0 = bf2f(zx[(base + 2 * lane) * DIPP + (DIP - 1)]) + bias;
  float x1 = bf2f(zx[(base + 2 * lane + 1) * DIPP + (DIP - 1)]) + bias;
  float d0 = (x0 > 20.f) ? x0 : log1pf(__expf(x0));
  float d1 = (x1 > 20.f) ? x1 : log1pf(__expf(x1));
  dtb[base + 2 * lane] = d0;
  dtb[base + 2 * lane + 1] = d1;
  float p = d0 + d1;
  #pragma unroll
  for (int off = 1; off < 64; off <<= 1) {
    float t = __shfl_up(p, off, 64);
    if (lane >= off) p += t;
  }
  csumb[base + 2 * lane]     = p - d1;
  csumb[base + 2 * lane + 1] = p;
}

// state GEMM: Hloc[bc][n][p] = sum_s exp(A(S - cs[s])) * B[s][n] * U[s][p]
__global__ __launch_bounds__(256) void state_gemm(const ushort_t* __restrict__ Bb,
    const ushort_t* __restrict__ Ut, const float* __restrict__ csumb,
    const float* __restrict__ alog, float* __restrict__ hst) {
  __shared__ short sW[64 * 144];
  __shared__ short sX[128 * 40];
  __shared__ float scs[128];
  int tid = threadIdx.x;
  int ph = blockIdx.x, ch = blockIdx.y, b = blockIdx.z;
  int bc = b * NC + ch;
  size_t tb = (size_t)b * LSEQ + ch * CL;
  float Aval = -expf(alog[0]);
  if (tid < 128) scs[tid] = csumb[tb + tid];
  __syncthreads();
  float Stot = scs[127];
  {
    int s = tid >> 1, noff = (tid & 1) * 32;
    float scale = __expf(Aval * (Stot - scs[s]));
    #pragma unroll
    for (int blk = 0; blk < 4; ++blk) {
      bf16x8 v = *(const bf16x8*)&Bb[(tb + s) * DS + noff + blk * 8];
      #pragma unroll
      for (int e = 0; e < 8; ++e)
        sW[(noff + blk * 8 + e) * 144 + s] = (short)f2bf(bf2f((ushort_t)v[e]) * scale);
    }
  }
  int wave = tid >> 6, lane = tid & 63;
  int wn = (wave >> 1) * 32, wp = (wave & 1) * 64;
  int q = lane >> 4, c = lane & 15;
  f32x4 acc[2][4];
  #pragma unroll
  for (int i = 0; i < 2; ++i)
    #pragma unroll
    for (int j = 0; j < 4; ++j) acc[i][j] = (f32x4)0.f;

  for (int ks = 0; ks < 4; ++ks) {
    __syncthreads();
    {
      int r = tid >> 1, off = (tid & 1) * 16;
      size_t ua = ((size_t)b * DI + ph * 128 + r) * LSEQ + ch * CL + ks * 32 + off;
      bf16x8 u0 = *(const bf16x8*)&Ut[ua];
      bf16x8 u1 = *(const bf16x8*)&Ut[ua + 8];
      *(bf16x8*)&sX[r * 40 + off]     = u0;
      *(bf16x8*)&sX[r * 40 + off + 8] = u1;
    }
    __syncthreads();
    bf16x8 af[2], bfr[4];
    #pragma unroll
    for (int i = 0; i < 2; ++i)
      af[i] = *(const bf16x8*)&sW[(wn + i * 16 + c) * 144 + ks * 32 + q * 8];
    #pragma unroll
    for (int j = 0; j < 4; ++j)
      bfr[j] = *(const bf16x8*)&sX[(wp + j * 16 + c) * 40 + q * 8];
    #pragma unroll
    for (int i = 0; i < 2; ++i)
      #pragma unroll
      for (int j = 0; j < 4; ++j)
        acc[i][j] = __builtin_amdgcn_mfma_f32_16x16x32_bf16(af[i], bfr[j], acc[i][j], 0, 0, 0);
  }
  #pragma unroll
  for (int i = 0; i < 2; ++i) {
    int n = wn + i * 16 + q * 4;
    #pragma unroll
    for (int j = 0; j < 4; ++j) {
      int pg = ph * 128 + wp + j * 16 + c;
      #pragma unroll
      for (int r = 0; r < 4; ++r)
        hst[((size_t)bc * DS + n + r) * DI + pg] = acc[i][j][r];
    }
  }
}

// combine: sequential over chunks; outputs carry-in states hin[bc][p][n] bf16
__global__ __launch_bounds__(256) void combine2(const float* __restrict__ hst,
    const float* __restrict__ csumb, const float* __restrict__ alog,
    ushort_t* __restrict__ hin) {
  __shared__ ushort_t ts[64 * 17];
  int tid = threadIdx.x;
  int pt = blockIdx.x, nt = blockIdx.y, b = blockIdx.z;
  int p0 = pt * 64, n0 = nt * 16;
  int pl = tid & 63, ng = tid >> 6;
  float Aval = -expf(alog[0]);
  float h[4];
  #pragma unroll
  for (int i = 0; i < 4; ++i) h[i] = 0.f;
  for (int c = 0; c < NC; ++c) {
    int bc = b * NC + c;
    #pragma unroll
    for (int i = 0; i < 4; ++i)
      ts[pl * 17 + ng * 4 + i] = f2bf(h[i]);
    __syncthreads();
    {
      int on = tid & 15;
      #pragma unroll
      for (int pass = 0; pass < 4; ++pass) {
        int op = (tid >> 4) + pass * 16;
        hin[((size_t)bc * DI + p0 + op) * DS + n0 + on] = ts[op * 17 + on];
      }
    }
    __syncthreads();
    float Sc = csumb[(size_t)b * LSEQ + c * CL + CL - 1];
    float dec = __expf(Aval * Sc);
    #pragma unroll
    for (int i = 0; i < 4; ++i) {
      float loc = hst[((size_t)bc * DS + n0 + ng * 4 + i) * DI + p0 + pl];
      h[i] = h[i] * dec + loc;
    }
  }
}

// y GEMM: G=C@B^T -> M masked-decayed -> Y = M@U + Chat@Hin; y = Y + dp*x (bf16)
__global__ __launch_bounds__(256) void y_gemm(const ushort_t* __restrict__ Bb,
    const ushort_t* __restrict__ Cb, const ushort_t* __restrict__ Ut,
    const ushort_t* __restrict__ hin, const float* __restrict__ csumb,
    const float* __restrict__ alog, const float* __restrict__ dpar,
    const ushort_t* __restrict__ xb, ushort_t* __restrict__ y) {
  __shared__ short sC[128 * 72];
  __shared__ short sM[128 * 136];
  __shared__ short sU[128 * 80];
  __shared__ float scs[128];
  int tid = threadIdx.x;
  int ph = blockIdx.x, ch = blockIdx.y, b = blockIdx.z;
  int bc = b * NC + ch;
  size_t tb = (size_t)b * LSEQ + ch * CL;
  float Aval = -expf(alog[0]);
  float dp = dpar[0];
  int wave = tid >> 6, lane = tid & 63;
  int q = lane >> 4, c = lane & 15;

  {
    int r = tid >> 1, off = (tid & 1) * 32;
    #pragma unroll
    for (int blk = 0; blk < 4; ++blk) {
      *(bf16x8*)&sC[r * 72 + off + blk * 8] = *(const bf16x8*)&Cb[(tb + r) * DS + off + blk * 8];
      *(bf16x8*)&sU[r * 80 + off + blk * 8] = *(const bf16x8*)&Bb[(tb + r) * DS + off + blk * 8];
    }
  }
  if (tid < 128) scs[tid] = csumb[tb + tid];
  __syncthreads();

  // phase 1: G = C @ B^T (128t x 128s, K=64). Wave (wm=0,ws=64) is fully masked.
  {
    int wm = (wave >> 1) * 64, wss = (wave & 1) * 64;
    if (wave == 1) {
      // all s > t: zeros, no MFMA
      #pragma unroll
      for (int i = 0; i < 4; ++i) {
        #pragma unroll
        for (int r = 0; r < 4; ++r) {
          int t = i * 16 + q * 4 + r;
          #pragma unroll
          for (int j = 0; j < 4; ++j)
            sM[t * 136 + 64 + j * 16 + c] = 0;
        }
      }
    } else {
      f32x4 g[4][4];
      #pragma unroll
      for (int i = 0; i < 4; ++i)
        #pragma unroll
        for (int j = 0; j < 4; ++j) g[i][j] = (f32x4)0.f;
      #pragma unroll
      for (int k0 = 0; k0 < 64; k0 += 32) {
        bf16x8 af[4], bfr[4];
        #pragma unroll
        for (int i = 0; i < 4; ++i)
          af[i] = *(const bf16x8*)&sC[(wm + i * 16 + c) * 72 + k0 + q * 8];
        #pragma unroll
        for (int j = 0; j < 4; ++j)
          bfr[j] = *(const bf16x8*)&sU[(wss + j * 16 + c) * 80 + k0 + q * 8];
        #pragma unroll
        for (int i = 0; i < 4; ++i)
          #pragma unroll
          for (int j = 0; j < 4; ++j)
            g[i][j] = __builtin_amdgcn_mfma_f32_16x16x32_bf16(af[i], bfr[j], g[i][j], 0, 0, 0);
      }
      #pragma unroll
      for (int i = 0; i < 4; ++i) {
        #pragma unroll
        for (int r = 0; r < 4; ++r) {
          int t = wm + i * 16 + q * 4 + r;
          float ct = scs[t];
          #pragma unroll
          for (int j = 0; j < 4; ++j) {
            int s = wss + j * 16 + c;
            float v = g[i][j][r];
            float m = (s <= t) ? v * __expf(Aval * (ct - scs[s])) : 0.f;
            sM[t * 136 + s] = (short)f2bf(m);
          }
        }
      }
    }
  }

  // phase 2: Y (128t x 128p) = M @ U + Chat @ Hin
  int wm2 = (wave >> 1) * 64, wp = (wave & 1) * 64;
  f32x4 acc[4][4];
  #pragma unroll
  for (int i = 0; i < 4; ++i)
    #pragma unroll
    for (int j = 0; j < 4; ++j) acc[i][j] = (f32x4)0.f;

  for (int ks = 0; ks < 4; ++ks) {
    __syncthreads();
    {
      int r = tid >> 1, off = (tid & 1) * 16;
      size_t ua = ((size_t)b * DI + ph * 128 + r) * LSEQ + ch * CL + ks * 32 + off;
      bf16x8 u0 = *(const bf16x8*)&Ut[ua];
      bf16x8 u1 = *(const bf16x8*)&Ut[ua + 8];
      *(bf16x8*)&sU[r * 40 + off]     = u0;
      *(bf16x8*)&sU[r * 40 + off + 8] = u1;
    }
    __syncthreads();
    bf16x8 af[4], bfr[4];
    #pragma unroll
    for (int i = 0; i < 4; ++i)
      af[i] = *(const bf16x8*)&sM[(wm2 + i * 16 + c) * 136 + ks * 32 + q * 8];
    #pragma unroll
    for (int j = 0; j < 4; ++j)
      bfr[j] = *(const bf16x8*)&sU[(wp + j * 16 + c) * 40 + q * 8];
    #pragma unroll
    for (int i = 0; i < 4; ++i)
      #pragma unroll
      for (int j = 0; j < 4; ++j)
        acc[i][j] = __builtin_amdgcn_mfma_f32_16x16x32_bf16(af[i], bfr[j], acc[i][j], 0, 0, 0);
  }

  __syncthreads();
  {
    int r = tid >> 1, off = (tid & 1) * 32;
    float sc_t = __expf(Aval * scs[r]);
    #pragma unroll
    for (int blk = 0; blk < 4; ++blk) {
      bf16x8 v = *(const bf16x8*)&sC[r * 72 + off + blk * 8];
      bf16x8 o;
      #pragma unroll
      for (int e = 0; e < 8; ++e)
        o[e] = (short)f2bf(bf2f((ushort_t)v[e]) * sc_t);
      *(bf16x8*)&sM[r * 80 + off + blk * 8] = o;
    }
  }
  for (int ks = 4; ks < 6; ++ks) {
    __syncthreads();
    {
      int r = tid >> 1, off = (tid & 1) * 16;
      size_t ha = ((size_t)bc * DI + ph * 128 + r) * DS + (ks - 4) * 32 + off;
      bf16x8 h0 = *(const bf16x8*)&hin[ha];
      bf16x8 h1 = *(const bf16x8*)&hin[ha + 8];
      *(bf16x8*)&sU[r * 40 + off]     = h0;
      *(bf16x8*)&sU[r * 40 + off + 8] = h1;
    }
    __syncthreads();
    bf16x8 af[4], bfr[4];
    #pragma unroll
    for (int i = 0; i < 4; ++i)
      af[i] = *(const bf16x8*)&sM[(wm2 + i * 16 + c) * 80 + (ks - 4) * 32 + q * 8];
    #pragma unroll
    for (int j = 0; j < 4; ++j)
      bfr[j] = *(const bf16x8*)&sU[(wp + j * 16 + c) * 40 + q * 8];
    #pragma unroll
    for (int i = 0; i < 4; ++i)
      #pragma unroll
      for (int j = 0; j < 4; ++j)
        acc[i][j] = __builtin_amdgcn_mfma_f32_16x16x32_bf16(af[i], bfr[j], acc[i][j], 0, 0, 0);
  }

  #pragma unroll
  for (int i = 0; i < 4; ++i) {
    #pragma unroll
    for (int r = 0; r < 4; ++r) {
      int t = wm2 + i * 16 + q * 4 + r;
      size_t row = (tb + t) * DI;
      #pragma unroll
      for (int j = 0; j < 4; ++j) {
        int pg = ph * 128 + wp + j * 16 + c;
        y[row + pg] = f2bf(acc[i][j][r] + dp * bf2f(xb[row + pg]));
      }
    }
  }
}

// last token only
__global__ __launch_bounds__(256) void finalize(const float* __restrict__ resid,
    const float* __restrict__ mixo, const float* __restrict__ embed,
    const float* __restrict__ nfw, float* __restrict__ out) {
  int b = blockIdx.x, tid = threadIdx.x;
  __shared__ float fin[DM];
  size_t off = ((size_t)b * LSEQ + (LSEQ - 1)) * DM;
  float r = resid[off + tid] + mixo[off + tid];
  float ss = block_reduce_sum256(r * r);
  fin[tid] = r * rsqrtf(ss * (1.f / DM) + 1e-5f) * nfw[tid];
  __syncthreads();
  if (tid < VOC) {
    float acc = 0.f;
    #pragma unroll 8
    for (int d = 0; d < DM; ++d) acc += fin[d] * embed[(size_t)tid * DM + d];
    out[b * VOC + tid] = acc;
  }
}

extern "C" void kernel_launch(void* const* d_in, const int* in_sizes, int n_in,
                              void* d_out, int out_size, void* d_ws, size_t ws_size,
                              hipStream_t stream) {
  const int*   ids   = (const int*)d_in[0];
  const float* embed = (const float*)d_in[1];
  const float* ipw   = (const float*)d_in[2];
  const float* cw    = (const float*)d_in[3];
  const float* cb    = (const float*)d_in[4];
  const float* dtbias= (const float*)d_in[5];
  const float* alog  = (const float*)d_in[6];
  const float* dpar  = (const float*)d_in[7];
  const float* ngw   = (const float*)d_in[8];
  const float* opw   = (const float*)d_in[9];
  const float* bnw   = (const float*)d_in[10];
  const float* nfw   = (const float*)d_in[11];
  float* out = (float*)d_out;

  // workspace layout (~156 MB)
  char* p = (char*)d_ws;
  float* resid = (float*)p;            p += (size_t)TKN * DM * 4;
  float* mixo  = (float*)p;            p += (size_t)TKN * DM * 4;
  ushort_t* hn = (ushort_t*)p;         p += (size_t)TKN * DM * 2;
  ushort_t* zx = (ushort_t*)p;         p += (size_t)TKN * DIPP * 2;
  float* dtb   = (float*)p;            p += (size_t)TKN * 4;
  float* csumb = (float*)p;            p += (size_t)TKN * 4;
  ushort_t* xb = (ushort_t*)p;         p += (size_t)TKN * DI * 2;
  ushort_t* yb = (ushort_t*)p;         p += (size_t)TKN * DI * 2;
  ushort_t* Bb = (ushort_t*)p;         p += (size_t)TKN * DS * 2;
  ushort_t* Cb = (ushort_t*)p;         p += (size_t)TKN * DS * 2;
  ushort_t* Ut = (ushort_t*)p;         p += (size_t)TKN * DI * 2;
  ushort_t* hin= (ushort_t*)p;         p += (size_t)NB * NC * DI * DS * 2;
  ushort_t* wbi= (ushort_t*)p;         p += (size_t)NL * DIP * DM * 2;
  ushort_t* wbo= (ushort_t*)p;         p += (size_t)NL * DM * DI * 2;
  // hst (fp32) aliases yb (bf16): consumed by combine2 before y_gemm writes yb
  float* hst = (float*)yb;

  convert_w<<<(NL * DIP * DM + NL * DM * DI + 1023) / 1024, 256, 0, stream>>>(
      ipw, opw, wbi, wbo);

  for (int i = 0; i < NL; ++i) {
    add_rmsnorm<<<TKN / 4, 256, 0, stream>>>(resid, mixo, hn, bnw + (size_t)i * DM,
                                             ids, embed, i == 0 ? 1 : 0);
    gemm_nt_bf16<ushort_t><<<dim3((DIP + 127) / 128, TKN / 128), 256, 0, stream>>>(
        hn, wbi + (size_t)i * DIP * DM, zx, DIP, DM, DIPP);
    csum_k<<<32, 256, 0, stream>>>(zx, dtbias + i, dtb, csumb);
    conv_silu<<<dim3(CDIM / 128, LSEQ / 64, NB), 256, 0, stream>>>(
        zx, cw + (size_t)i * CDIM * 4, cb + (size_t)i * CDIM, dtb, xb, Bb, Cb, Ut);
    state_gemm<<<dim3(4, NC, NB), 256, 0, stream>>>(Bb, Ut, csumb, alog + i, hst);
    combine2<<<dim3(DI / 64, 4, NB), 256, 0, stream>>>(hst, csumb, alog + i, hin);
    y_gemm<<<dim3(4, NC, NB), 256, 0, stream>>>(Bb, Cb, Ut, hin, csumb, alog + i,
                                                dpar + i, xb, yb);
    outproj_fused<<<dim3(2, TKN / 64), 256, 0, stream>>>(
        yb, zx, wbo + (size_t)i * DM * DI, ngw + (size_t)i * DI, mixo);
  }

  finalize<<<NB, 256, 0, stream>>>(resid, mixo, embed, nfw, out);
}